// Round 1
// baseline (1249.288 us; speedup 1.0000x reference)
//
#include <hip/hip_runtime.h>

#define HD 128

// ===================== graph preprocessing =====================

__global__ void fill_ones2(float* a, float* b, int n) {
  int i = blockIdx.x * blockDim.x + threadIdx.x;
  if (i < n) { a[i] = 1.f; b[i] = 1.f; }
}

__global__ void hist_kernel(const int* __restrict__ row, const int* __restrict__ col,
                            int* __restrict__ cnt_in, int* __restrict__ outdeg, int e) {
  int i = blockIdx.x * blockDim.x + threadIdx.x;
  if (i < e) { atomicAdd(&cnt_in[col[i]], 1); atomicAdd(&outdeg[row[i]], 1); }
}

__global__ void scan_kernel(const int* __restrict__ cnt, int n, int* __restrict__ ptr,
                            int* __restrict__ cursor) {
  __shared__ int buf[2][1024];
  __shared__ int carry;
  int t = threadIdx.x;
  if (t == 0) { carry = 0; ptr[0] = 0; }
  __syncthreads();
  for (int base = 0; base < n; base += 1024) {
    int v = (base + t < n) ? cnt[base + t] : 0;
    buf[0][t] = v;
    __syncthreads();
    int cur = 0;
    for (int off = 1; off < 1024; off <<= 1) {
      int val = buf[cur][t];
      if (t >= off) val += buf[cur][t - off];
      buf[cur ^ 1][t] = val;
      cur ^= 1;
      __syncthreads();
    }
    int incl = buf[cur][t];
    int c = carry;
    if (base + t < n) {
      ptr[base + t + 1] = c + incl;
      cursor[base + t] = c + incl - v;   // exclusive start
    }
    __syncthreads();
    if (t == 1023) carry = c + incl;
    __syncthreads();
  }
}

__global__ void place_kernel(const int* __restrict__ row, const int* __restrict__ col,
                             int* __restrict__ cursor, int* __restrict__ csr_src,
                             int* __restrict__ csr_eid, int e) {
  int i = blockIdx.x * blockDim.x + threadIdx.x;
  if (i < e) {
    int c = col[i];
    int pos = atomicAdd(&cursor[c], 1);
    csr_src[pos] = row[i];
    csr_eid[pos] = i;
  }
}

__global__ void dinv1_kernel(const int* __restrict__ outdeg, float* __restrict__ dinv1, int n) {
  int i = blockIdx.x * blockDim.x + threadIdx.x;
  if (i < n) dinv1[i] = rsqrtf((float)(outdeg[i] + 1));
}

__global__ void build_wnorm1(const int* __restrict__ ptr, const int* __restrict__ src,
                             const float* __restrict__ dinv1, float* __restrict__ wn) {
  int n = blockIdx.x;
  float dn = dinv1[n];
  int e1 = ptr[n + 1];
  for (int e = ptr[n] + threadIdx.x; e < e1; e += blockDim.x)
    wn[e] = dinv1[src[e]] * dn;
}

__global__ void dinvw_kernel(float* a, float* b, int n) {
  int i = blockIdx.x * blockDim.x + threadIdx.x;
  if (i < n) { a[i] = rsqrtf(a[i]); b[i] = rsqrtf(b[i]); }
}

__global__ void build_wnormco(const int* __restrict__ ptr, const int* __restrict__ src,
                              const int* __restrict__ eid, const float* __restrict__ eatt,
                              const float* __restrict__ dc, const float* __restrict__ dd,
                              float* __restrict__ wc, float* __restrict__ wo) {
  int n = blockIdx.x;
  float dcn = dc[n], don = dd[n];
  int e1 = ptr[n + 1];
  for (int e = ptr[n] + threadIdx.x; e < e1; e += blockDim.x) {
    int s = src[e]; int id = eid[e];
    wc[e] = dc[s] * eatt[id * 2 + 0] * dcn;
    wo[e] = dd[s] * eatt[id * 2 + 1] * don;
  }
}

// ===================== BN stats + weight folding =====================

__global__ void colstats(const float* __restrict__ A, int n, int rpb,
                         float* __restrict__ sum, float* __restrict__ sumsq) {
  int colj = threadIdx.x & (HD - 1);
  int half = threadIdx.x >> 7;
  int r0 = blockIdx.x * rpb;
  int r1 = min(n, r0 + rpb);
  float s = 0.f, q = 0.f;
  for (int r = r0 + half; r < r1; r += 2) {
    float v = A[(size_t)r * HD + colj];
    s += v; q += v * v;
  }
  atomicAdd(&sum[colj], s);
  atomicAdd(&sumsq[colj], q);
}

__global__ void colstats_scaled(const float* __restrict__ A, const float* __restrict__ natt,
                                int n, int rpb, float* __restrict__ o4) {
  int colj = threadIdx.x & (HD - 1);
  int half = threadIdx.x >> 7;
  int r0 = blockIdx.x * rpb;
  int r1 = min(n, r0 + rpb);
  float sc = 0.f, qc = 0.f, so = 0.f, qo = 0.f;
  for (int r = r0 + half; r < r1; r += 2) {
    float v = A[(size_t)r * HD + colj];
    float a0 = natt[r * 2], a1 = natt[r * 2 + 1];
    float vc = a0 * v, vo = a1 * v;
    sc += vc; qc += vc * vc; so += vo; qo += vo * vo;
  }
  atomicAdd(&o4[colj], sc);
  atomicAdd(&o4[HD + colj], qc);
  atomicAdd(&o4[2 * HD + colj], so);
  atomicAdd(&o4[3 * HD + colj], qo);
}

// bn(x) = x*s + t with s = g*rsqrt(var+eps), t = b - m*s
// (x*s+t) @ W  =  x @ (s o W) + (t @ W)
__global__ void fold_bn(const float* __restrict__ W, const float* __restrict__ g,
                        const float* __restrict__ b, const float* __restrict__ sum,
                        const float* __restrict__ sumsq, float invN,
                        float* __restrict__ Wout, float* __restrict__ bout) {
  __shared__ float sA[HD], tA[HD];
  int tid = threadIdx.x;  // 0..127
  float m = sum[tid] * invN;
  float v = sumsq[tid] * invN - m * m;
  float s = g[tid] * rsqrtf(v + 1e-5f);
  sA[tid] = s;
  tA[tid] = b[tid] - m * s;
  __syncthreads();
  float acc = 0.f;
  for (int k = 0; k < HD; k++) {
    float w = W[k * HD + tid];
    acc += tA[k] * w;
    Wout[k * HD + tid] = sA[k] * w;
  }
  bout[tid] = acc;
}

// ===================== GEMM: out[n,128] = rs(n)*(A[n,128] @ W[128,128]) + bias =====================

__global__ __launch_bounds__(256) void gemm128(
    const float* __restrict__ A, const float* __restrict__ W,
    const float* __restrict__ bias, const float* __restrict__ rowscale, int rsStride,
    float* __restrict__ out, int n, int relu) {
  __shared__ float As[32][68];    // [k][row], padded
  __shared__ float Ws[32][132];   // [k][j], padded
  int tid = threadIdx.x;
  int r0 = blockIdx.x * 64;
  int tr = tid >> 4, tc = tid & 15;
  float acc[4][8];
#pragma unroll
  for (int i = 0; i < 4; i++)
#pragma unroll
    for (int j = 0; j < 8; j++) acc[i][j] = 0.f;

  for (int kk = 0; kk < 128; kk += 32) {
#pragma unroll
    for (int i = 0; i < 2; i++) {           // A tile 64x32, transposed into LDS
      int f = tid + i * 256;
      int rloc = f >> 3;
      int kc = (f & 7) * 4;
      int gr = r0 + rloc;
      float4 v = make_float4(0.f, 0.f, 0.f, 0.f);
      if (gr < n) v = *(const float4*)(A + (size_t)gr * 128 + kk + kc);
      As[kc + 0][rloc] = v.x;
      As[kc + 1][rloc] = v.y;
      As[kc + 2][rloc] = v.z;
      As[kc + 3][rloc] = v.w;
    }
#pragma unroll
    for (int i = 0; i < 4; i++) {           // W tile 32x128
      int f = tid + i * 256;
      int krow = f >> 5;
      int jc = (f & 31) * 4;
      *(float4*)&Ws[krow][jc] = *(const float4*)(W + (size_t)(kk + krow) * 128 + jc);
    }
    __syncthreads();
#pragma unroll
    for (int k = 0; k < 32; k++) {
      float4 a = *(float4*)&As[k][tr * 4];
      float4 b0 = *(float4*)&Ws[k][tc * 4];
      float4 b1 = *(float4*)&Ws[k][64 + tc * 4];
      float av[4] = {a.x, a.y, a.z, a.w};
      float bv[8] = {b0.x, b0.y, b0.z, b0.w, b1.x, b1.y, b1.z, b1.w};
#pragma unroll
      for (int i = 0; i < 4; i++)
#pragma unroll
        for (int j = 0; j < 8; j++) acc[i][j] += av[i] * bv[j];
    }
    __syncthreads();
  }
#pragma unroll
  for (int i = 0; i < 4; i++) {
    int r = r0 + tr * 4 + i;
    if (r >= n) break;
    float rs = rowscale ? rowscale[(size_t)r * rsStride] : 1.f;
    float vals[8];
#pragma unroll
    for (int j = 0; j < 4; j++) {
      float v0 = acc[i][j] * rs + bias[tc * 4 + j];
      float v1 = acc[i][j + 4] * rs + bias[64 + tc * 4 + j];
      if (relu) { v0 = fmaxf(v0, 0.f); v1 = fmaxf(v1, 0.f); }
      vals[j] = v0; vals[4 + j] = v1;
    }
    *(float4*)(out + (size_t)r * 128 + tc * 4) = *(float4*)&vals[0];
    *(float4*)(out + (size_t)r * 128 + 64 + tc * 4) = *(float4*)&vals[4];
  }
}

// ===================== GCN aggregation (gather over CSR-by-destination) =====================

__global__ void prop_kernel(const float* __restrict__ z, const int* __restrict__ ptr,
                            const int* __restrict__ src, const float* __restrict__ wn,
                            const float* __restrict__ dinv, const float* __restrict__ bias,
                            float* __restrict__ out, int relu) {
  int n = blockIdx.x;
  int j = threadIdx.x;  // 128 threads
  float dn = dinv[n];
  float acc = dn * dn * z[(size_t)n * HD + j];   // self loop, weight 1
  int e1 = ptr[n + 1];
  for (int e = ptr[n]; e < e1; e++) {
    int s = src[e];
    acc += wn[e] * z[(size_t)s * HD + j];
  }
  acc += bias[j];
  if (relu) acc = fmaxf(acc, 0.f);
  out[(size_t)n * HD + j] = acc;
}

// ===================== attention projections =====================

__global__ void proj_kernel(const float* __restrict__ h, const float* __restrict__ We,
                            const float* __restrict__ Wn, const float* __restrict__ bn,
                            float* __restrict__ natt, float* __restrict__ pe, int n) {
  int gtid = blockIdx.x * blockDim.x + threadIdx.x;
  int wave = gtid >> 6;
  int lane = threadIdx.x & 63;
  int nwaves = (gridDim.x * blockDim.x) >> 6;
  for (int node = wave; node < n; node += nwaves) {
    float h0 = h[(size_t)node * HD + lane];
    float h1 = h[(size_t)node * HD + 64 + lane];
    float v[6];
    v[0] = h0 * We[lane * 2 + 0] + h1 * We[(64 + lane) * 2 + 0];
    v[1] = h0 * We[lane * 2 + 1] + h1 * We[(64 + lane) * 2 + 1];
    v[2] = h0 * We[(128 + lane) * 2 + 0] + h1 * We[(192 + lane) * 2 + 0];
    v[3] = h0 * We[(128 + lane) * 2 + 1] + h1 * We[(192 + lane) * 2 + 1];
    v[4] = h0 * Wn[lane * 2 + 0] + h1 * Wn[(64 + lane) * 2 + 0];
    v[5] = h0 * Wn[lane * 2 + 1] + h1 * Wn[(64 + lane) * 2 + 1];
#pragma unroll
    for (int m = 32; m > 0; m >>= 1) {
#pragma unroll
      for (int q = 0; q < 6; q++) v[q] += __shfl_xor(v[q], m, 64);
    }
    if (lane == 0) {
      float q0 = v[4] + bn[0], q1 = v[5] + bn[1];
      float mx = fmaxf(q0, q1);
      float e0 = expf(q0 - mx), e1 = expf(q1 - mx);
      float inv = 1.f / (e0 + e1);
      natt[node * 2 + 0] = e0 * inv;
      natt[node * 2 + 1] = e1 * inv;
      pe[node * 4 + 0] = v[0];
      pe[node * 4 + 1] = v[1];
      pe[node * 4 + 2] = v[2];
      pe[node * 4 + 3] = v[3];
    }
  }
}

__global__ void eatt_kernel(const int* __restrict__ row, const int* __restrict__ col,
                            const float* __restrict__ pe, const float* __restrict__ be,
                            float* __restrict__ eatt, float* __restrict__ degc,
                            float* __restrict__ dego, int e) {
  int i = blockIdx.x * blockDim.x + threadIdx.x;
  if (i >= e) return;
  int r = row[i], c = col[i];
  float l0 = pe[r * 4 + 0] + pe[c * 4 + 2] + be[0];
  float l1 = pe[r * 4 + 1] + pe[c * 4 + 3] + be[1];
  float m = fmaxf(l0, l1);
  float e0 = expf(l0 - m), e1 = expf(l1 - m);
  float inv = 1.f / (e0 + e1);
  e0 *= inv; e1 *= inv;
  eatt[i * 2 + 0] = e0;
  eatt[i * 2 + 1] = e1;
  atomicAdd(&degc[r], e0);
  atomicAdd(&dego[r], e1);
}

// ===================== pooling (batch sorted -> contiguous segments) =====================

__global__ void pool_kernel(const float* __restrict__ xc, const float* __restrict__ xo,
                            const int* __restrict__ batch, int n,
                            float* __restrict__ pc, float* __restrict__ po) {
  int g = blockIdx.x;
  int j = threadIdx.x;  // 128
  __shared__ int s0, s1;
  if (threadIdx.x == 0) {
    int lo = 0, hi = n;
    while (lo < hi) { int mid = (lo + hi) >> 1; if (batch[mid] < g) lo = mid + 1; else hi = mid; }
    s0 = lo;
    lo = 0; hi = n;
    while (lo < hi) { int mid = (lo + hi) >> 1; if (batch[mid] < g + 1) lo = mid + 1; else hi = mid; }
    s1 = lo;
  }
  __syncthreads();
  float ac = 0.f, ao = 0.f;
  for (int r = s0; r < s1; r++) {
    ac += xc[(size_t)r * HD + j];
    ao += xo[(size_t)r * HD + j];
  }
  pc[g * HD + j] = ac;
  po[g * HD + j] = ao;
}

// ===================== readout heads (G=128 rows, all in LDS) =====================

__global__ __launch_bounds__(512) void head_kernel(
    const float* __restrict__ pc, const float* __restrict__ po,
    const float* __restrict__ bn1g, const float* __restrict__ bn1b,
    const float* __restrict__ W1, const float* __restrict__ b1,
    const float* __restrict__ bn2g, const float* __restrict__ bn2b,
    const float* __restrict__ W2, const float* __restrict__ b2,
    float* __restrict__ out) {
  int t = blockIdx.x;  // head 0,1,2
  __shared__ float V[128][129];
  __shared__ float Y[128][129];
  __shared__ float Z[128][12];
  __shared__ float sA[128], tA[128];
  int tid = threadIdx.x, nt = blockDim.x;
  for (int idx = tid; idx < 16384; idx += nt) {
    int r = idx >> 7, j = idx & 127;
    float v = (t == 0) ? pc[idx] : (t == 1) ? po[idx] : (pc[idx] + po[idx]);
    V[r][j] = v;
  }
  __syncthreads();
  if (tid < 128) {
    float s = 0.f, q = 0.f;
    for (int r = 0; r < 128; r++) { float v = V[r][tid]; s += v; q += v * v; }
    float m = s * (1.f / 128.f), var = q * (1.f / 128.f) - m * m;
    float sc = bn1g[t * 128 + tid] * rsqrtf(var + 1e-5f);
    sA[tid] = sc; tA[tid] = bn1b[t * 128 + tid] - m * sc;
  }
  __syncthreads();
  for (int idx = tid; idx < 16384; idx += nt) {
    int r = idx >> 7, j = idx & 127;
    V[r][j] = V[r][j] * sA[j] + tA[j];
  }
  __syncthreads();
  for (int idx = tid; idx < 16384; idx += nt) {
    int r = idx >> 7, j = idx & 127;
    float acc = b1[t * 128 + j];
    for (int k = 0; k < 128; k++) acc += V[r][k] * W1[(size_t)t * 16384 + k * 128 + j];
    Y[r][j] = fmaxf(acc, 0.f);
  }
  __syncthreads();
  if (tid < 128) {
    float s = 0.f, q = 0.f;
    for (int r = 0; r < 128; r++) { float v = Y[r][tid]; s += v; q += v * v; }
    float m = s * (1.f / 128.f), var = q * (1.f / 128.f) - m * m;
    float sc = bn2g[t * 128 + tid] * rsqrtf(var + 1e-5f);
    sA[tid] = sc; tA[tid] = bn2b[t * 128 + tid] - m * sc;
  }
  __syncthreads();
  for (int idx = tid; idx < 16384; idx += nt) {
    int r = idx >> 7, j = idx & 127;
    Y[r][j] = Y[r][j] * sA[j] + tA[j];
  }
  __syncthreads();
  for (int idx = tid; idx < 1280; idx += nt) {
    int r = idx / 10, c = idx % 10;
    float acc = b2[t * 10 + c];
    for (int k = 0; k < 128; k++) acc += Y[r][k] * W2[(size_t)t * 1280 + k * 10 + c];
    Z[r][c] = acc;
  }
  __syncthreads();
  if (tid < 128) {
    int r = tid;
    float m = -1e30f;
    for (int c = 0; c < 10; c++) m = fmaxf(m, Z[r][c]);
    float se = 0.f;
    for (int c = 0; c < 10; c++) se += expf(Z[r][c] - m);
    float lse = m + logf(se);
    for (int c = 0; c < 10; c++) out[t * 1280 + r * 10 + c] = Z[r][c] - lse;
  }
}

// ===================== launch =====================

extern "C" void kernel_launch(void* const* d_in, const int* in_sizes, int n_in,
                              void* d_out, int out_size, void* d_ws, size_t ws_size,
                              hipStream_t stream) {
  const int N = in_sizes[0] / HD;    // 40000
  const int E = in_sizes[1] / 2;     // 480000
  const int G = out_size / 30;       // 128

  const float* x      = (const float*)d_in[0];
  const int*   ei     = (const int*)d_in[1];
  const int*   batch  = (const int*)d_in[2];
  const float* bnfg   = (const float*)d_in[3];
  const float* bnfb   = (const float*)d_in[4];
  const float* Wfeat  = (const float*)d_in[5];
  const float* bnsg   = (const float*)d_in[6];
  const float* bnsb   = (const float*)d_in[7];
  const float* convW  = (const float*)d_in[8];
  const float* convb  = (const float*)d_in[9];
  const float* Weatt  = (const float*)d_in[10];
  const float* beatt  = (const float*)d_in[11];
  const float* Wnatt  = (const float*)d_in[12];
  const float* bnatt  = (const float*)d_in[13];
  const float* bncg   = (const float*)d_in[14];
  const float* bncb   = (const float*)d_in[15];
  const float* bnog   = (const float*)d_in[16];
  const float* bnob   = (const float*)d_in[17];
  const float* Wc     = (const float*)d_in[18];
  const float* bc     = (const float*)d_in[19];
  const float* Wo     = (const float*)d_in[20];
  const float* bo     = (const float*)d_in[21];
  const float* robn1g = (const float*)d_in[22];
  const float* robn1b = (const float*)d_in[23];
  const float* roW1   = (const float*)d_in[24];
  const float* rob1   = (const float*)d_in[25];
  const float* robn2g = (const float*)d_in[26];
  const float* robn2b = (const float*)d_in[27];
  const float* roW2   = (const float*)d_in[28];
  const float* rob2   = (const float*)d_in[29];
  float* out = (float*)d_out;

  const int* row = ei;
  const int* col = ei + E;

  char* p = (char*)d_ws;
  auto alloc = [&](size_t bytes) -> void* {
    void* r = (void*)p;
    p += (bytes + 255) & ~(size_t)255;
    return r;
  };
  float* B0      = (float*)alloc((size_t)N * HD * 4);
  float* B1      = (float*)alloc((size_t)N * HD * 4);
  float* B2      = (float*)alloc((size_t)N * HD * 4);
  float* B3      = (float*)alloc((size_t)N * HD * 4);
  float* eatt    = (float*)alloc((size_t)E * 2 * 4);
  int*   csr_src = (int*)alloc((size_t)E * 4);
  int*   csr_eid = (int*)alloc((size_t)E * 4);
  float* wn1     = (float*)alloc((size_t)E * 4);
  float* wnc     = (float*)alloc((size_t)E * 4);
  float* wno     = (float*)alloc((size_t)E * 4);
  int*   ptrA    = (int*)alloc((size_t)(N + 1) * 4);
  int*   cursor  = (int*)alloc((size_t)N * 4);
  int*   cnt_in  = (int*)alloc((size_t)N * 4);
  int*   outdeg  = (int*)alloc((size_t)N * 4);
  float* dinv1   = (float*)alloc((size_t)N * 4);
  float* degc    = (float*)alloc((size_t)N * 4);
  float* dego    = (float*)alloc((size_t)N * 4);
  float* natt    = (float*)alloc((size_t)N * 2 * 4);
  float* pe      = (float*)alloc((size_t)N * 4 * 4);
  float* stats   = (float*)alloc(12 * HD * 4);   // x(2), h0..h2(2 each), co(4)
  float* Wbuf    = (float*)alloc(HD * HD * 4);
  float* bbuf    = (float*)alloc(HD * 4);
  float* pooledc = (float*)alloc((size_t)G * HD * 4);
  float* pooledo = (float*)alloc((size_t)G * HD * 4);

  // ---- init accumulators ----
  hipMemsetAsync(cnt_in, 0, (size_t)N * 4, stream);
  hipMemsetAsync(outdeg, 0, (size_t)N * 4, stream);
  hipMemsetAsync(stats, 0, 12 * HD * 4, stream);
  fill_ones2<<<(N + 255) / 256, 256, 0, stream>>>(degc, dego, N);

  // ---- CSR by destination + unweighted norms ----
  hist_kernel<<<(E + 255) / 256, 256, 0, stream>>>(row, col, cnt_in, outdeg, E);
  scan_kernel<<<1, 1024, 0, stream>>>(cnt_in, N, ptrA, cursor);
  place_kernel<<<(E + 255) / 256, 256, 0, stream>>>(row, col, cursor, csr_src, csr_eid, E);
  dinv1_kernel<<<(N + 255) / 256, 256, 0, stream>>>(outdeg, dinv1, N);
  build_wnorm1<<<N, 64, 0, stream>>>(ptrA, csr_src, dinv1, wn1);

  const int SB = 160;
  int rpb = (N + SB - 1) / SB;
  int gblocks = (N + 63) / 64;
  float invN = 1.f / (float)N;

  // ---- feature BN + gfn linear + relu ----
  colstats<<<SB, 256, 0, stream>>>(x, N, rpb, stats, stats + HD);
  fold_bn<<<1, 128, 0, stream>>>(Wfeat, bnfg, bnfb, stats, stats + HD, invN, Wbuf, bbuf);
  gemm128<<<gblocks, 256, 0, stream>>>(x, Wbuf, bbuf, nullptr, 0, B0, N, 1);

  // ---- 3 GCN conv layers ----
  for (int i = 0; i < 3; i++) {
    float* hs = stats + 2 * HD + i * 2 * HD;
    colstats<<<SB, 256, 0, stream>>>(B0, N, rpb, hs, hs + HD);
    fold_bn<<<1, 128, 0, stream>>>(convW + (size_t)i * HD * HD, bnsg + i * HD, bnsb + i * HD,
                                   hs, hs + HD, invN, Wbuf, bbuf);
    gemm128<<<gblocks, 256, 0, stream>>>(B0, Wbuf, bbuf, nullptr, 0, B1, N, 0);
    prop_kernel<<<N, 128, 0, stream>>>(B1, ptrA, csr_src, wn1, dinv1, convb + i * HD, B0, 1);
  }

  // ---- attention ----
  proj_kernel<<<256, 256, 0, stream>>>(B0, Weatt, Wnatt, bnatt, natt, pe, N);
  eatt_kernel<<<(E + 255) / 256, 256, 0, stream>>>(row, col, pe, beatt, eatt, degc, dego, E);
  dinvw_kernel<<<(N + 255) / 256, 256, 0, stream>>>(degc, dego, N);
  build_wnormco<<<N, 64, 0, stream>>>(ptrA, csr_src, csr_eid, eatt, degc, dego, wnc, wno);

  // ---- xc / xo paths: stats of a0*h, a1*h, fold BN, GEMM with row scale ----
  float* cs = stats + 8 * HD;
  colstats_scaled<<<SB, 256, 0, stream>>>(B0, natt, N, rpb, cs);
  fold_bn<<<1, 128, 0, stream>>>(Wc, bncg, bncb, cs, cs + HD, invN, Wbuf, bbuf);
  gemm128<<<gblocks, 256, 0, stream>>>(B0, Wbuf, bbuf, natt, 2, B1, N, 0);      // zc
  fold_bn<<<1, 128, 0, stream>>>(Wo, bnog, bnob, cs + 2 * HD, cs + 3 * HD, invN, Wbuf, bbuf);
  gemm128<<<gblocks, 256, 0, stream>>>(B0, Wbuf, bbuf, natt + 1, 2, B2, N, 0);  // zo

  prop_kernel<<<N, 128, 0, stream>>>(B1, ptrA, csr_src, wnc, degc, bc, B3, 1);  // xc_out
  prop_kernel<<<N, 128, 0, stream>>>(B2, ptrA, csr_src, wno, dego, bo, B1, 1);  // xo_out

  // ---- pool + heads ----
  pool_kernel<<<G, 128, 0, stream>>>(B3, B1, batch, N, pooledc, pooledo);
  head_kernel<<<3, 512, 0, stream>>>(pooledc, pooledo, robn1g, robn1b, roW1, rob1,
                                     robn2g, robn2b, roW2, rob2, out);
}

// Round 2
// 1025.334 us; speedup vs baseline: 1.2184x; 1.2184x over previous
//
#include <hip/hip_runtime.h>

#define HD 128

// ===================== graph preprocessing =====================

__global__ void fill_ones2(float* a, float* b, int n) {
  int i = blockIdx.x * blockDim.x + threadIdx.x;
  if (i < n) { a[i] = 1.f; b[i] = 1.f; }
}

__global__ void hist_kernel(const int* __restrict__ row, const int* __restrict__ col,
                            int* __restrict__ cnt_in, int* __restrict__ outdeg, int e) {
  int i = blockIdx.x * blockDim.x + threadIdx.x;
  if (i < e) { atomicAdd(&cnt_in[col[i]], 1); atomicAdd(&outdeg[row[i]], 1); }
}

// ---- 3-stage scan over cnt[n] -> ptr[n+1], cursor[n] ----

__global__ void scan1(const int* __restrict__ cnt, int n, int* __restrict__ sums) {
  __shared__ int lds[256];
  int b = blockIdx.x, t = threadIdx.x;
  int base = b * 1024 + t * 4;
  int s = 0;
#pragma unroll
  for (int m = 0; m < 4; m++) if (base + m < n) s += cnt[base + m];
  lds[t] = s;
  __syncthreads();
  for (int d = 128; d > 0; d >>= 1) {
    if (t < d) lds[t] += lds[t + d];
    __syncthreads();
  }
  if (t == 0) sums[b] = lds[0];
}

__global__ void scan2(const int* __restrict__ sums, int nc, int* __restrict__ off) {
  int l = threadIdx.x;
  int v = (l < nc) ? sums[l] : 0;
  int x = v;
#pragma unroll
  for (int d = 1; d < 64; d <<= 1) {
    int y = __shfl_up(x, d, 64);
    if (l >= d) x += y;
  }
  if (l < nc) off[l] = x - v;  // exclusive
}

__global__ void scan3(const int* __restrict__ cnt, int n, const int* __restrict__ off,
                      int* __restrict__ ptr, int* __restrict__ cursor) {
  __shared__ int lds[256];
  int b = blockIdx.x, t = threadIdx.x;
  int base = b * 1024 + t * 4;
  int v[4], p[4];
#pragma unroll
  for (int m = 0; m < 4; m++) v[m] = (base + m < n) ? cnt[base + m] : 0;
  p[0] = v[0];
#pragma unroll
  for (int m = 1; m < 4; m++) p[m] = p[m - 1] + v[m];
  int tsum = p[3];
  lds[t] = tsum;
  __syncthreads();
  for (int d = 1; d < 256; d <<= 1) {
    int y = 0;
    if (t >= d) y = lds[t - d];
    __syncthreads();
    lds[t] += y;
    __syncthreads();
  }
  int basev = off[b] + lds[t] - tsum;  // exclusive thread base
  if (b == 0 && t == 0) ptr[0] = 0;
#pragma unroll
  for (int m = 0; m < 4; m++) {
    int i = base + m;
    if (i < n) {
      int incl = basev + p[m];
      ptr[i + 1] = incl;
      cursor[i] = incl - v[m];
    }
  }
}

__global__ void place_kernel(const int* __restrict__ row, const int* __restrict__ col,
                             int* __restrict__ cursor, int* __restrict__ csr_src,
                             int* __restrict__ csr_eid, int e) {
  int i = blockIdx.x * blockDim.x + threadIdx.x;
  if (i < e) {
    int c = col[i];
    int pos = atomicAdd(&cursor[c], 1);
    csr_src[pos] = row[i];
    csr_eid[pos] = i;
  }
}

__global__ void dinv1_kernel(const int* __restrict__ outdeg, float* __restrict__ dinv1, int n) {
  int i = blockIdx.x * blockDim.x + threadIdx.x;
  if (i < n) dinv1[i] = rsqrtf((float)(outdeg[i] + 1));
}

__global__ void build_wnorm1(const int* __restrict__ ptr, const int* __restrict__ src,
                             const float* __restrict__ dinv1, float* __restrict__ wn) {
  int n = blockIdx.x;
  float dn = dinv1[n];
  int e1 = ptr[n + 1];
  for (int e = ptr[n] + threadIdx.x; e < e1; e += blockDim.x)
    wn[e] = dinv1[src[e]] * dn;
}

__global__ void dinvw_kernel(float* a, float* b, int n) {
  int i = blockIdx.x * blockDim.x + threadIdx.x;
  if (i < n) { a[i] = rsqrtf(a[i]); b[i] = rsqrtf(b[i]); }
}

__global__ void build_wnormco(const int* __restrict__ ptr, const int* __restrict__ src,
                              const int* __restrict__ eid, const float* __restrict__ eatt,
                              const float* __restrict__ dc, const float* __restrict__ dd,
                              float* __restrict__ wc, float* __restrict__ wo) {
  int n = blockIdx.x;
  float dcn = dc[n], don = dd[n];
  int e1 = ptr[n + 1];
  for (int e = ptr[n] + threadIdx.x; e < e1; e += blockDim.x) {
    int s = src[e]; int id = eid[e];
    wc[e] = dc[s] * eatt[id * 2 + 0] * dcn;
    wo[e] = dd[s] * eatt[id * 2 + 1] * don;
  }
}

// ===================== BN stats + weight folding =====================

__global__ void colstats(const float* __restrict__ A, int n, int rpb,
                         float* __restrict__ sum, float* __restrict__ sumsq) {
  int colj = threadIdx.x & (HD - 1);
  int half = threadIdx.x >> 7;
  int r0 = blockIdx.x * rpb;
  int r1 = min(n, r0 + rpb);
  float s = 0.f, q = 0.f;
  for (int r = r0 + half; r < r1; r += 2) {
    float v = A[(size_t)r * HD + colj];
    s += v; q += v * v;
  }
  atomicAdd(&sum[colj], s);
  atomicAdd(&sumsq[colj], q);
}

__global__ void colstats_scaled(const float* __restrict__ A, const float* __restrict__ natt,
                                int n, int rpb, float* __restrict__ o4) {
  int colj = threadIdx.x & (HD - 1);
  int half = threadIdx.x >> 7;
  int r0 = blockIdx.x * rpb;
  int r1 = min(n, r0 + rpb);
  float sc = 0.f, qc = 0.f, so = 0.f, qo = 0.f;
  for (int r = r0 + half; r < r1; r += 2) {
    float v = A[(size_t)r * HD + colj];
    float a0 = natt[r * 2], a1 = natt[r * 2 + 1];
    float vc = a0 * v, vo = a1 * v;
    sc += vc; qc += vc * vc; so += vo; qo += vo * vo;
  }
  atomicAdd(&o4[colj], sc);
  atomicAdd(&o4[HD + colj], qc);
  atomicAdd(&o4[2 * HD + colj], so);
  atomicAdd(&o4[3 * HD + colj], qo);
}

// bn(x) = x*s + t with s = g*rsqrt(var+eps), t = b - m*s
// (x*s+t) @ W  =  x @ (s o W) + (t @ W)
__global__ void fold_bn(const float* __restrict__ W, const float* __restrict__ g,
                        const float* __restrict__ b, const float* __restrict__ sum,
                        const float* __restrict__ sumsq, float invN,
                        float* __restrict__ Wout, float* __restrict__ bout) {
  __shared__ float sA[HD], tA[HD];
  int tid = threadIdx.x;  // 0..127
  float m = sum[tid] * invN;
  float v = sumsq[tid] * invN - m * m;
  float s = g[tid] * rsqrtf(v + 1e-5f);
  sA[tid] = s;
  tA[tid] = b[tid] - m * s;
  __syncthreads();
  float acc = 0.f;
  for (int k = 0; k < HD; k++) {
    float w = W[k * HD + tid];
    acc += tA[k] * w;
    Wout[k * HD + tid] = sA[k] * w;
  }
  bout[tid] = acc;
}

// ===================== GEMM: out[n,128] = rs(n)*(A[n,128] @ W[128,128]) + bias =====================

__global__ __launch_bounds__(256) void gemm128(
    const float* __restrict__ A, const float* __restrict__ W,
    const float* __restrict__ bias, const float* __restrict__ rowscale, int rsStride,
    float* __restrict__ out, int n, int relu) {
  __shared__ float As[32][68];    // [k][row], padded
  __shared__ float Ws[32][132];   // [k][j], padded
  int tid = threadIdx.x;
  int r0 = blockIdx.x * 64;
  int tr = tid >> 4, tc = tid & 15;
  float acc[4][8];
#pragma unroll
  for (int i = 0; i < 4; i++)
#pragma unroll
    for (int j = 0; j < 8; j++) acc[i][j] = 0.f;

  for (int kk = 0; kk < 128; kk += 32) {
#pragma unroll
    for (int i = 0; i < 2; i++) {           // A tile 64x32, transposed into LDS
      int f = tid + i * 256;
      int rloc = f >> 3;
      int kc = (f & 7) * 4;
      int gr = r0 + rloc;
      float4 v = make_float4(0.f, 0.f, 0.f, 0.f);
      if (gr < n) v = *(const float4*)(A + (size_t)gr * 128 + kk + kc);
      As[kc + 0][rloc] = v.x;
      As[kc + 1][rloc] = v.y;
      As[kc + 2][rloc] = v.z;
      As[kc + 3][rloc] = v.w;
    }
#pragma unroll
    for (int i = 0; i < 4; i++) {           // W tile 32x128
      int f = tid + i * 256;
      int krow = f >> 5;
      int jc = (f & 31) * 4;
      *(float4*)&Ws[krow][jc] = *(const float4*)(W + (size_t)(kk + krow) * 128 + jc);
    }
    __syncthreads();
#pragma unroll
    for (int k = 0; k < 32; k++) {
      float4 a = *(float4*)&As[k][tr * 4];
      float4 b0 = *(float4*)&Ws[k][tc * 4];
      float4 b1 = *(float4*)&Ws[k][64 + tc * 4];
      float av[4] = {a.x, a.y, a.z, a.w};
      float bv[8] = {b0.x, b0.y, b0.z, b0.w, b1.x, b1.y, b1.z, b1.w};
#pragma unroll
      for (int i = 0; i < 4; i++)
#pragma unroll
        for (int j = 0; j < 8; j++) acc[i][j] += av[i] * bv[j];
    }
    __syncthreads();
  }
#pragma unroll
  for (int i = 0; i < 4; i++) {
    int r = r0 + tr * 4 + i;
    if (r >= n) break;
    float rs = rowscale ? rowscale[(size_t)r * rsStride] : 1.f;
    float vals[8];
#pragma unroll
    for (int j = 0; j < 4; j++) {
      float v0 = acc[i][j] * rs + bias[tc * 4 + j];
      float v1 = acc[i][j + 4] * rs + bias[64 + tc * 4 + j];
      if (relu) { v0 = fmaxf(v0, 0.f); v1 = fmaxf(v1, 0.f); }
      vals[j] = v0; vals[4 + j] = v1;
    }
    *(float4*)(out + (size_t)r * 128 + tc * 4) = *(float4*)&vals[0];
    *(float4*)(out + (size_t)r * 128 + 64 + tc * 4) = *(float4*)&vals[4];
  }
}

// ===================== GCN aggregation (gather over CSR-by-destination) =====================
// 2 nodes per block (256 threads), edge loop unrolled x4.

__global__ __launch_bounds__(256) void prop_kernel(
    const float* __restrict__ z, const int* __restrict__ ptr,
    const int* __restrict__ src, const float* __restrict__ wn,
    const float* __restrict__ dinv, const float* __restrict__ bias,
    float* __restrict__ out, int n, int relu) {
  int node = blockIdx.x * 2 + (threadIdx.x >> 7);
  if (node >= n) return;
  int j = threadIdx.x & 127;
  float dn = dinv[node];
  float acc = dn * dn * z[(size_t)node * HD + j];  // self loop, weight 1
  int e = ptr[node], e1 = ptr[node + 1];
  for (; e + 3 < e1; e += 4) {
    int s0 = src[e], s1 = src[e + 1], s2 = src[e + 2], s3 = src[e + 3];
    float w0 = wn[e], w1 = wn[e + 1], w2 = wn[e + 2], w3 = wn[e + 3];
    float z0 = z[(size_t)s0 * HD + j];
    float z1 = z[(size_t)s1 * HD + j];
    float z2 = z[(size_t)s2 * HD + j];
    float z3 = z[(size_t)s3 * HD + j];
    acc += w0 * z0 + w1 * z1 + w2 * z2 + w3 * z3;
  }
  for (; e < e1; e++) acc += wn[e] * z[(size_t)src[e] * HD + j];
  acc += bias[j];
  if (relu) acc = fmaxf(acc, 0.f);
  out[(size_t)node * HD + j] = acc;
}

// ===================== attention projections =====================

__global__ void proj_kernel(const float* __restrict__ h, const float* __restrict__ We,
                            const float* __restrict__ Wn, const float* __restrict__ bn,
                            float* __restrict__ natt, float* __restrict__ pe, int n) {
  int gtid = blockIdx.x * blockDim.x + threadIdx.x;
  int wave = gtid >> 6;
  int lane = threadIdx.x & 63;
  int nwaves = (gridDim.x * blockDim.x) >> 6;
  for (int node = wave; node < n; node += nwaves) {
    float h0 = h[(size_t)node * HD + lane];
    float h1 = h[(size_t)node * HD + 64 + lane];
    float v[6];
    v[0] = h0 * We[lane * 2 + 0] + h1 * We[(64 + lane) * 2 + 0];
    v[1] = h0 * We[lane * 2 + 1] + h1 * We[(64 + lane) * 2 + 1];
    v[2] = h0 * We[(128 + lane) * 2 + 0] + h1 * We[(192 + lane) * 2 + 0];
    v[3] = h0 * We[(128 + lane) * 2 + 1] + h1 * We[(192 + lane) * 2 + 1];
    v[4] = h0 * Wn[lane * 2 + 0] + h1 * Wn[(64 + lane) * 2 + 0];
    v[5] = h0 * Wn[lane * 2 + 1] + h1 * Wn[(64 + lane) * 2 + 1];
#pragma unroll
    for (int m = 32; m > 0; m >>= 1) {
#pragma unroll
      for (int q = 0; q < 6; q++) v[q] += __shfl_xor(v[q], m, 64);
    }
    if (lane == 0) {
      float q0 = v[4] + bn[0], q1 = v[5] + bn[1];
      float mx = fmaxf(q0, q1);
      float e0 = expf(q0 - mx), e1 = expf(q1 - mx);
      float inv = 1.f / (e0 + e1);
      natt[node * 2 + 0] = e0 * inv;
      natt[node * 2 + 1] = e1 * inv;
      pe[node * 4 + 0] = v[0];
      pe[node * 4 + 1] = v[1];
      pe[node * 4 + 2] = v[2];
      pe[node * 4 + 3] = v[3];
    }
  }
}

__global__ void eatt_kernel(const int* __restrict__ row, const int* __restrict__ col,
                            const float* __restrict__ pe, const float* __restrict__ be,
                            float* __restrict__ eatt, float* __restrict__ degc,
                            float* __restrict__ dego, int e) {
  int i = blockIdx.x * blockDim.x + threadIdx.x;
  if (i >= e) return;
  int r = row[i], c = col[i];
  float l0 = pe[r * 4 + 0] + pe[c * 4 + 2] + be[0];
  float l1 = pe[r * 4 + 1] + pe[c * 4 + 3] + be[1];
  float m = fmaxf(l0, l1);
  float e0 = expf(l0 - m), e1 = expf(l1 - m);
  float inv = 1.f / (e0 + e1);
  e0 *= inv; e1 *= inv;
  eatt[i * 2 + 0] = e0;
  eatt[i * 2 + 1] = e1;
  atomicAdd(&degc[r], e0);
  atomicAdd(&dego[r], e1);
}

// ===================== pooling (batch sorted; chunked, atomic flush) =====================

#define POOL_RPB 32

__global__ void pool_kernel(const float* __restrict__ xc, const float* __restrict__ xo,
                            const int* __restrict__ batch, int n,
                            float* __restrict__ pc, float* __restrict__ po) {
  int j = threadIdx.x;  // 128
  int r0 = blockIdx.x * POOL_RPB;
  int r1 = min(n, r0 + POOL_RPB);
  if (r0 >= n) return;
  int g = batch[r0];
  float ac = 0.f, ao = 0.f;
  for (int r = r0; r < r1; r++) {
    int br = batch[r];
    if (br != g) {
      atomicAdd(&pc[g * HD + j], ac);
      atomicAdd(&po[g * HD + j], ao);
      ac = 0.f; ao = 0.f; g = br;
    }
    ac += xc[(size_t)r * HD + j];
    ao += xo[(size_t)r * HD + j];
  }
  atomicAdd(&pc[g * HD + j], ac);
  atomicAdd(&po[g * HD + j], ao);
}

// ===================== readout heads (G=128 rows, all in LDS) =====================

__global__ __launch_bounds__(512) void head_kernel(
    const float* __restrict__ pc, const float* __restrict__ po,
    const float* __restrict__ bn1g, const float* __restrict__ bn1b,
    const float* __restrict__ W1, const float* __restrict__ b1,
    const float* __restrict__ bn2g, const float* __restrict__ bn2b,
    const float* __restrict__ W2, const float* __restrict__ b2,
    float* __restrict__ out) {
  int t = blockIdx.x;  // head 0,1,2
  __shared__ float V[128][129];
  __shared__ float Y[128][129];
  __shared__ float Z[128][12];
  __shared__ float sA[128], tA[128];
  __shared__ float redS[4][129], redQ[4][129];
  int tid = threadIdx.x, nt = blockDim.x;
  int cj = tid & 127, ch = tid >> 7;  // col, row-chunk(0..3)
  for (int idx = tid; idx < 16384; idx += nt) {
    int r = idx >> 7, j = idx & 127;
    float v = (t == 0) ? pc[idx] : (t == 1) ? po[idx] : (pc[idx] + po[idx]);
    V[r][j] = v;
  }
  __syncthreads();
  {
    float s = 0.f, q = 0.f;
    for (int r = ch * 32; r < ch * 32 + 32; r++) { float v = V[r][cj]; s += v; q += v * v; }
    redS[ch][cj] = s; redQ[ch][cj] = q;
  }
  __syncthreads();
  if (tid < 128) {
    float s = redS[0][tid] + redS[1][tid] + redS[2][tid] + redS[3][tid];
    float q = redQ[0][tid] + redQ[1][tid] + redQ[2][tid] + redQ[3][tid];
    float m = s * (1.f / 128.f), var = q * (1.f / 128.f) - m * m;
    float sc = bn1g[t * 128 + tid] * rsqrtf(var + 1e-5f);
    sA[tid] = sc; tA[tid] = bn1b[t * 128 + tid] - m * sc;
  }
  __syncthreads();
  for (int idx = tid; idx < 16384; idx += nt) {
    int r = idx >> 7, j = idx & 127;
    V[r][j] = V[r][j] * sA[j] + tA[j];
  }
  __syncthreads();
  for (int idx = tid; idx < 16384; idx += nt) {
    int r = idx >> 7, j = idx & 127;
    float acc = b1[t * 128 + j];
    for (int k = 0; k < 128; k++) acc += V[r][k] * W1[(size_t)t * 16384 + k * 128 + j];
    Y[r][j] = fmaxf(acc, 0.f);
  }
  __syncthreads();
  {
    float s = 0.f, q = 0.f;
    for (int r = ch * 32; r < ch * 32 + 32; r++) { float v = Y[r][cj]; s += v; q += v * v; }
    redS[ch][cj] = s; redQ[ch][cj] = q;
  }
  __syncthreads();
  if (tid < 128) {
    float s = redS[0][tid] + redS[1][tid] + redS[2][tid] + redS[3][tid];
    float q = redQ[0][tid] + redQ[1][tid] + redQ[2][tid] + redQ[3][tid];
    float m = s * (1.f / 128.f), var = q * (1.f / 128.f) - m * m;
    float sc = bn2g[t * 128 + tid] * rsqrtf(var + 1e-5f);
    sA[tid] = sc; tA[tid] = bn2b[t * 128 + tid] - m * sc;
  }
  __syncthreads();
  for (int idx = tid; idx < 16384; idx += nt) {
    int r = idx >> 7, j = idx & 127;
    Y[r][j] = Y[r][j] * sA[j] + tA[j];
  }
  __syncthreads();
  for (int idx = tid; idx < 1280; idx += nt) {
    int r = idx / 10, c = idx % 10;
    float acc = b2[t * 10 + c];
    for (int k = 0; k < 128; k++) acc += Y[r][k] * W2[(size_t)t * 1280 + k * 10 + c];
    Z[r][c] = acc;
  }
  __syncthreads();
  if (tid < 128) {
    int r = tid;
    float m = -1e30f;
    for (int c = 0; c < 10; c++) m = fmaxf(m, Z[r][c]);
    float se = 0.f;
    for (int c = 0; c < 10; c++) se += expf(Z[r][c] - m);
    float lse = m + logf(se);
    for (int c = 0; c < 10; c++) out[t * 1280 + r * 10 + c] = Z[r][c] - lse;
  }
}

// ===================== launch =====================

extern "C" void kernel_launch(void* const* d_in, const int* in_sizes, int n_in,
                              void* d_out, int out_size, void* d_ws, size_t ws_size,
                              hipStream_t stream) {
  const int N = in_sizes[0] / HD;    // 40000
  const int E = in_sizes[1] / 2;     // 480000
  const int G = out_size / 30;       // 128

  const float* x      = (const float*)d_in[0];
  const int*   ei     = (const int*)d_in[1];
  const int*   batch  = (const int*)d_in[2];
  const float* bnfg   = (const float*)d_in[3];
  const float* bnfb   = (const float*)d_in[4];
  const float* Wfeat  = (const float*)d_in[5];
  const float* bnsg   = (const float*)d_in[6];
  const float* bnsb   = (const float*)d_in[7];
  const float* convW  = (const float*)d_in[8];
  const float* convb  = (const float*)d_in[9];
  const float* Weatt  = (const float*)d_in[10];
  const float* beatt  = (const float*)d_in[11];
  const float* Wnatt  = (const float*)d_in[12];
  const float* bnatt  = (const float*)d_in[13];
  const float* bncg   = (const float*)d_in[14];
  const float* bncb   = (const float*)d_in[15];
  const float* bnog   = (const float*)d_in[16];
  const float* bnob   = (const float*)d_in[17];
  const float* Wc     = (const float*)d_in[18];
  const float* bc     = (const float*)d_in[19];
  const float* Wo     = (const float*)d_in[20];
  const float* bo     = (const float*)d_in[21];
  const float* robn1g = (const float*)d_in[22];
  const float* robn1b = (const float*)d_in[23];
  const float* roW1   = (const float*)d_in[24];
  const float* rob1   = (const float*)d_in[25];
  const float* robn2g = (const float*)d_in[26];
  const float* robn2b = (const float*)d_in[27];
  const float* roW2   = (const float*)d_in[28];
  const float* rob2   = (const float*)d_in[29];
  float* out = (float*)d_out;

  const int* row = ei;
  const int* col = ei + E;

  char* p = (char*)d_ws;
  auto alloc = [&](size_t bytes) -> void* {
    void* r = (void*)p;
    p += (bytes + 255) & ~(size_t)255;
    return r;
  };
  float* B0      = (float*)alloc((size_t)N * HD * 4);
  float* B1      = (float*)alloc((size_t)N * HD * 4);
  float* B2      = (float*)alloc((size_t)N * HD * 4);
  float* B3      = (float*)alloc((size_t)N * HD * 4);
  float* eatt    = (float*)alloc((size_t)E * 2 * 4);
  int*   csr_src = (int*)alloc((size_t)E * 4);
  int*   csr_eid = (int*)alloc((size_t)E * 4);
  float* wn1     = (float*)alloc((size_t)E * 4);
  float* wnc     = (float*)alloc((size_t)E * 4);
  float* wno     = (float*)alloc((size_t)E * 4);
  int*   ptrA    = (int*)alloc((size_t)(N + 1) * 4);
  int*   cursor  = (int*)alloc((size_t)N * 4);
  int*   cnt_in  = (int*)alloc((size_t)N * 4);
  int*   outdeg  = (int*)alloc((size_t)N * 4);
  float* dinv1   = (float*)alloc((size_t)N * 4);
  float* degc    = (float*)alloc((size_t)N * 4);
  float* dego    = (float*)alloc((size_t)N * 4);
  float* natt    = (float*)alloc((size_t)N * 2 * 4);
  float* pe      = (float*)alloc((size_t)N * 4 * 4);
  float* stats   = (float*)alloc(12 * HD * 4);   // x(2), h0..h2(2 each), co(4)
  float* Wbuf    = (float*)alloc(HD * HD * 4);
  float* bbuf    = (float*)alloc(HD * 4);
  float* pooledc = (float*)alloc((size_t)G * HD * 4);
  float* pooledo = (float*)alloc((size_t)G * HD * 4);
  int*   csums   = (int*)alloc(64 * 4);
  int*   coffs   = (int*)alloc(64 * 4);

  const int NCH = (N + 1023) / 1024;  // scan chunks

  // ---- init accumulators ----
  hipMemsetAsync(cnt_in, 0, (size_t)N * 4, stream);
  hipMemsetAsync(outdeg, 0, (size_t)N * 4, stream);
  hipMemsetAsync(stats, 0, 12 * HD * 4, stream);
  hipMemsetAsync(pooledc, 0, (size_t)G * HD * 4, stream);
  hipMemsetAsync(pooledo, 0, (size_t)G * HD * 4, stream);
  fill_ones2<<<(N + 255) / 256, 256, 0, stream>>>(degc, dego, N);

  // ---- CSR by destination + unweighted norms ----
  hist_kernel<<<(E + 255) / 256, 256, 0, stream>>>(row, col, cnt_in, outdeg, E);
  scan1<<<NCH, 256, 0, stream>>>(cnt_in, N, csums);
  scan2<<<1, 64, 0, stream>>>(csums, NCH, coffs);
  scan3<<<NCH, 256, 0, stream>>>(cnt_in, N, coffs, ptrA, cursor);
  place_kernel<<<(E + 255) / 256, 256, 0, stream>>>(row, col, cursor, csr_src, csr_eid, E);
  dinv1_kernel<<<(N + 255) / 256, 256, 0, stream>>>(outdeg, dinv1, N);
  build_wnorm1<<<N, 64, 0, stream>>>(ptrA, csr_src, dinv1, wn1);

  const int SB = 512;
  int rpb = (N + SB - 1) / SB;
  int gblocks = (N + 63) / 64;
  int pblocks = (N + 1) / 2;
  float invN = 1.f / (float)N;

  // ---- feature BN + gfn linear + relu ----
  colstats<<<SB, 256, 0, stream>>>(x, N, rpb, stats, stats + HD);
  fold_bn<<<1, 128, 0, stream>>>(Wfeat, bnfg, bnfb, stats, stats + HD, invN, Wbuf, bbuf);
  gemm128<<<gblocks, 256, 0, stream>>>(x, Wbuf, bbuf, nullptr, 0, B0, N, 1);

  // ---- 3 GCN conv layers ----
  for (int i = 0; i < 3; i++) {
    float* hs = stats + 2 * HD + i * 2 * HD;
    colstats<<<SB, 256, 0, stream>>>(B0, N, rpb, hs, hs + HD);
    fold_bn<<<1, 128, 0, stream>>>(convW + (size_t)i * HD * HD, bnsg + i * HD, bnsb + i * HD,
                                   hs, hs + HD, invN, Wbuf, bbuf);
    gemm128<<<gblocks, 256, 0, stream>>>(B0, Wbuf, bbuf, nullptr, 0, B1, N, 0);
    prop_kernel<<<pblocks, 256, 0, stream>>>(B1, ptrA, csr_src, wn1, dinv1, convb + i * HD, B0, N, 1);
  }

  // ---- attention ----
  proj_kernel<<<512, 256, 0, stream>>>(B0, Weatt, Wnatt, bnatt, natt, pe, N);
  eatt_kernel<<<(E + 255) / 256, 256, 0, stream>>>(row, col, pe, beatt, eatt, degc, dego, E);
  dinvw_kernel<<<(N + 255) / 256, 256, 0, stream>>>(degc, dego, N);
  build_wnormco<<<N, 64, 0, stream>>>(ptrA, csr_src, csr_eid, eatt, degc, dego, wnc, wno);

  // ---- xc / xo paths: stats of a0*h, a1*h, fold BN, GEMM with row scale ----
  float* cs = stats + 8 * HD;
  colstats_scaled<<<SB, 256, 0, stream>>>(B0, natt, N, rpb, cs);
  fold_bn<<<1, 128, 0, stream>>>(Wc, bncg, bncb, cs, cs + HD, invN, Wbuf, bbuf);
  gemm128<<<gblocks, 256, 0, stream>>>(B0, Wbuf, bbuf, natt, 2, B1, N, 0);      // zc
  fold_bn<<<1, 128, 0, stream>>>(Wo, bnog, bnob, cs + 2 * HD, cs + 3 * HD, invN, Wbuf, bbuf);
  gemm128<<<gblocks, 256, 0, stream>>>(B0, Wbuf, bbuf, natt + 1, 2, B2, N, 0);  // zo

  prop_kernel<<<pblocks, 256, 0, stream>>>(B1, ptrA, csr_src, wnc, degc, bc, B3, N, 1);  // xc_out
  prop_kernel<<<pblocks, 256, 0, stream>>>(B2, ptrA, csr_src, wno, dego, bo, B1, N, 1);  // xo_out

  // ---- pool + heads ----
  pool_kernel<<<(N + POOL_RPB - 1) / POOL_RPB, 128, 0, stream>>>(B3, B1, batch, N, pooledc, pooledo);
  head_kernel<<<3, 512, 0, stream>>>(pooledc, pooledo, robn1g, robn1b, roW1, rob1,
                                     robn2g, robn2b, roW2, rob2, out);
}

// Round 3
// 943.953 us; speedup vs baseline: 1.3235x; 1.0862x over previous
//
#include <hip/hip_runtime.h>

#define HD 128

// ===================== graph preprocessing =====================

__global__ void fill_ones2(float* a, float* b, int n) {
  int i = blockIdx.x * blockDim.x + threadIdx.x;
  if (i < n) { a[i] = 1.f; b[i] = 1.f; }
}

__global__ void hist_kernel(const int* __restrict__ row, const int* __restrict__ col,
                            int* __restrict__ cnt_in, int* __restrict__ outdeg, int e) {
  int i = blockIdx.x * blockDim.x + threadIdx.x;
  if (i < e) { atomicAdd(&cnt_in[col[i]], 1); atomicAdd(&outdeg[row[i]], 1); }
}

// ---- 3-stage scan over cnt[n] -> ptr[n+1], cursor[n] ----

__global__ void scan1(const int* __restrict__ cnt, int n, int* __restrict__ sums) {
  __shared__ int lds[256];
  int b = blockIdx.x, t = threadIdx.x;
  int base = b * 1024 + t * 4;
  int s = 0;
#pragma unroll
  for (int m = 0; m < 4; m++) if (base + m < n) s += cnt[base + m];
  lds[t] = s;
  __syncthreads();
  for (int d = 128; d > 0; d >>= 1) {
    if (t < d) lds[t] += lds[t + d];
    __syncthreads();
  }
  if (t == 0) sums[b] = lds[0];
}

__global__ void scan2(const int* __restrict__ sums, int nc, int* __restrict__ off) {
  int l = threadIdx.x;
  int v = (l < nc) ? sums[l] : 0;
  int x = v;
#pragma unroll
  for (int d = 1; d < 64; d <<= 1) {
    int y = __shfl_up(x, d, 64);
    if (l >= d) x += y;
  }
  if (l < nc) off[l] = x - v;  // exclusive
}

__global__ void scan3(const int* __restrict__ cnt, int n, const int* __restrict__ off,
                      int* __restrict__ ptr, int* __restrict__ cursor) {
  __shared__ int lds[256];
  int b = blockIdx.x, t = threadIdx.x;
  int base = b * 1024 + t * 4;
  int v[4], p[4];
#pragma unroll
  for (int m = 0; m < 4; m++) v[m] = (base + m < n) ? cnt[base + m] : 0;
  p[0] = v[0];
#pragma unroll
  for (int m = 1; m < 4; m++) p[m] = p[m - 1] + v[m];
  int tsum = p[3];
  lds[t] = tsum;
  __syncthreads();
  for (int d = 1; d < 256; d <<= 1) {
    int y = 0;
    if (t >= d) y = lds[t - d];
    __syncthreads();
    lds[t] += y;
    __syncthreads();
  }
  int basev = off[b] + lds[t] - tsum;  // exclusive thread base
  if (b == 0 && t == 0) ptr[0] = 0;
#pragma unroll
  for (int m = 0; m < 4; m++) {
    int i = base + m;
    if (i < n) {
      int incl = basev + p[m];
      ptr[i + 1] = incl;
      cursor[i] = incl - v[m];
    }
  }
}

__global__ void place_kernel(const int* __restrict__ row, const int* __restrict__ col,
                             int* __restrict__ cursor, int* __restrict__ csr_src,
                             int* __restrict__ csr_eid, int e) {
  int i = blockIdx.x * blockDim.x + threadIdx.x;
  if (i < e) {
    int c = col[i];
    int pos = atomicAdd(&cursor[c], 1);
    csr_src[pos] = row[i];
    csr_eid[pos] = i;
  }
}

__global__ void dinv1_kernel(const int* __restrict__ outdeg, float* __restrict__ dinv1, int n) {
  int i = blockIdx.x * blockDim.x + threadIdx.x;
  if (i < n) dinv1[i] = rsqrtf((float)(outdeg[i] + 1));
}

__global__ void build_wnorm1(const int* __restrict__ ptr, const int* __restrict__ src,
                             const float* __restrict__ dinv1, float* __restrict__ wn) {
  int n = blockIdx.x;
  float dn = dinv1[n];
  int e1 = ptr[n + 1];
  for (int e = ptr[n] + threadIdx.x; e < e1; e += blockDim.x)
    wn[e] = dinv1[src[e]] * dn;
}

__global__ void dinvw_kernel(float* a, float* b, int n) {
  int i = blockIdx.x * blockDim.x + threadIdx.x;
  if (i < n) { a[i] = rsqrtf(a[i]); b[i] = rsqrtf(b[i]); }
}

__global__ void build_wnormco(const int* __restrict__ ptr, const int* __restrict__ src,
                              const int* __restrict__ eid, const float* __restrict__ eatt,
                              const float* __restrict__ dc, const float* __restrict__ dd,
                              float* __restrict__ wc, float* __restrict__ wo) {
  int n = blockIdx.x;
  float dcn = dc[n], don = dd[n];
  int e1 = ptr[n + 1];
  for (int e = ptr[n] + threadIdx.x; e < e1; e += blockDim.x) {
    int s = src[e]; int id = eid[e];
    wc[e] = dc[s] * eatt[id * 2 + 0] * dcn;
    wo[e] = dd[s] * eatt[id * 2 + 1] * don;
  }
}

// ===================== BN stats =====================

__global__ void colstats(const float* __restrict__ A, int n, int rpb,
                         float* __restrict__ sum, float* __restrict__ sumsq) {
  int colj = threadIdx.x & (HD - 1);
  int half = threadIdx.x >> 7;
  int r0 = blockIdx.x * rpb;
  int r1 = min(n, r0 + rpb);
  float s = 0.f, q = 0.f;
  for (int r = r0 + half; r < r1; r += 2) {
    float v = A[(size_t)r * HD + colj];
    s += v; q += v * v;
  }
  atomicAdd(&sum[colj], s);
  atomicAdd(&sumsq[colj], q);
}

__global__ void colstats_scaled(const float* __restrict__ A, const float* __restrict__ natt,
                                int n, int rpb, float* __restrict__ o4) {
  int colj = threadIdx.x & (HD - 1);
  int half = threadIdx.x >> 7;
  int r0 = blockIdx.x * rpb;
  int r1 = min(n, r0 + rpb);
  float sc = 0.f, qc = 0.f, so = 0.f, qo = 0.f;
  for (int r = r0 + half; r < r1; r += 2) {
    float v = A[(size_t)r * HD + colj];
    float a0 = natt[r * 2], a1 = natt[r * 2 + 1];
    float vc = a0 * v, vo = a1 * v;
    sc += vc; qc += vc * vc; so += vo; qo += vo * vo;
  }
  atomicAdd(&o4[colj], sc);
  atomicAdd(&o4[HD + colj], qc);
  atomicAdd(&o4[2 * HD + colj], so);
  atomicAdd(&o4[3 * HD + colj], qo);
}

// ===================== GEMM with fused BN-fold =====================
// bn(a) = a*s + t, s = g*rsqrt(var+eps), t = b - m*s
// out[r,:] = rs(r) * ((A[r,:] o s) @ W) + t @ W    (rs optional)

__global__ __launch_bounds__(256) void gemm128(
    const float* __restrict__ A, const float* __restrict__ W,
    const float* __restrict__ g, const float* __restrict__ b,
    const float* __restrict__ ssum, const float* __restrict__ ssq, float invN,
    const float* __restrict__ rowscale, int rsStride,
    float* __restrict__ out, int n, int relu) {
  __shared__ float As[32][68];    // [k][row], padded
  __shared__ float Ws[32][132];   // [k][j], padded
  __shared__ float sA[HD], tA[HD], tb[HD];
  int tid = threadIdx.x;
  int r0 = blockIdx.x * 64;
  int tr = tid >> 4, tc = tid & 15;

  if (tid < HD) {
    float m = ssum[tid] * invN;
    float v = ssq[tid] * invN - m * m;
    float s = g[tid] * rsqrtf(v + 1e-5f);
    sA[tid] = s;
    tA[tid] = b[tid] - m * s;
  }
  __syncthreads();
  if (tid < HD) {  // bias = t @ W, coalesced column walk
    float acc = 0.f;
#pragma unroll 8
    for (int k = 0; k < HD; k++) acc += tA[k] * W[k * HD + tid];
    tb[tid] = acc;
  }

  float acc[4][8];
#pragma unroll
  for (int i = 0; i < 4; i++)
#pragma unroll
    for (int j = 0; j < 8; j++) acc[i][j] = 0.f;

  for (int kk = 0; kk < 128; kk += 32) {
#pragma unroll
    for (int i = 0; i < 2; i++) {           // A tile 64x32, transposed + s-folded
      int f = tid + i * 256;
      int rloc = f >> 3;
      int kc = (f & 7) * 4;
      int gr = r0 + rloc;
      float4 v = make_float4(0.f, 0.f, 0.f, 0.f);
      if (gr < n) v = *(const float4*)(A + (size_t)gr * 128 + kk + kc);
      As[kc + 0][rloc] = v.x * sA[kk + kc + 0];
      As[kc + 1][rloc] = v.y * sA[kk + kc + 1];
      As[kc + 2][rloc] = v.z * sA[kk + kc + 2];
      As[kc + 3][rloc] = v.w * sA[kk + kc + 3];
    }
#pragma unroll
    for (int i = 0; i < 4; i++) {           // W tile 32x128
      int f = tid + i * 256;
      int krow = f >> 5;
      int jc = (f & 31) * 4;
      *(float4*)&Ws[krow][jc] = *(const float4*)(W + (size_t)(kk + krow) * 128 + jc);
    }
    __syncthreads();
#pragma unroll
    for (int k = 0; k < 32; k++) {
      float4 a = *(float4*)&As[k][tr * 4];
      float4 b0 = *(float4*)&Ws[k][tc * 4];
      float4 b1 = *(float4*)&Ws[k][64 + tc * 4];
      float av[4] = {a.x, a.y, a.z, a.w};
      float bv[8] = {b0.x, b0.y, b0.z, b0.w, b1.x, b1.y, b1.z, b1.w};
#pragma unroll
      for (int i = 0; i < 4; i++)
#pragma unroll
        for (int j = 0; j < 8; j++) acc[i][j] += av[i] * bv[j];
    }
    __syncthreads();
  }
#pragma unroll
  for (int i = 0; i < 4; i++) {
    int r = r0 + tr * 4 + i;
    if (r >= n) break;
    float rs = rowscale ? rowscale[(size_t)r * rsStride] : 1.f;
    float vals[8];
#pragma unroll
    for (int j = 0; j < 4; j++) {
      float v0 = acc[i][j] * rs + tb[tc * 4 + j];
      float v1 = acc[i][j + 4] * rs + tb[64 + tc * 4 + j];
      if (relu) { v0 = fmaxf(v0, 0.f); v1 = fmaxf(v1, 0.f); }
      vals[j] = v0; vals[4 + j] = v1;
    }
    *(float4*)(out + (size_t)r * 128 + tc * 4) = *(float4*)&vals[0];
    *(float4*)(out + (size_t)r * 128 + 64 + tc * 4) = *(float4*)&vals[4];
  }
}

// ===================== GCN aggregation (gather over CSR-by-destination) =====================

__global__ __launch_bounds__(256) void prop_kernel(
    const float* __restrict__ z, const int* __restrict__ ptr,
    const int* __restrict__ src, const float* __restrict__ wn,
    const float* __restrict__ dinv, const float* __restrict__ bias,
    float* __restrict__ out, int n, int relu) {
  int node = blockIdx.x * 2 + (threadIdx.x >> 7);
  if (node >= n) return;
  int j = threadIdx.x & 127;
  float dn = dinv[node];
  float acc = dn * dn * z[(size_t)node * HD + j];  // self loop, weight 1
  int e = ptr[node], e1 = ptr[node + 1];
  for (; e + 3 < e1; e += 4) {
    int s0 = src[e], s1 = src[e + 1], s2 = src[e + 2], s3 = src[e + 3];
    float w0 = wn[e], w1 = wn[e + 1], w2 = wn[e + 2], w3 = wn[e + 3];
    float z0 = z[(size_t)s0 * HD + j];
    float z1 = z[(size_t)s1 * HD + j];
    float z2 = z[(size_t)s2 * HD + j];
    float z3 = z[(size_t)s3 * HD + j];
    acc += w0 * z0 + w1 * z1 + w2 * z2 + w3 * z3;
  }
  for (; e < e1; e++) acc += wn[e] * z[(size_t)src[e] * HD + j];
  acc += bias[j];
  if (relu) acc = fmaxf(acc, 0.f);
  out[(size_t)node * HD + j] = acc;
}

// ===================== attention projections =====================

__global__ void proj_kernel(const float* __restrict__ h, const float* __restrict__ We,
                            const float* __restrict__ Wn, const float* __restrict__ bn,
                            float* __restrict__ natt, float* __restrict__ pe, int n) {
  int gtid = blockIdx.x * blockDim.x + threadIdx.x;
  int wave = gtid >> 6;
  int lane = threadIdx.x & 63;
  int nwaves = (gridDim.x * blockDim.x) >> 6;
  for (int node = wave; node < n; node += nwaves) {
    float h0 = h[(size_t)node * HD + lane];
    float h1 = h[(size_t)node * HD + 64 + lane];
    float v[6];
    v[0] = h0 * We[lane * 2 + 0] + h1 * We[(64 + lane) * 2 + 0];
    v[1] = h0 * We[lane * 2 + 1] + h1 * We[(64 + lane) * 2 + 1];
    v[2] = h0 * We[(128 + lane) * 2 + 0] + h1 * We[(192 + lane) * 2 + 0];
    v[3] = h0 * We[(128 + lane) * 2 + 1] + h1 * We[(192 + lane) * 2 + 1];
    v[4] = h0 * Wn[lane * 2 + 0] + h1 * Wn[(64 + lane) * 2 + 0];
    v[5] = h0 * Wn[lane * 2 + 1] + h1 * Wn[(64 + lane) * 2 + 1];
#pragma unroll
    for (int m = 32; m > 0; m >>= 1) {
#pragma unroll
      for (int q = 0; q < 6; q++) v[q] += __shfl_xor(v[q], m, 64);
    }
    if (lane == 0) {
      float q0 = v[4] + bn[0], q1 = v[5] + bn[1];
      float mx = fmaxf(q0, q1);
      float e0 = expf(q0 - mx), e1 = expf(q1 - mx);
      float inv = 1.f / (e0 + e1);
      natt[node * 2 + 0] = e0 * inv;
      natt[node * 2 + 1] = e1 * inv;
      pe[node * 4 + 0] = v[0];
      pe[node * 4 + 1] = v[1];
      pe[node * 4 + 2] = v[2];
      pe[node * 4 + 3] = v[3];
    }
  }
}

__global__ void eatt_kernel(const int* __restrict__ row, const int* __restrict__ col,
                            const float* __restrict__ pe, const float* __restrict__ be,
                            float* __restrict__ eatt, float* __restrict__ degc,
                            float* __restrict__ dego, int e) {
  int i = blockIdx.x * blockDim.x + threadIdx.x;
  if (i >= e) return;
  int r = row[i], c = col[i];
  float l0 = pe[r * 4 + 0] + pe[c * 4 + 2] + be[0];
  float l1 = pe[r * 4 + 1] + pe[c * 4 + 3] + be[1];
  float m = fmaxf(l0, l1);
  float e0 = expf(l0 - m), e1 = expf(l1 - m);
  float inv = 1.f / (e0 + e1);
  e0 *= inv; e1 *= inv;
  eatt[i * 2 + 0] = e0;
  eatt[i * 2 + 1] = e1;
  atomicAdd(&degc[r], e0);
  atomicAdd(&dego[r], e1);
}

// ===================== pooling (batch sorted; chunked, atomic flush) =====================

#define POOL_RPB 32

__global__ void pool_kernel(const float* __restrict__ xc, const float* __restrict__ xo,
                            const int* __restrict__ batch, int n,
                            float* __restrict__ pc, float* __restrict__ po) {
  int j = threadIdx.x;  // 128
  int r0 = blockIdx.x * POOL_RPB;
  int r1 = min(n, r0 + POOL_RPB);
  if (r0 >= n) return;
  int g = batch[r0];
  float ac = 0.f, ao = 0.f;
  for (int r = r0; r < r1; r++) {
    int br = batch[r];
    if (br != g) {
      atomicAdd(&pc[g * HD + j], ac);
      atomicAdd(&po[g * HD + j], ao);
      ac = 0.f; ao = 0.f; g = br;
    }
    ac += xc[(size_t)r * HD + j];
    ao += xo[(size_t)r * HD + j];
  }
  atomicAdd(&pc[g * HD + j], ac);
  atomicAdd(&po[g * HD + j], ao);
}

// ===================== readout heads =====================
// head1: grid = 3 heads x 4 col-tiles; Y[t] = relu(bn1(V) @ W1[t] + b1[t]) -> Ybuf
// head2: grid = 3 heads; out[t] = log_softmax(bn2(Y) @ W2[t] + b2[t])

__global__ __launch_bounds__(256) void head1(
    const float* __restrict__ pc, const float* __restrict__ po,
    const float* __restrict__ bn1g, const float* __restrict__ bn1b,
    const float* __restrict__ W1, const float* __restrict__ b1,
    float* __restrict__ Ybuf) {
  int t = blockIdx.x >> 2;
  int jt = blockIdx.x & 3;          // 32-col tile
  __shared__ float V[128][132];
  __shared__ float Wt[128][33];
  __shared__ float sA[128], tA[128];
  __shared__ float redS[2][128], redQ[2][128];
  int tid = threadIdx.x;

  for (int idx = tid; idx < 16384; idx += 256) {
    int r = idx >> 7, j = idx & 127;
    float v = (t == 0) ? pc[idx] : (t == 1) ? po[idx] : (pc[idx] + po[idx]);
    V[r][j] = v;
  }
  for (int idx = tid; idx < 4096; idx += 256) {
    int k = idx >> 5, c = idx & 31;
    Wt[k][c] = W1[(size_t)t * 16384 + k * 128 + jt * 32 + c];
  }
  __syncthreads();
  {
    int cj = tid & 127, ch = tid >> 7;
    float s = 0.f, q = 0.f;
    for (int r = ch * 64; r < ch * 64 + 64; r++) { float v = V[r][cj]; s += v; q += v * v; }
    redS[ch][cj] = s; redQ[ch][cj] = q;
  }
  __syncthreads();
  if (tid < 128) {
    float s = redS[0][tid] + redS[1][tid];
    float q = redQ[0][tid] + redQ[1][tid];
    float m = s * (1.f / 128.f), var = q * (1.f / 128.f) - m * m;
    float sc = bn1g[t * 128 + tid] * rsqrtf(var + 1e-5f);
    sA[tid] = sc; tA[tid] = bn1b[t * 128 + tid] - m * sc;
  }
  __syncthreads();
  for (int idx = tid; idx < 16384; idx += 256) {
    int r = idx >> 7, j = idx & 127;
    V[r][j] = V[r][j] * sA[j] + tA[j];
  }
  __syncthreads();
  // GEMM: 128 rows x 32 cols; thread -> 16 rows, 1 col
  int tr = tid >> 5, tc = tid & 31;
  float acc[16];
#pragma unroll
  for (int i = 0; i < 16; i++) acc[i] = 0.f;
  for (int k = 0; k < 128; k += 4) {
    float w0 = Wt[k][tc], w1 = Wt[k + 1][tc], w2 = Wt[k + 2][tc], w3 = Wt[k + 3][tc];
#pragma unroll
    for (int i = 0; i < 16; i++) {
      float4 v = *(float4*)&V[tr * 16 + i][k];
      acc[i] += v.x * w0 + v.y * w1 + v.z * w2 + v.w * w3;
    }
  }
  float bj = b1[t * 128 + jt * 32 + tc];
#pragma unroll
  for (int i = 0; i < 16; i++) {
    int r = tr * 16 + i;
    Ybuf[(size_t)t * 16384 + r * 128 + jt * 32 + tc] = fmaxf(acc[i] + bj, 0.f);
  }
}

__global__ __launch_bounds__(256) void head2(
    const float* __restrict__ Ybuf,
    const float* __restrict__ bn2g, const float* __restrict__ bn2b,
    const float* __restrict__ W2, const float* __restrict__ b2,
    float* __restrict__ out) {
  int t = blockIdx.x;
  __shared__ float Y[128][132];
  __shared__ float W2s[128][11];
  __shared__ float Z[128][12];
  __shared__ float sA[128], tA[128];
  __shared__ float redS[2][128], redQ[2][128];
  int tid = threadIdx.x;

  for (int idx = tid; idx < 16384; idx += 256) {
    int r = idx >> 7, j = idx & 127;
    Y[r][j] = Ybuf[(size_t)t * 16384 + idx];
  }
  for (int idx = tid; idx < 1280; idx += 256) {
    int k = idx / 10, c = idx % 10;
    W2s[k][c] = W2[(size_t)t * 1280 + idx];
  }
  __syncthreads();
  {
    int cj = tid & 127, ch = tid >> 7;
    float s = 0.f, q = 0.f;
    for (int r = ch * 64; r < ch * 64 + 64; r++) { float v = Y[r][cj]; s += v; q += v * v; }
    redS[ch][cj] = s; redQ[ch][cj] = q;
  }
  __syncthreads();
  if (tid < 128) {
    float s = redS[0][tid] + redS[1][tid];
    float q = redQ[0][tid] + redQ[1][tid];
    float m = s * (1.f / 128.f), var = q * (1.f / 128.f) - m * m;
    float sc = bn2g[t * 128 + tid] * rsqrtf(var + 1e-5f);
    sA[tid] = sc; tA[tid] = bn2b[t * 128 + tid] - m * sc;
  }
  __syncthreads();
  for (int idx = tid; idx < 16384; idx += 256) {
    int r = idx >> 7, j = idx & 127;
    Y[r][j] = Y[r][j] * sA[j] + tA[j];
  }
  __syncthreads();
  for (int idx = tid; idx < 1280; idx += 256) {
    int r = idx / 10, c = idx % 10;
    float acc = b2[t * 10 + c];
#pragma unroll 8
    for (int k = 0; k < 128; k++) acc += Y[r][k] * W2s[k][c];
    Z[r][c] = acc;
  }
  __syncthreads();
  if (tid < 128) {
    int r = tid;
    float m = -1e30f;
    for (int c = 0; c < 10; c++) m = fmaxf(m, Z[r][c]);
    float se = 0.f;
    for (int c = 0; c < 10; c++) se += expf(Z[r][c] - m);
    float lse = m + logf(se);
    for (int c = 0; c < 10; c++) out[t * 1280 + r * 10 + c] = Z[r][c] - lse;
  }
}

// ===================== launch =====================

extern "C" void kernel_launch(void* const* d_in, const int* in_sizes, int n_in,
                              void* d_out, int out_size, void* d_ws, size_t ws_size,
                              hipStream_t stream) {
  const int N = in_sizes[0] / HD;    // 40000
  const int E = in_sizes[1] / 2;     // 480000
  const int G = out_size / 30;       // 128

  const float* x      = (const float*)d_in[0];
  const int*   ei     = (const int*)d_in[1];
  const int*   batch  = (const int*)d_in[2];
  const float* bnfg   = (const float*)d_in[3];
  const float* bnfb   = (const float*)d_in[4];
  const float* Wfeat  = (const float*)d_in[5];
  const float* bnsg   = (const float*)d_in[6];
  const float* bnsb   = (const float*)d_in[7];
  const float* convW  = (const float*)d_in[8];
  const float* convb  = (const float*)d_in[9];
  const float* Weatt  = (const float*)d_in[10];
  const float* beatt  = (const float*)d_in[11];
  const float* Wnatt  = (const float*)d_in[12];
  const float* bnatt  = (const float*)d_in[13];
  const float* bncg   = (const float*)d_in[14];
  const float* bncb   = (const float*)d_in[15];
  const float* bnog   = (const float*)d_in[16];
  const float* bnob   = (const float*)d_in[17];
  const float* Wc     = (const float*)d_in[18];
  const float* bc     = (const float*)d_in[19];
  const float* Wo     = (const float*)d_in[20];
  const float* bo     = (const float*)d_in[21];
  const float* robn1g = (const float*)d_in[22];
  const float* robn1b = (const float*)d_in[23];
  const float* roW1   = (const float*)d_in[24];
  const float* rob1   = (const float*)d_in[25];
  const float* robn2g = (const float*)d_in[26];
  const float* robn2b = (const float*)d_in[27];
  const float* roW2   = (const float*)d_in[28];
  const float* rob2   = (const float*)d_in[29];
  float* out = (float*)d_out;

  const int* row = ei;
  const int* col = ei + E;

  char* p = (char*)d_ws;
  auto alloc = [&](size_t bytes) -> void* {
    void* r = (void*)p;
    p += (bytes + 255) & ~(size_t)255;
    return r;
  };
  float* B0      = (float*)alloc((size_t)N * HD * 4);
  float* B1      = (float*)alloc((size_t)N * HD * 4);
  float* B2      = (float*)alloc((size_t)N * HD * 4);
  float* B3      = (float*)alloc((size_t)N * HD * 4);
  float* eatt    = (float*)alloc((size_t)E * 2 * 4);
  int*   csr_src = (int*)alloc((size_t)E * 4);
  int*   csr_eid = (int*)alloc((size_t)E * 4);
  float* wn1     = (float*)alloc((size_t)E * 4);
  float* wnc     = (float*)alloc((size_t)E * 4);
  float* wno     = (float*)alloc((size_t)E * 4);
  int*   ptrA    = (int*)alloc((size_t)(N + 1) * 4);
  int*   cursor  = (int*)alloc((size_t)N * 4);
  int*   cnt_in  = (int*)alloc((size_t)N * 4);
  int*   outdeg  = (int*)alloc((size_t)N * 4);
  float* dinv1   = (float*)alloc((size_t)N * 4);
  float* degc    = (float*)alloc((size_t)N * 4);
  float* dego    = (float*)alloc((size_t)N * 4);
  float* natt    = (float*)alloc((size_t)N * 2 * 4);
  float* pe      = (float*)alloc((size_t)N * 4 * 4);
  float* stats   = (float*)alloc(12 * HD * 4);   // x(2), h0..h2(2 each), co(4)
  float* pooledc = (float*)alloc((size_t)G * HD * 4);
  float* pooledo = (float*)alloc((size_t)G * HD * 4);
  float* Ybuf    = (float*)alloc((size_t)3 * 128 * 128 * 4);
  int*   csums   = (int*)alloc(64 * 4);
  int*   coffs   = (int*)alloc(64 * 4);

  const int NCH = (N + 1023) / 1024;  // scan chunks

  // ---- init accumulators ----
  hipMemsetAsync(cnt_in, 0, (size_t)N * 4, stream);
  hipMemsetAsync(outdeg, 0, (size_t)N * 4, stream);
  hipMemsetAsync(stats, 0, 12 * HD * 4, stream);
  hipMemsetAsync(pooledc, 0, (size_t)G * HD * 4, stream);
  hipMemsetAsync(pooledo, 0, (size_t)G * HD * 4, stream);
  fill_ones2<<<(N + 255) / 256, 256, 0, stream>>>(degc, dego, N);

  // ---- CSR by destination + unweighted norms ----
  hist_kernel<<<(E + 255) / 256, 256, 0, stream>>>(row, col, cnt_in, outdeg, E);
  scan1<<<NCH, 256, 0, stream>>>(cnt_in, N, csums);
  scan2<<<1, 64, 0, stream>>>(csums, NCH, coffs);
  scan3<<<NCH, 256, 0, stream>>>(cnt_in, N, coffs, ptrA, cursor);
  place_kernel<<<(E + 255) / 256, 256, 0, stream>>>(row, col, cursor, csr_src, csr_eid, E);
  dinv1_kernel<<<(N + 255) / 256, 256, 0, stream>>>(outdeg, dinv1, N);
  build_wnorm1<<<N, 64, 0, stream>>>(ptrA, csr_src, dinv1, wn1);

  const int SB = 256;
  int rpb = (N + SB - 1) / SB;
  int gblocks = (N + 63) / 64;
  int pblocks = (N + 1) / 2;
  float invN = 1.f / (float)N;

  // ---- feature BN + gfn linear + relu (BN folded into GEMM) ----
  colstats<<<SB, 256, 0, stream>>>(x, N, rpb, stats, stats + HD);
  gemm128<<<gblocks, 256, 0, stream>>>(x, Wfeat, bnfg, bnfb, stats, stats + HD, invN,
                                       nullptr, 0, B0, N, 1);

  // ---- 3 GCN conv layers ----
  for (int i = 0; i < 3; i++) {
    float* hs = stats + 2 * HD + i * 2 * HD;
    colstats<<<SB, 256, 0, stream>>>(B0, N, rpb, hs, hs + HD);
    gemm128<<<gblocks, 256, 0, stream>>>(B0, convW + (size_t)i * HD * HD,
                                         bnsg + i * HD, bnsb + i * HD, hs, hs + HD, invN,
                                         nullptr, 0, B1, N, 0);
    prop_kernel<<<pblocks, 256, 0, stream>>>(B1, ptrA, csr_src, wn1, dinv1, convb + i * HD, B0, N, 1);
  }

  // ---- attention ----
  proj_kernel<<<512, 256, 0, stream>>>(B0, Weatt, Wnatt, bnatt, natt, pe, N);
  eatt_kernel<<<(E + 255) / 256, 256, 0, stream>>>(row, col, pe, beatt, eatt, degc, dego, E);
  dinvw_kernel<<<(N + 255) / 256, 256, 0, stream>>>(degc, dego, N);
  build_wnormco<<<N, 64, 0, stream>>>(ptrA, csr_src, csr_eid, eatt, degc, dego, wnc, wno);

  // ---- xc / xo paths ----
  float* cs = stats + 8 * HD;
  colstats_scaled<<<SB, 256, 0, stream>>>(B0, natt, N, rpb, cs);
  gemm128<<<gblocks, 256, 0, stream>>>(B0, Wc, bncg, bncb, cs, cs + HD, invN,
                                       natt, 2, B1, N, 0);      // zc
  gemm128<<<gblocks, 256, 0, stream>>>(B0, Wo, bnog, bnob, cs + 2 * HD, cs + 3 * HD, invN,
                                       natt + 1, 2, B2, N, 0);  // zo

  prop_kernel<<<pblocks, 256, 0, stream>>>(B1, ptrA, csr_src, wnc, degc, bc, B3, N, 1);  // xc_out
  prop_kernel<<<pblocks, 256, 0, stream>>>(B2, ptrA, csr_src, wno, dego, bo, B1, N, 1);  // xo_out

  // ---- pool + heads ----
  pool_kernel<<<(N + POOL_RPB - 1) / POOL_RPB, 128, 0, stream>>>(B3, B1, batch, N, pooledc, pooledo);
  head1<<<12, 256, 0, stream>>>(pooledc, pooledo, robn1g, robn1b, roW1, rob1, Ybuf);
  head2<<<3, 256, 0, stream>>>(Ybuf, robn2g, robn2b, roW2, rob2, out);
}

// Round 5
// 919.290 us; speedup vs baseline: 1.3590x; 1.0268x over previous
//
#include <hip/hip_runtime.h>

#define HD 128
#define NREP 16

__device__ __forceinline__ unsigned short f2bf(float f) {
  unsigned int u = __float_as_uint(f);
  u += 0x7FFFu + ((u >> 16) & 1u);   // RNE
  return (unsigned short)(u >> 16);
}
__device__ __forceinline__ float bf2f(unsigned short h) {
  return __uint_as_float(((unsigned int)h) << 16);
}

// ===================== graph preprocessing =====================

__global__ void hist_kernel(const int* __restrict__ row, const int* __restrict__ col,
                            int* __restrict__ cnt_in, int* __restrict__ outdeg, int e) {
  int i = blockIdx.x * blockDim.x + threadIdx.x;
  if (i < e) { atomicAdd(&cnt_in[col[i]], 1); atomicAdd(&outdeg[row[i]], 1); }
}

// ---- 3-stage scan over cnt[n] -> ptr[n+1], cursor[n] ----

__global__ void scan1(const int* __restrict__ cnt, int n, int* __restrict__ sums) {
  __shared__ int lds[256];
  int b = blockIdx.x, t = threadIdx.x;
  int base = b * 1024 + t * 4;
  int s = 0;
#pragma unroll
  for (int m = 0; m < 4; m++) if (base + m < n) s += cnt[base + m];
  lds[t] = s;
  __syncthreads();
  for (int d = 128; d > 0; d >>= 1) {
    if (t < d) lds[t] += lds[t + d];
    __syncthreads();
  }
  if (t == 0) sums[b] = lds[0];
}

__global__ void scan2(const int* __restrict__ sums, int nc, int* __restrict__ off) {
  int l = threadIdx.x;
  int v = (l < nc) ? sums[l] : 0;
  int x = v;
#pragma unroll
  for (int d = 1; d < 64; d <<= 1) {
    int y = __shfl_up(x, d, 64);
    if (l >= d) x += y;
  }
  if (l < nc) off[l] = x - v;  // exclusive
}

__global__ void scan3(const int* __restrict__ cnt, int n, const int* __restrict__ off,
                      int* __restrict__ ptr, int* __restrict__ cursor) {
  __shared__ int lds[256];
  int b = blockIdx.x, t = threadIdx.x;
  int base = b * 1024 + t * 4;
  int v[4], p[4];
#pragma unroll
  for (int m = 0; m < 4; m++) v[m] = (base + m < n) ? cnt[base + m] : 0;
  p[0] = v[0];
#pragma unroll
  for (int m = 1; m < 4; m++) p[m] = p[m - 1] + v[m];
  int tsum = p[3];
  lds[t] = tsum;
  __syncthreads();
  for (int d = 1; d < 256; d <<= 1) {
    int y = 0;
    if (t >= d) y = lds[t - d];
    __syncthreads();
    lds[t] += y;
    __syncthreads();
  }
  int basev = off[b] + lds[t] - tsum;  // exclusive thread base
  if (b == 0 && t == 0) ptr[0] = 0;
#pragma unroll
  for (int m = 0; m < 4; m++) {
    int i = base + m;
    if (i < n) {
      int incl = basev + p[m];
      ptr[i + 1] = incl;
      cursor[i] = incl - v[m];
    }
  }
}

__global__ void place_kernel(const int* __restrict__ row, const int* __restrict__ col,
                             int* __restrict__ cursor, int* __restrict__ csr_src,
                             int* __restrict__ csr_eid, int e) {
  int i = blockIdx.x * blockDim.x + threadIdx.x;
  if (i < e) {
    int c = col[i];
    int pos = atomicAdd(&cursor[c], 1);
    csr_src[pos] = row[i];
    csr_eid[pos] = i;
  }
}

__global__ void dinv1_kernel(const int* __restrict__ outdeg, float* __restrict__ dinv1, int n) {
  int i = blockIdx.x * blockDim.x + threadIdx.x;
  if (i < n) dinv1[i] = rsqrtf((float)(outdeg[i] + 1));
}

__global__ void build_wnorm1(const int* __restrict__ ptr, const int* __restrict__ src,
                             const float* __restrict__ dinv1, float* __restrict__ wn) {
  int n = blockIdx.x;
  float dn = dinv1[n];
  int e1 = ptr[n + 1];
  for (int e = ptr[n] + threadIdx.x; e < e1; e += blockDim.x)
    wn[e] = dinv1[src[e]] * dn;
}

__global__ void build_wnormco(const int* __restrict__ ptr, const int* __restrict__ src,
                              const int* __restrict__ eid, const float* __restrict__ eatt,
                              const float* __restrict__ dc, const float* __restrict__ dd,
                              float* __restrict__ wc, float* __restrict__ wo) {
  int n = blockIdx.x;
  float dcn = dc[n], don = dd[n];
  int e1 = ptr[n + 1];
  for (int e = ptr[n] + threadIdx.x; e < e1; e += blockDim.x) {
    int s = src[e]; int id = eid[e];
    wc[e] = dc[s] * eatt[id * 2 + 0] * dcn;
    wo[e] = dd[s] * eatt[id * 2 + 1] * don;
  }
}

// ===================== BN stats =====================

__global__ void colstats(const float* __restrict__ A, int n, int rpb,
                         float* __restrict__ sum, float* __restrict__ sumsq) {
  int colj = threadIdx.x & (HD - 1);
  int half = threadIdx.x >> 7;
  int r0 = blockIdx.x * rpb;
  int r1 = min(n, r0 + rpb);
  float s = 0.f, q = 0.f;
  for (int r = r0 + half; r < r1; r += 2) {
    float v = A[(size_t)r * HD + colj];
    s += v; q += v * v;
  }
  atomicAdd(&sum[colj], s);
  atomicAdd(&sumsq[colj], q);
}

__global__ void colstats_scaled(const float* __restrict__ A, const float* __restrict__ natt,
                                int n, int rpb, float* __restrict__ o4) {
  int colj = threadIdx.x & (HD - 1);
  int half = threadIdx.x >> 7;
  int r0 = blockIdx.x * rpb;
  int r1 = min(n, r0 + rpb);
  float sc = 0.f, qc = 0.f, so = 0.f, qo = 0.f;
  for (int r = r0 + half; r < r1; r += 2) {
    float v = A[(size_t)r * HD + colj];
    float a0 = natt[r * 2], a1 = natt[r * 2 + 1];
    float vc = a0 * v, vo = a1 * v;
    sc += vc; qc += vc * vc; so += vo; qo += vo * vo;
  }
  atomicAdd(&o4[colj], sc);
  atomicAdd(&o4[HD + colj], qc);
  atomicAdd(&o4[2 * HD + colj], so);
  atomicAdd(&o4[3 * HD + colj], qo);
}

// ===================== GEMM with fused BN-fold =====================
// bn(a) = a*s + t, s = g*rsqrt(var+eps), t = b - m*s
// out[r,:] = rs(r) * ((A[r,:] o s) @ W) + t @ W    (rs optional)
// obf16: write bf16 (z-buffers consumed only by prop), else fp32.

__global__ __launch_bounds__(256) void gemm128(
    const float* __restrict__ A, const float* __restrict__ W,
    const float* __restrict__ g, const float* __restrict__ b,
    const float* __restrict__ ssum, const float* __restrict__ ssq, float invN,
    const float* __restrict__ rowscale, int rsStride,
    void* __restrict__ outp, int n, int relu, int obf16) {
  __shared__ float As[32][68];    // [k][row], padded
  __shared__ float Ws[32][132];   // [k][j], padded
  __shared__ float sA[HD], tA[HD], tb[HD];
  int tid = threadIdx.x;
  int r0 = blockIdx.x * 64;
  int tr = tid >> 4, tc = tid & 15;

  if (tid < HD) {
    float m = ssum[tid] * invN;
    float v = ssq[tid] * invN - m * m;
    float s = g[tid] * rsqrtf(v + 1e-5f);
    sA[tid] = s;
    tA[tid] = b[tid] - m * s;
  }
  __syncthreads();
  if (tid < HD) {  // bias = t @ W, coalesced column walk
    float acc = 0.f;
#pragma unroll 8
    for (int k = 0; k < HD; k++) acc += tA[k] * W[k * HD + tid];
    tb[tid] = acc;
  }

  float acc[4][8];
#pragma unroll
  for (int i = 0; i < 4; i++)
#pragma unroll
    for (int j = 0; j < 8; j++) acc[i][j] = 0.f;

  for (int kk = 0; kk < 128; kk += 32) {
#pragma unroll
    for (int i = 0; i < 2; i++) {           // A tile 64x32, transposed + s-folded
      int f = tid + i * 256;
      int rloc = f >> 3;
      int kc = (f & 7) * 4;
      int gr = r0 + rloc;
      float4 v = make_float4(0.f, 0.f, 0.f, 0.f);
      if (gr < n) v = *(const float4*)(A + (size_t)gr * 128 + kk + kc);
      As[kc + 0][rloc] = v.x * sA[kk + kc + 0];
      As[kc + 1][rloc] = v.y * sA[kk + kc + 1];
      As[kc + 2][rloc] = v.z * sA[kk + kc + 2];
      As[kc + 3][rloc] = v.w * sA[kk + kc + 3];
    }
#pragma unroll
    for (int i = 0; i < 4; i++) {           // W tile 32x128
      int f = tid + i * 256;
      int krow = f >> 5;
      int jc = (f & 31) * 4;
      *(float4*)&Ws[krow][jc] = *(const float4*)(W + (size_t)(kk + krow) * 128 + jc);
    }
    __syncthreads();
#pragma unroll
    for (int k = 0; k < 32; k++) {
      float4 a = *(float4*)&As[k][tr * 4];
      float4 b0 = *(float4*)&Ws[k][tc * 4];
      float4 b1 = *(float4*)&Ws[k][64 + tc * 4];
      float av[4] = {a.x, a.y, a.z, a.w};
      float bv[8] = {b0.x, b0.y, b0.z, b0.w, b1.x, b1.y, b1.z, b1.w};
#pragma unroll
      for (int i = 0; i < 4; i++)
#pragma unroll
        for (int j = 0; j < 8; j++) acc[i][j] += av[i] * bv[j];
    }
    __syncthreads();
  }
#pragma unroll
  for (int i = 0; i < 4; i++) {
    int r = r0 + tr * 4 + i;
    if (r >= n) break;
    float rs = rowscale ? rowscale[(size_t)r * rsStride] : 1.f;
    float vals[8];
#pragma unroll
    for (int j = 0; j < 4; j++) {
      float v0 = acc[i][j] * rs + tb[tc * 4 + j];
      float v1 = acc[i][j + 4] * rs + tb[64 + tc * 4 + j];
      if (relu) { v0 = fmaxf(v0, 0.f); v1 = fmaxf(v1, 0.f); }
      vals[j] = v0; vals[4 + j] = v1;
    }
    if (obf16) {
      unsigned short h[8];
#pragma unroll
      for (int j = 0; j < 8; j++) h[j] = f2bf(vals[j]);
      *(ushort4*)((unsigned short*)outp + (size_t)r * 128 + tc * 4) = *(ushort4*)&h[0];
      *(ushort4*)((unsigned short*)outp + (size_t)r * 128 + 64 + tc * 4) = *(ushort4*)&h[4];
    } else {
      *(float4*)((float*)outp + (size_t)r * 128 + tc * 4) = *(float4*)&vals[0];
      *(float4*)((float*)outp + (size_t)r * 128 + 64 + tc * 4) = *(float4*)&vals[4];
    }
  }
}

// ===================== GCN aggregation (gather over CSR-by-destination, bf16 z) =====================

__global__ __launch_bounds__(256) void prop_kernel(
    const unsigned short* __restrict__ z, const int* __restrict__ ptr,
    const int* __restrict__ src, const float* __restrict__ wn,
    const float* __restrict__ dinv, const float* __restrict__ bias,
    float* __restrict__ out, int n, int relu) {
  int node = blockIdx.x * 2 + (threadIdx.x >> 7);
  if (node >= n) return;
  int j = threadIdx.x & 127;
  float dn = dinv[node];
  float acc = dn * dn * bf2f(z[(size_t)node * HD + j]);  // self loop, weight 1
  int e = ptr[node], e1 = ptr[node + 1];
  for (; e + 3 < e1; e += 4) {
    int s0 = src[e], s1 = src[e + 1], s2 = src[e + 2], s3 = src[e + 3];
    float w0 = wn[e], w1 = wn[e + 1], w2 = wn[e + 2], w3 = wn[e + 3];
    float z0 = bf2f(z[(size_t)s0 * HD + j]);
    float z1 = bf2f(z[(size_t)s1 * HD + j]);
    float z2 = bf2f(z[(size_t)s2 * HD + j]);
    float z3 = bf2f(z[(size_t)s3 * HD + j]);
    acc += w0 * z0 + w1 * z1 + w2 * z2 + w3 * z3;
  }
  for (; e < e1; e++) acc += wn[e] * bf2f(z[(size_t)src[e] * HD + j]);
  acc += bias[j];
  if (relu) acc = fmaxf(acc, 0.f);
  out[(size_t)node * HD + j] = acc;
}

// ===================== attention projections =====================

__global__ void proj_kernel(const float* __restrict__ h, const float* __restrict__ We,
                            const float* __restrict__ Wn, const float* __restrict__ bn,
                            float* __restrict__ natt, float* __restrict__ pe, int n) {
  int gtid = blockIdx.x * blockDim.x + threadIdx.x;
  int wave = gtid >> 6;
  int lane = threadIdx.x & 63;
  int nwaves = (gridDim.x * blockDim.x) >> 6;
  for (int node = wave; node < n; node += nwaves) {
    float h0 = h[(size_t)node * HD + lane];
    float h1 = h[(size_t)node * HD + 64 + lane];
    float v[6];
    v[0] = h0 * We[lane * 2 + 0] + h1 * We[(64 + lane) * 2 + 0];
    v[1] = h0 * We[lane * 2 + 1] + h1 * We[(64 + lane) * 2 + 1];
    v[2] = h0 * We[(128 + lane) * 2 + 0] + h1 * We[(192 + lane) * 2 + 0];
    v[3] = h0 * We[(128 + lane) * 2 + 1] + h1 * We[(192 + lane) * 2 + 1];
    v[4] = h0 * Wn[lane * 2 + 0] + h1 * Wn[(64 + lane) * 2 + 0];
    v[5] = h0 * Wn[lane * 2 + 1] + h1 * Wn[(64 + lane) * 2 + 1];
#pragma unroll
    for (int m = 32; m > 0; m >>= 1) {
#pragma unroll
      for (int q = 0; q < 6; q++) v[q] += __shfl_xor(v[q], m, 64);
    }
    if (lane == 0) {
      float q0 = v[4] + bn[0], q1 = v[5] + bn[1];
      float mx = fmaxf(q0, q1);
      float e0 = expf(q0 - mx), e1 = expf(q1 - mx);
      float inv = 1.f / (e0 + e1);
      natt[node * 2 + 0] = e0 * inv;
      natt[node * 2 + 1] = e1 * inv;
      pe[node * 4 + 0] = v[0];
      pe[node * 4 + 1] = v[1];
      pe[node * 4 + 2] = v[2];
      pe[node * 4 + 3] = v[3];
    }
  }
}

// degree atomics spread over NREP replicas to cut same-address contention
__global__ void eatt_kernel(const int* __restrict__ row, const int* __restrict__ col,
                            const float* __restrict__ pe, const float* __restrict__ be,
                            float* __restrict__ eatt, float* __restrict__ drep, int n, int e) {
  int i = blockIdx.x * blockDim.x + threadIdx.x;
  if (i >= e) return;
  int bin = blockIdx.x & (NREP - 1);
  int r = row[i], c = col[i];
  float l0 = pe[r * 4 + 0] + pe[c * 4 + 2] + be[0];
  float l1 = pe[r * 4 + 1] + pe[c * 4 + 3] + be[1];
  float m = fmaxf(l0, l1);
  float e0 = expf(l0 - m), e1 = expf(l1 - m);
  float inv = 1.f / (e0 + e1);
  e0 *= inv; e1 *= inv;
  eatt[i * 2 + 0] = e0;
  eatt[i * 2 + 1] = e1;
  atomicAdd(&drep[(size_t)(bin * 2 + 0) * n + r], e0);
  atomicAdd(&drep[(size_t)(bin * 2 + 1) * n + r], e1);
}

// reduce replicas, add self-loop weight 1, emit rsqrt directly
__global__ void deg_reduce(const float* __restrict__ drep, int n,
                           float* __restrict__ degc, float* __restrict__ dego) {
  int i = blockIdx.x * blockDim.x + threadIdx.x;
  if (i >= n) return;
  float sc = 1.f, so = 1.f;
#pragma unroll
  for (int k = 0; k < NREP; k++) {
    sc += drep[(size_t)(k * 2 + 0) * n + i];
    so += drep[(size_t)(k * 2 + 1) * n + i];
  }
  degc[i] = rsqrtf(sc);
  dego[i] = rsqrtf(so);
}

// ===================== pooling (batch sorted; chunked, atomic flush) =====================

#define POOL_RPB 32

__global__ void pool_kernel(const float* __restrict__ xc, const float* __restrict__ xo,
                            const int* __restrict__ batch, int n,
                            float* __restrict__ pc, float* __restrict__ po) {
  int j = threadIdx.x;  // 128
  int r0 = blockIdx.x * POOL_RPB;
  int r1 = min(n, r0 + POOL_RPB);
  if (r0 >= n) return;
  int g = batch[r0];
  float ac = 0.f, ao = 0.f;
  for (int r = r0; r < r1; r++) {
    int br = batch[r];
    if (br != g) {
      atomicAdd(&pc[g * HD + j], ac);
      atomicAdd(&po[g * HD + j], ao);
      ac = 0.f; ao = 0.f; g = br;
    }
    ac += xc[(size_t)r * HD + j];
    ao += xo[(size_t)r * HD + j];
  }
  atomicAdd(&pc[g * HD + j], ac);
  atomicAdd(&po[g * HD + j], ao);
}

// ===================== readout heads =====================

__global__ __launch_bounds__(256) void head1(
    const float* __restrict__ pc, const float* __restrict__ po,
    const float* __restrict__ bn1g, const float* __restrict__ bn1b,
    const float* __restrict__ W1, const float* __restrict__ b1,
    float* __restrict__ Ybuf) {
  int t = blockIdx.x >> 2;
  int jt = blockIdx.x & 3;          // 32-col tile
  __shared__ float V[128][132];
  __shared__ float Wt[128][33];
  __shared__ float sA[128], tA[128];
  __shared__ float redS[2][128], redQ[2][128];
  int tid = threadIdx.x;

  for (int idx = tid; idx < 16384; idx += 256) {
    int r = idx >> 7, j = idx & 127;
    float v = (t == 0) ? pc[idx] : (t == 1) ? po[idx] : (pc[idx] + po[idx]);
    V[r][j] = v;
  }
  for (int idx = tid; idx < 4096; idx += 256) {
    int k = idx >> 5, c = idx & 31;
    Wt[k][c] = W1[(size_t)t * 16384 + k * 128 + jt * 32 + c];
  }
  __syncthreads();
  {
    int cj = tid & 127, ch = tid >> 7;
    float s = 0.f, q = 0.f;
    for (int r = ch * 64; r < ch * 64 + 64; r++) { float v = V[r][cj]; s += v; q += v * v; }
    redS[ch][cj] = s; redQ[ch][cj] = q;
  }
  __syncthreads();
  if (tid < 128) {
    float s = redS[0][tid] + redS[1][tid];
    float q = redQ[0][tid] + redQ[1][tid];
    float m = s * (1.f / 128.f), var = q * (1.f / 128.f) - m * m;
    float sc = bn1g[t * 128 + tid] * rsqrtf(var + 1e-5f);
    sA[tid] = sc; tA[tid] = bn1b[t * 128 + tid] - m * sc;
  }
  __syncthreads();
  for (int idx = tid; idx < 16384; idx += 256) {
    int r = idx >> 7, j = idx & 127;
    V[r][j] = V[r][j] * sA[j] + tA[j];
  }
  __syncthreads();
  // GEMM: 128 rows x 32 cols; thread -> 16 rows, 1 col
  int tr = tid >> 5, tc = tid & 31;
  float acc[16];
#pragma unroll
  for (int i = 0; i < 16; i++) acc[i] = 0.f;
  for (int k = 0; k < 128; k += 4) {
    float w0 = Wt[k][tc], w1 = Wt[k + 1][tc], w2 = Wt[k + 2][tc], w3 = Wt[k + 3][tc];
#pragma unroll
    for (int i = 0; i < 16; i++) {
      float4 v = *(float4*)&V[tr * 16 + i][k];
      acc[i] += v.x * w0 + v.y * w1 + v.z * w2 + v.w * w3;
    }
  }
  float bj = b1[t * 128 + jt * 32 + tc];
#pragma unroll
  for (int i = 0; i < 16; i++) {
    int r = tr * 16 + i;
    Ybuf[(size_t)t * 16384 + r * 128 + jt * 32 + tc] = fmaxf(acc[i] + bj, 0.f);
  }
}

__global__ __launch_bounds__(256) void head2(
    const float* __restrict__ Ybuf,
    const float* __restrict__ bn2g, const float* __restrict__ bn2b,
    const float* __restrict__ W2, const float* __restrict__ b2,
    float* __restrict__ out) {
  int t = blockIdx.x;
  __shared__ float Y[128][132];
  __shared__ float W2s[128][11];
  __shared__ float Z[128][12];
  __shared__ float sA[128], tA[128];
  __shared__ float redS[2][128], redQ[2][128];
  int tid = threadIdx.x;

  for (int idx = tid; idx < 16384; idx += 256) {
    int r = idx >> 7, j = idx & 127;
    Y[r][j] = Ybuf[(size_t)t * 16384 + idx];
  }
  for (int idx = tid; idx < 1280; idx += 256) {
    int k = idx / 10, c = idx % 10;
    W2s[k][c] = W2[(size_t)t * 1280 + idx];
  }
  __syncthreads();
  {
    int cj = tid & 127, ch = tid >> 7;
    float s = 0.f, q = 0.f;
    for (int r = ch * 64; r < ch * 64 + 64; r++) { float v = Y[r][cj]; s += v; q += v * v; }
    redS[ch][cj] = s; redQ[ch][cj] = q;
  }
  __syncthreads();
  if (tid < 128) {
    float s = redS[0][tid] + redS[1][tid];
    float q = redQ[0][tid] + redQ[1][tid];
    float m = s * (1.f / 128.f), var = q * (1.f / 128.f) - m * m;
    float sc = bn2g[t * 128 + tid] * rsqrtf(var + 1e-5f);
    sA[tid] = sc; tA[tid] = bn2b[t * 128 + tid] - m * sc;
  }
  __syncthreads();
  for (int idx = tid; idx < 16384; idx += 256) {
    int r = idx >> 7, j = idx & 127;
    Y[r][j] = Y[r][j] * sA[j] + tA[j];
  }
  __syncthreads();
  for (int idx = tid; idx < 1280; idx += 256) {
    int r = idx / 10, c = idx % 10;
    float acc = b2[t * 10 + c];
#pragma unroll 8
    for (int k = 0; k < 128; k++) acc += Y[r][k] * W2s[k][c];
    Z[r][c] = acc;
  }
  __syncthreads();
  if (tid < 128) {
    int r = tid;
    float m = -1e30f;
    for (int c = 0; c < 10; c++) m = fmaxf(m, Z[r][c]);
    float se = 0.f;
    for (int c = 0; c < 10; c++) se += expf(Z[r][c] - m);
    float lse = m + logf(se);
    for (int c = 0; c < 10; c++) out[t * 1280 + r * 10 + c] = Z[r][c] - lse;
  }
}

// ===================== launch =====================

extern "C" void kernel_launch(void* const* d_in, const int* in_sizes, int n_in,
                              void* d_out, int out_size, void* d_ws, size_t ws_size,
                              hipStream_t stream) {
  const int N = in_sizes[0] / HD;    // 40000
  const int E = in_sizes[1] / 2;     // 480000
  const int G = out_size / 30;       // 128

  const float* x      = (const float*)d_in[0];
  const int*   ei     = (const int*)d_in[1];
  const int*   batch  = (const int*)d_in[2];
  const float* bnfg   = (const float*)d_in[3];
  const float* bnfb   = (const float*)d_in[4];
  const float* Wfeat  = (const float*)d_in[5];
  const float* bnsg   = (const float*)d_in[6];
  const float* bnsb   = (const float*)d_in[7];
  const float* convW  = (const float*)d_in[8];
  const float* convb  = (const float*)d_in[9];
  const float* Weatt  = (const float*)d_in[10];
  const float* beatt  = (const float*)d_in[11];
  const float* Wnatt  = (const float*)d_in[12];
  const float* bnatt  = (const float*)d_in[13];
  const float* bncg   = (const float*)d_in[14];
  const float* bncb   = (const float*)d_in[15];
  const float* bnog   = (const float*)d_in[16];
  const float* bnob   = (const float*)d_in[17];
  const float* Wc     = (const float*)d_in[18];
  const float* bc     = (const float*)d_in[19];
  const float* Wo     = (const float*)d_in[20];
  const float* bo     = (const float*)d_in[21];
  const float* robn1g = (const float*)d_in[22];
  const float* robn1b = (const float*)d_in[23];
  const float* roW1   = (const float*)d_in[24];
  const float* rob1   = (const float*)d_in[25];
  const float* robn2g = (const float*)d_in[26];
  const float* robn2b = (const float*)d_in[27];
  const float* roW2   = (const float*)d_in[28];
  const float* rob2   = (const float*)d_in[29];
  float* out = (float*)d_out;

  const int* row = ei;
  const int* col = ei + E;

  char* p = (char*)d_ws;
  auto alloc = [&](size_t bytes) -> void* {
    void* r = (void*)p;
    p += (bytes + 255) & ~(size_t)255;
    return r;
  };
  float* B0      = (float*)alloc((size_t)N * HD * 4);           // h (fp32)
  float* Xc      = (float*)alloc((size_t)N * HD * 4);           // fp32
  float* Xo      = (float*)alloc((size_t)N * HD * 4);           // fp32
  unsigned short* Z1 = (unsigned short*)alloc((size_t)N * HD * 2);  // bf16 z
  unsigned short* Z2 = (unsigned short*)alloc((size_t)N * HD * 2);  // bf16 z
  float* eatt    = (float*)alloc((size_t)E * 2 * 4);
  int*   csr_src = (int*)alloc((size_t)E * 4);
  int*   csr_eid = (int*)alloc((size_t)E * 4);
  float* wn1     = (float*)alloc((size_t)E * 4);
  float* wnc     = (float*)alloc((size_t)E * 4);
  float* wno     = (float*)alloc((size_t)E * 4);
  int*   ptrA    = (int*)alloc((size_t)(N + 1) * 4);
  int*   cursor  = (int*)alloc((size_t)N * 4);
  int*   cnt_in  = (int*)alloc((size_t)N * 4);
  int*   outdeg  = (int*)alloc((size_t)N * 4);
  float* dinv1   = (float*)alloc((size_t)N * 4);
  float* degc    = (float*)alloc((size_t)N * 4);
  float* dego    = (float*)alloc((size_t)N * 4);
  float* natt    = (float*)alloc((size_t)N * 2 * 4);
  float* pe      = (float*)alloc((size_t)N * 4 * 4);
  float* drep    = (float*)alloc((size_t)NREP * 2 * N * 4);
  float* stats   = (float*)alloc(12 * HD * 4);
  float* pooledc = (float*)alloc((size_t)G * HD * 4);
  float* pooledo = (float*)alloc((size_t)G * HD * 4);
  float* Ybuf    = (float*)alloc((size_t)3 * 128 * 128 * 4);
  int*   csums   = (int*)alloc(64 * 4);
  int*   coffs   = (int*)alloc(64 * 4);

  const int NCH = (N + 1023) / 1024;  // scan chunks

  // ---- init accumulators ----
  hipMemsetAsync(cnt_in, 0, (size_t)N * 4, stream);
  hipMemsetAsync(outdeg, 0, (size_t)N * 4, stream);
  hipMemsetAsync(stats, 0, 12 * HD * 4, stream);
  hipMemsetAsync(pooledc, 0, (size_t)G * HD * 4, stream);
  hipMemsetAsync(pooledo, 0, (size_t)G * HD * 4, stream);
  hipMemsetAsync(drep, 0, (size_t)NREP * 2 * N * 4, stream);

  // ---- CSR by destination + unweighted norms ----
  hist_kernel<<<(E + 255) / 256, 256, 0, stream>>>(row, col, cnt_in, outdeg, E);
  scan1<<<NCH, 256, 0, stream>>>(cnt_in, N, csums);
  scan2<<<1, 64, 0, stream>>>(csums, NCH, coffs);
  scan3<<<NCH, 256, 0, stream>>>(cnt_in, N, coffs, ptrA, cursor);
  place_kernel<<<(E + 255) / 256, 256, 0, stream>>>(row, col, cursor, csr_src, csr_eid, E);
  dinv1_kernel<<<(N + 255) / 256, 256, 0, stream>>>(outdeg, dinv1, N);
  build_wnorm1<<<N, 64, 0, stream>>>(ptrA, csr_src, dinv1, wn1);

  const int SB = 256;
  int rpb = (N + SB - 1) / SB;
  int gblocks = (N + 63) / 64;
  int pblocks = (N + 1) / 2;
  float invN = 1.f / (float)N;

  // ---- feature BN + gfn linear + relu (BN folded into GEMM) ----
  colstats<<<SB, 256, 0, stream>>>(x, N, rpb, stats, stats + HD);
  gemm128<<<gblocks, 256, 0, stream>>>(x, Wfeat, bnfg, bnfb, stats, stats + HD, invN,
                                       nullptr, 0, B0, N, 1, 0);

  // ---- 3 GCN conv layers (z in bf16) ----
  for (int i = 0; i < 3; i++) {
    float* hs = stats + 2 * HD + i * 2 * HD;
    colstats<<<SB, 256, 0, stream>>>(B0, N, rpb, hs, hs + HD);
    gemm128<<<gblocks, 256, 0, stream>>>(B0, convW + (size_t)i * HD * HD,
                                         bnsg + i * HD, bnsb + i * HD, hs, hs + HD, invN,
                                         nullptr, 0, Z1, N, 0, 1);
    prop_kernel<<<pblocks, 256, 0, stream>>>(Z1, ptrA, csr_src, wn1, dinv1, convb + i * HD, B0, N, 1);
  }

  // ---- attention ----
  proj_kernel<<<512, 256, 0, stream>>>(B0, Weatt, Wnatt, bnatt, natt, pe, N);
  eatt_kernel<<<(E + 255) / 256, 256, 0, stream>>>(row, col, pe, beatt, eatt, drep, N, E);
  deg_reduce<<<(N + 255) / 256, 256, 0, stream>>>(drep, N, degc, dego);
  build_wnormco<<<N, 64, 0, stream>>>(ptrA, csr_src, csr_eid, eatt, degc, dego, wnc, wno);

  // ---- xc / xo paths ----
  float* cs = stats + 8 * HD;
  colstats_scaled<<<SB, 256, 0, stream>>>(B0, natt, N, rpb, cs);
  gemm128<<<gblocks, 256, 0, stream>>>(B0, Wc, bncg, bncb, cs, cs + HD, invN,
                                       natt, 2, Z1, N, 0, 1);      // zc
  gemm128<<<gblocks, 256, 0, stream>>>(B0, Wo, bnog, bnob, cs + 2 * HD, cs + 3 * HD, invN,
                                       natt + 1, 2, Z2, N, 0, 1);  // zo

  prop_kernel<<<pblocks, 256, 0, stream>>>(Z1, ptrA, csr_src, wnc, degc, bc, Xc, N, 1);
  prop_kernel<<<pblocks, 256, 0, stream>>>(Z2, ptrA, csr_src, wno, dego, bo, Xo, N, 1);

  // ---- pool + heads ----
  pool_kernel<<<(N + POOL_RPB - 1) / POOL_RPB, 128, 0, stream>>>(Xc, Xo, batch, N, pooledc, pooledo);
  head1<<<12, 256, 0, stream>>>(pooledc, pooledo, robn1g, robn1b, roW1, rob1, Ybuf);
  head2<<<3, 256, 0, stream>>>(Ybuf, robn2g, robn2b, roW2, rob2, out);
}

// Round 6
// 875.005 us; speedup vs baseline: 1.4277x; 1.0506x over previous
//
#include <hip/hip_runtime.h>

#define HD 128

typedef __attribute__((ext_vector_type(8))) short bf16x8v;
typedef __attribute__((ext_vector_type(4))) float f32x4v;

__device__ __forceinline__ unsigned short f2bf(float f) {
  unsigned int u = __float_as_uint(f);
  u += 0x7FFFu + ((u >> 16) & 1u);   // RNE
  return (unsigned short)(u >> 16);
}
__device__ __forceinline__ float bf2f(unsigned short h) {
  return __uint_as_float(((unsigned int)h) << 16);
}

// ===================== graph preprocessing =====================

__global__ void hist_kernel(const int* __restrict__ row, const int* __restrict__ col,
                            int* __restrict__ cnt_in, int* __restrict__ outdeg, int e) {
  int i = blockIdx.x * blockDim.x + threadIdx.x;
  if (i < e) { atomicAdd(&cnt_in[col[i]], 1); atomicAdd(&outdeg[row[i]], 1); }
}

// ---- 3-stage scan over cnt[n] -> ptr[n+1], cursor[n] ----

__global__ void scan1(const int* __restrict__ cnt, int n, int* __restrict__ sums) {
  __shared__ int lds[256];
  int b = blockIdx.x, t = threadIdx.x;
  int base = b * 1024 + t * 4;
  int s = 0;
#pragma unroll
  for (int m = 0; m < 4; m++) if (base + m < n) s += cnt[base + m];
  lds[t] = s;
  __syncthreads();
  for (int d = 128; d > 0; d >>= 1) {
    if (t < d) lds[t] += lds[t + d];
    __syncthreads();
  }
  if (t == 0) sums[b] = lds[0];
}

__global__ void scan2(const int* __restrict__ sums, int nc, int* __restrict__ off) {
  int l = threadIdx.x;
  int v = (l < nc) ? sums[l] : 0;
  int x = v;
#pragma unroll
  for (int d = 1; d < 64; d <<= 1) {
    int y = __shfl_up(x, d, 64);
    if (l >= d) x += y;
  }
  if (l < nc) off[l] = x - v;  // exclusive
}

__global__ void scan3(const int* __restrict__ cnt, int n, const int* __restrict__ off,
                      int* __restrict__ ptr, int* __restrict__ cursor) {
  __shared__ int lds[256];
  int b = blockIdx.x, t = threadIdx.x;
  int base = b * 1024 + t * 4;
  int v[4], p[4];
#pragma unroll
  for (int m = 0; m < 4; m++) v[m] = (base + m < n) ? cnt[base + m] : 0;
  p[0] = v[0];
#pragma unroll
  for (int m = 1; m < 4; m++) p[m] = p[m - 1] + v[m];
  int tsum = p[3];
  lds[t] = tsum;
  __syncthreads();
  for (int d = 1; d < 256; d <<= 1) {
    int y = 0;
    if (t >= d) y = lds[t - d];
    __syncthreads();
    lds[t] += y;
    __syncthreads();
  }
  int basev = off[b] + lds[t] - tsum;  // exclusive thread base
  if (b == 0 && t == 0) ptr[0] = 0;
#pragma unroll
  for (int m = 0; m < 4; m++) {
    int i = base + m;
    if (i < n) {
      int incl = basev + p[m];
      ptr[i + 1] = incl;
      cursor[i] = incl - v[m];
    }
  }
}

// dest-CSR: store src, dst, eid
__global__ void place1(const int* __restrict__ row, const int* __restrict__ col,
                       int* __restrict__ cursor, int* __restrict__ csr_src,
                       int* __restrict__ csr_dst, int* __restrict__ csr_eid, int e) {
  int i = blockIdx.x * blockDim.x + threadIdx.x;
  if (i < e) {
    int c = col[i];
    int pos = atomicAdd(&cursor[c], 1);
    csr_src[pos] = row[i];
    csr_dst[pos] = c;
    csr_eid[pos] = i;
  }
}

// row-CSR: store eid only
__global__ void place2(const int* __restrict__ row, int* __restrict__ cursor2,
                       int* __restrict__ csr2_eid, int e) {
  int i = blockIdx.x * blockDim.x + threadIdx.x;
  if (i < e) {
    int pos = atomicAdd(&cursor2[row[i]], 1);
    csr2_eid[pos] = i;
  }
}

__global__ void dinv1_kernel(const int* __restrict__ outdeg, float* __restrict__ dinv1, int n) {
  int i = blockIdx.x * blockDim.x + threadIdx.x;
  if (i < n) dinv1[i] = rsqrtf((float)(outdeg[i] + 1));
}

__global__ void wn1_flat(const int* __restrict__ csr_src, const int* __restrict__ csr_dst,
                         const float* __restrict__ dinv1, float* __restrict__ wn, int e) {
  int i = blockIdx.x * blockDim.x + threadIdx.x;
  if (i < e) wn[i] = dinv1[csr_src[i]] * dinv1[csr_dst[i]];
}

// ===================== BN stats =====================

// fp32 in -> stats + bf16 copy out
__global__ void colstats_castx(const float* __restrict__ A, unsigned short* __restrict__ Abf,
                               int n, int rpb, float* __restrict__ sum, float* __restrict__ sumsq) {
  int colj = threadIdx.x & (HD - 1);
  int half = threadIdx.x >> 7;
  int r0 = blockIdx.x * rpb;
  int r1 = min(n, r0 + rpb);
  float s = 0.f, q = 0.f;
  for (int r = r0 + half; r < r1; r += 2) {
    float v = A[(size_t)r * HD + colj];
    Abf[(size_t)r * HD + colj] = f2bf(v);
    s += v; q += v * v;
  }
  atomicAdd(&sum[colj], s);
  atomicAdd(&sumsq[colj], q);
}

__global__ void colstats_bf(const unsigned short* __restrict__ A, int n, int rpb,
                            float* __restrict__ sum, float* __restrict__ sumsq) {
  int colj = threadIdx.x & (HD - 1);
  int half = threadIdx.x >> 7;
  int r0 = blockIdx.x * rpb;
  int r1 = min(n, r0 + rpb);
  float s = 0.f, q = 0.f;
  for (int r = r0 + half; r < r1; r += 2) {
    float v = bf2f(A[(size_t)r * HD + colj]);
    s += v; q += v * v;
  }
  atomicAdd(&sum[colj], s);
  atomicAdd(&sumsq[colj], q);
}

__global__ void colstats_scaled(const unsigned short* __restrict__ A, const float* __restrict__ natt,
                                int n, int rpb, float* __restrict__ o4) {
  int colj = threadIdx.x & (HD - 1);
  int half = threadIdx.x >> 7;
  int r0 = blockIdx.x * rpb;
  int r1 = min(n, r0 + rpb);
  float sc = 0.f, qc = 0.f, so = 0.f, qo = 0.f;
  for (int r = r0 + half; r < r1; r += 2) {
    float v = bf2f(A[(size_t)r * HD + colj]);
    float a0 = natt[r * 2], a1 = natt[r * 2 + 1];
    float vc = a0 * v, vo = a1 * v;
    sc += vc; qc += vc * vc; so += vo; qo += vo * vo;
  }
  atomicAdd(&o4[colj], sc);
  atomicAdd(&o4[HD + colj], qc);
  atomicAdd(&o4[2 * HD + colj], so);
  atomicAdd(&o4[3 * HD + colj], qo);
}

// ===================== MFMA GEMM (bf16 in/out, fp32 acc) with fused BN-fold =====================
// bn(a) = a*s + t ; out[r,:] = relu?( rs(r) * ((a o s) @ W) + t@W )
// s folded into W during LDS staging; A-frags loaded straight from global bf16.

__global__ __launch_bounds__(256) void gemm_mfma(
    const unsigned short* __restrict__ A, const float* __restrict__ W,
    const float* __restrict__ g, const float* __restrict__ b,
    const float* __restrict__ ssum, const float* __restrict__ ssq, float invN,
    const float* __restrict__ rowscale, int rsStride,
    unsigned short* __restrict__ out, int n, int relu) {
  __shared__ unsigned short WT[128][136];   // [col][k] bf16, padded (+8) for banks
  __shared__ float sA[HD], tA[HD], tb[HD];
  int tid = threadIdx.x;
  int r0 = blockIdx.x * 64;

  if (tid < HD) {
    float m = ssum[tid] * invN;
    float v = ssq[tid] * invN - m * m;
    float s = g[tid] * rsqrtf(v + 1e-5f);
    sA[tid] = s;
    tA[tid] = b[tid] - m * s;
  }
  __syncthreads();
  // stage W transposed into LDS with s-fold (bf16)
  for (int idx = tid; idx < 4096; idx += 256) {
    int k = idx >> 5;
    int j4 = (idx & 31) * 4;
    float4 w = *(const float4*)(W + (size_t)k * 128 + j4);
    float s = sA[k];
    WT[j4 + 0][k] = f2bf(w.x * s);
    WT[j4 + 1][k] = f2bf(w.y * s);
    WT[j4 + 2][k] = f2bf(w.z * s);
    WT[j4 + 3][k] = f2bf(w.w * s);
  }
  if (tid < HD) {  // tb = t @ W (fp32, coalesced column walk)
    float acc = 0.f;
#pragma unroll 8
    for (int k = 0; k < HD; k++) acc += tA[k] * W[(size_t)k * 128 + tid];
    tb[tid] = acc;
  }
  __syncthreads();

  int w = tid >> 6;         // wave 0..3
  int l = tid & 63;         // lane
  int colb = l & 15;
  int kcb = l >> 4;         // k-chunk 0..3 (8 elems each)
  int arow = r0 + w * 16 + colb;   // A-frag row for this lane
  bool rowok = arow < n;

  f32x4v acc[8];
#pragma unroll
  for (int jt = 0; jt < 8; jt++) acc[jt] = (f32x4v){0.f, 0.f, 0.f, 0.f};

  const unsigned short* Ap = A + (size_t)(rowok ? arow : 0) * 128 + kcb * 8;
#pragma unroll
  for (int kit = 0; kit < 4; kit++) {
    bf16x8v a;
    if (rowok) a = *(const bf16x8v*)(Ap + kit * 32);
    else a = (bf16x8v){0, 0, 0, 0, 0, 0, 0, 0};
#pragma unroll
    for (int jt = 0; jt < 8; jt++) {
      bf16x8v bb = *(const bf16x8v*)&WT[jt * 16 + colb][kit * 32 + kcb * 8];
      acc[jt] = __builtin_amdgcn_mfma_f32_16x16x32_bf16(a, bb, acc[jt], 0, 0, 0);
    }
  }

  // epilogue: lane holds col=colb, rows (l>>4)*4+i of its wave tile
  int rbase = r0 + w * 16 + kcb * 4;
  float rs[4];
#pragma unroll
  for (int i = 0; i < 4; i++)
    rs[i] = rowscale ? ((rbase + i < n) ? rowscale[(size_t)(rbase + i) * rsStride] : 0.f) : 1.f;
#pragma unroll
  for (int jt = 0; jt < 8; jt++) {
    int colj = jt * 16 + colb;
    float tbv = tb[colj];
#pragma unroll
    for (int i = 0; i < 4; i++) {
      int r = rbase + i;
      if (r < n) {
        float v = acc[jt][i] * rs[i] + tbv;
        if (relu) v = fmaxf(v, 0.f);
        out[(size_t)r * 128 + colj] = f2bf(v);
      }
    }
  }
}

// ===================== GCN aggregation (gather over dest-CSR, bf16 z -> bf16 out) =====================

__global__ __launch_bounds__(256) void prop_kernel(
    const unsigned short* __restrict__ z, const int* __restrict__ ptr,
    const int* __restrict__ src, const float* __restrict__ wn,
    const float* __restrict__ dinv, int dstride, const float* __restrict__ bias,
    unsigned short* __restrict__ out, int n, int relu) {
  int node = blockIdx.x * 2 + (threadIdx.x >> 7);
  if (node >= n) return;
  int j = threadIdx.x & 127;
  float dn = dinv[(size_t)node * dstride];
  float acc = dn * dn * bf2f(z[(size_t)node * HD + j]);  // self loop, weight 1
  int e = ptr[node], e1 = ptr[node + 1];
  for (; e + 3 < e1; e += 4) {
    int s0 = src[e], s1 = src[e + 1], s2 = src[e + 2], s3 = src[e + 3];
    float w0 = wn[e], w1 = wn[e + 1], w2 = wn[e + 2], w3 = wn[e + 3];
    float z0 = bf2f(z[(size_t)s0 * HD + j]);
    float z1 = bf2f(z[(size_t)s1 * HD + j]);
    float z2 = bf2f(z[(size_t)s2 * HD + j]);
    float z3 = bf2f(z[(size_t)s3 * HD + j]);
    acc += w0 * z0 + w1 * z1 + w2 * z2 + w3 * z3;
  }
  for (; e < e1; e++) acc += wn[e] * bf2f(z[(size_t)src[e] * HD + j]);
  acc += bias[j];
  if (relu) acc = fmaxf(acc, 0.f);
  out[(size_t)node * HD + j] = f2bf(acc);
}

// ===================== attention =====================

__global__ void proj_kernel(const unsigned short* __restrict__ h, const float* __restrict__ We,
                            const float* __restrict__ Wn, const float* __restrict__ bn,
                            float* __restrict__ natt, float* __restrict__ pe, int n) {
  int gtid = blockIdx.x * blockDim.x + threadIdx.x;
  int wave = gtid >> 6;
  int lane = threadIdx.x & 63;
  int nwaves = (gridDim.x * blockDim.x) >> 6;
  for (int node = wave; node < n; node += nwaves) {
    float h0 = bf2f(h[(size_t)node * HD + lane]);
    float h1 = bf2f(h[(size_t)node * HD + 64 + lane]);
    float v[6];
    v[0] = h0 * We[lane * 2 + 0] + h1 * We[(64 + lane) * 2 + 0];
    v[1] = h0 * We[lane * 2 + 1] + h1 * We[(64 + lane) * 2 + 1];
    v[2] = h0 * We[(128 + lane) * 2 + 0] + h1 * We[(192 + lane) * 2 + 0];
    v[3] = h0 * We[(128 + lane) * 2 + 1] + h1 * We[(192 + lane) * 2 + 1];
    v[4] = h0 * Wn[lane * 2 + 0] + h1 * Wn[(64 + lane) * 2 + 0];
    v[5] = h0 * Wn[lane * 2 + 1] + h1 * Wn[(64 + lane) * 2 + 1];
#pragma unroll
    for (int m = 32; m > 0; m >>= 1) {
#pragma unroll
      for (int q = 0; q < 6; q++) v[q] += __shfl_xor(v[q], m, 64);
    }
    if (lane == 0) {
      float q0 = v[4] + bn[0], q1 = v[5] + bn[1];
      float mx = fmaxf(q0, q1);
      float e0 = expf(q0 - mx), e1 = expf(q1 - mx);
      float inv = 1.f / (e0 + e1);
      natt[node * 2 + 0] = e0 * inv;
      natt[node * 2 + 1] = e1 * inv;
      pe[node * 4 + 0] = v[0];
      pe[node * 4 + 1] = v[1];
      pe[node * 4 + 2] = v[2];
      pe[node * 4 + 3] = v[3];
    }
  }
}

// per-edge softmax, contiguous write, NO atomics
__global__ void eatt_flat(const int* __restrict__ row, const int* __restrict__ col,
                          const float* __restrict__ pe, const float* __restrict__ be,
                          float2* __restrict__ eattO, int e) {
  int i = blockIdx.x * blockDim.x + threadIdx.x;
  if (i >= e) return;
  int r = row[i], c = col[i];
  float l0 = pe[r * 4 + 0] + pe[c * 4 + 2] + be[0];
  float l1 = pe[r * 4 + 1] + pe[c * 4 + 3] + be[1];
  float m = fmaxf(l0, l1);
  float e0 = expf(l0 - m), e1 = expf(l1 - m);
  float inv = 1.f / (e0 + e1);
  eattO[i] = make_float2(e0 * inv, e1 * inv);
}

// one wave per source node over row-CSR: sum out-edge attention -> rsqrt degrees
__global__ void deg_kernel(const int* __restrict__ ptrR, const int* __restrict__ csr2_eid,
                           const float2* __restrict__ eattO, float2* __restrict__ ddeg, int n) {
  int gtid = blockIdx.x * blockDim.x + threadIdx.x;
  int node = gtid >> 6;
  int lane = threadIdx.x & 63;
  if (node >= n) return;
  int e0 = ptrR[node], e1 = ptrR[node + 1];
  float sc = 0.f, so = 0.f;
  for (int e = e0 + lane; e < e1; e += 64) {
    float2 at = eattO[csr2_eid[e]];
    sc += at.x; so += at.y;
  }
#pragma unroll
  for (int m = 32; m > 0; m >>= 1) {
    sc += __shfl_xor(sc, m, 64);
    so += __shfl_xor(so, m, 64);
  }
  if (lane == 0) ddeg[node] = make_float2(rsqrtf(1.f + sc), rsqrtf(1.f + so));
}

// flat thread-per-dest-position: normalized edge weights
__global__ void wn_flat(const int* __restrict__ csr_src, const int* __restrict__ csr_dst,
                        const int* __restrict__ csr_eid, const float2* __restrict__ eattO,
                        const float2* __restrict__ ddeg, float* __restrict__ wnc,
                        float* __restrict__ wno, int e) {
  int i = blockIdx.x * blockDim.x + threadIdx.x;
  if (i >= e) return;
  int s = csr_src[i], c = csr_dst[i];
  float2 at = eattO[csr_eid[i]];
  float2 ds = ddeg[s], dc = ddeg[c];
  wnc[i] = ds.x * at.x * dc.x;
  wno[i] = ds.y * at.y * dc.y;
}

// ===================== pooling (batch sorted; chunked, atomic flush) =====================

#define POOL_RPB 32

__global__ void pool_kernel(const unsigned short* __restrict__ xc,
                            const unsigned short* __restrict__ xo,
                            const int* __restrict__ batch, int n,
                            float* __restrict__ pc, float* __restrict__ po) {
  int j = threadIdx.x;  // 128
  int r0 = blockIdx.x * POOL_RPB;
  int r1 = min(n, r0 + POOL_RPB);
  if (r0 >= n) return;
  int g = batch[r0];
  float ac = 0.f, ao = 0.f;
  for (int r = r0; r < r1; r++) {
    int br = batch[r];
    if (br != g) {
      atomicAdd(&pc[g * HD + j], ac);
      atomicAdd(&po[g * HD + j], ao);
      ac = 0.f; ao = 0.f; g = br;
    }
    ac += bf2f(xc[(size_t)r * HD + j]);
    ao += bf2f(xo[(size_t)r * HD + j]);
  }
  atomicAdd(&pc[g * HD + j], ac);
  atomicAdd(&po[g * HD + j], ao);
}

// ===================== readout heads =====================

__global__ __launch_bounds__(256) void head1(
    const float* __restrict__ pc, const float* __restrict__ po,
    const float* __restrict__ bn1g, const float* __restrict__ bn1b,
    const float* __restrict__ W1, const float* __restrict__ b1,
    float* __restrict__ Ybuf) {
  int t = blockIdx.x >> 2;
  int jt = blockIdx.x & 3;          // 32-col tile
  __shared__ float V[128][132];
  __shared__ float Wt[128][33];
  __shared__ float sA[128], tA[128];
  __shared__ float redS[2][128], redQ[2][128];
  int tid = threadIdx.x;

  for (int idx = tid; idx < 16384; idx += 256) {
    int r = idx >> 7, j = idx & 127;
    float v = (t == 0) ? pc[idx] : (t == 1) ? po[idx] : (pc[idx] + po[idx]);
    V[r][j] = v;
  }
  for (int idx = tid; idx < 4096; idx += 256) {
    int k = idx >> 5, c = idx & 31;
    Wt[k][c] = W1[(size_t)t * 16384 + k * 128 + jt * 32 + c];
  }
  __syncthreads();
  {
    int cj = tid & 127, ch = tid >> 7;
    float s = 0.f, q = 0.f;
    for (int r = ch * 64; r < ch * 64 + 64; r++) { float v = V[r][cj]; s += v; q += v * v; }
    redS[ch][cj] = s; redQ[ch][cj] = q;
  }
  __syncthreads();
  if (tid < 128) {
    float s = redS[0][tid] + redS[1][tid];
    float q = redQ[0][tid] + redQ[1][tid];
    float m = s * (1.f / 128.f), var = q * (1.f / 128.f) - m * m;
    float sc = bn1g[t * 128 + tid] * rsqrtf(var + 1e-5f);
    sA[tid] = sc; tA[tid] = bn1b[t * 128 + tid] - m * sc;
  }
  __syncthreads();
  for (int idx = tid; idx < 16384; idx += 256) {
    int r = idx >> 7, j = idx & 127;
    V[r][j] = V[r][j] * sA[j] + tA[j];
  }
  __syncthreads();
  int tr = tid >> 5, tc = tid & 31;
  float acc[16];
#pragma unroll
  for (int i = 0; i < 16; i++) acc[i] = 0.f;
  for (int k = 0; k < 128; k += 4) {
    float w0 = Wt[k][tc], w1 = Wt[k + 1][tc], w2 = Wt[k + 2][tc], w3 = Wt[k + 3][tc];
#pragma unroll
    for (int i = 0; i < 16; i++) {
      float4 v = *(float4*)&V[tr * 16 + i][k];
      acc[i] += v.x * w0 + v.y * w1 + v.z * w2 + v.w * w3;
    }
  }
  float bj = b1[t * 128 + jt * 32 + tc];
#pragma unroll
  for (int i = 0; i < 16; i++) {
    int r = tr * 16 + i;
    Ybuf[(size_t)t * 16384 + r * 128 + jt * 32 + tc] = fmaxf(acc[i] + bj, 0.f);
  }
}

__global__ __launch_bounds__(256) void head2(
    const float* __restrict__ Ybuf,
    const float* __restrict__ bn2g, const float* __restrict__ bn2b,
    const float* __restrict__ W2, const float* __restrict__ b2,
    float* __restrict__ out) {
  int t = blockIdx.x;
  __shared__ float Y[128][132];
  __shared__ float W2s[128][11];
  __shared__ float Z[128][12];
  __shared__ float sA[128], tA[128];
  __shared__ float redS[2][128], redQ[2][128];
  int tid = threadIdx.x;

  for (int idx = tid; idx < 16384; idx += 256) {
    int r = idx >> 7, j = idx & 127;
    Y[r][j] = Ybuf[(size_t)t * 16384 + idx];
  }
  for (int idx = tid; idx < 1280; idx += 256) {
    int k = idx / 10, c = idx % 10;
    W2s[k][c] = W2[(size_t)t * 1280 + idx];
  }
  __syncthreads();
  {
    int cj = tid & 127, ch = tid >> 7;
    float s = 0.f, q = 0.f;
    for (int r = ch * 64; r < ch * 64 + 64; r++) { float v = Y[r][cj]; s += v; q += v * v; }
    redS[ch][cj] = s; redQ[ch][cj] = q;
  }
  __syncthreads();
  if (tid < 128) {
    float s = redS[0][tid] + redS[1][tid];
    float q = redQ[0][tid] + redQ[1][tid];
    float m = s * (1.f / 128.f), var = q * (1.f / 128.f) - m * m;
    float sc = bn2g[t * 128 + tid] * rsqrtf(var + 1e-5f);
    sA[tid] = sc; tA[tid] = bn2b[t * 128 + tid] - m * sc;
  }
  __syncthreads();
  for (int idx = tid; idx < 16384; idx += 256) {
    int r = idx >> 7, j = idx & 127;
    Y[r][j] = Y[r][j] * sA[j] + tA[j];
  }
  __syncthreads();
  for (int idx = tid; idx < 1280; idx += 256) {
    int r = idx / 10, c = idx % 10;
    float acc = b2[t * 10 + c];
#pragma unroll 8
    for (int k = 0; k < 128; k++) acc += Y[r][k] * W2s[k][c];
    Z[r][c] = acc;
  }
  __syncthreads();
  if (tid < 128) {
    int r = tid;
    float m = -1e30f;
    for (int c = 0; c < 10; c++) m = fmaxf(m, Z[r][c]);
    float se = 0.f;
    for (int c = 0; c < 10; c++) se += expf(Z[r][c] - m);
    float lse = m + logf(se);
    for (int c = 0; c < 10; c++) out[t * 1280 + r * 10 + c] = Z[r][c] - lse;
  }
}

// ===================== launch =====================

extern "C" void kernel_launch(void* const* d_in, const int* in_sizes, int n_in,
                              void* d_out, int out_size, void* d_ws, size_t ws_size,
                              hipStream_t stream) {
  const int N = in_sizes[0] / HD;    // 40000
  const int E = in_sizes[1] / 2;     // 480000
  const int G = out_size / 30;       // 128

  const float* x      = (const float*)d_in[0];
  const int*   ei     = (const int*)d_in[1];
  const int*   batch  = (const int*)d_in[2];
  const float* bnfg   = (const float*)d_in[3];
  const float* bnfb   = (const float*)d_in[4];
  const float* Wfeat  = (const float*)d_in[5];
  const float* bnsg   = (const float*)d_in[6];
  const float* bnsb   = (const float*)d_in[7];
  const float* convW  = (const float*)d_in[8];
  const float* convb  = (const float*)d_in[9];
  const float* Weatt  = (const float*)d_in[10];
  const float* beatt  = (const float*)d_in[11];
  const float* Wnatt  = (const float*)d_in[12];
  const float* bnatt  = (const float*)d_in[13];
  const float* bncg   = (const float*)d_in[14];
  const float* bncb   = (const float*)d_in[15];
  const float* bnog   = (const float*)d_in[16];
  const float* bnob   = (const float*)d_in[17];
  const float* Wc     = (const float*)d_in[18];
  const float* bc     = (const float*)d_in[19];
  const float* Wo     = (const float*)d_in[20];
  const float* bo     = (const float*)d_in[21];
  const float* robn1g = (const float*)d_in[22];
  const float* robn1b = (const float*)d_in[23];
  const float* roW1   = (const float*)d_in[24];
  const float* rob1   = (const float*)d_in[25];
  const float* robn2g = (const float*)d_in[26];
  const float* robn2b = (const float*)d_in[27];
  const float* roW2   = (const float*)d_in[28];
  const float* rob2   = (const float*)d_in[29];
  float* out = (float*)d_out;

  const int* row = ei;
  const int* col = ei + E;

  char* p = (char*)d_ws;
  auto alloc = [&](size_t bytes) -> void* {
    void* r = (void*)p;
    p += (bytes + 255) & ~(size_t)255;
    return r;
  };
  unsigned short* xbf = (unsigned short*)alloc((size_t)N * HD * 2);
  unsigned short* B0  = (unsigned short*)alloc((size_t)N * HD * 2);   // h bf16
  unsigned short* Xc  = (unsigned short*)alloc((size_t)N * HD * 2);
  unsigned short* Xo  = (unsigned short*)alloc((size_t)N * HD * 2);
  unsigned short* Z1  = (unsigned short*)alloc((size_t)N * HD * 2);
  unsigned short* Z2  = (unsigned short*)alloc((size_t)N * HD * 2);
  float2* eattO  = (float2*)alloc((size_t)E * 8);
  int*   csr_src = (int*)alloc((size_t)E * 4);
  int*   csr_dst = (int*)alloc((size_t)E * 4);
  int*   csr_eid = (int*)alloc((size_t)E * 4);
  int*   csr2_eid= (int*)alloc((size_t)E * 4);
  float* wn1     = (float*)alloc((size_t)E * 4);
  float* wnc     = (float*)alloc((size_t)E * 4);
  float* wno     = (float*)alloc((size_t)E * 4);
  int*   ptrA    = (int*)alloc((size_t)(N + 1) * 4);
  int*   ptrR    = (int*)alloc((size_t)(N + 1) * 4);
  int*   cursor  = (int*)alloc((size_t)N * 4);
  int*   cursor2 = (int*)alloc((size_t)N * 4);
  int*   cnt_in  = (int*)alloc((size_t)N * 4);
  int*   outdeg  = (int*)alloc((size_t)N * 4);
  float* dinv1   = (float*)alloc((size_t)N * 4);
  float2* ddeg   = (float2*)alloc((size_t)N * 8);
  float* natt    = (float*)alloc((size_t)N * 2 * 4);
  float* pe      = (float*)alloc((size_t)N * 4 * 4);
  float* stats   = (float*)alloc(12 * HD * 4);
  float* pooledc = (float*)alloc((size_t)G * HD * 4);
  float* pooledo = (float*)alloc((size_t)G * HD * 4);
  float* Ybuf    = (float*)alloc((size_t)3 * 128 * 128 * 4);
  int*   csums   = (int*)alloc(64 * 4);
  int*   coffs   = (int*)alloc(64 * 4);
  int*   csums2  = (int*)alloc(64 * 4);
  int*   coffs2  = (int*)alloc(64 * 4);

  const int NCH = (N + 1023) / 1024;  // scan chunks

  // ---- init ----
  hipMemsetAsync(cnt_in, 0, (size_t)N * 4, stream);
  hipMemsetAsync(outdeg, 0, (size_t)N * 4, stream);
  hipMemsetAsync(stats, 0, 12 * HD * 4, stream);
  hipMemsetAsync(pooledc, 0, (size_t)G * HD * 4, stream);
  hipMemsetAsync(pooledo, 0, (size_t)G * HD * 4, stream);

  // ---- CSRs (by dest for prop; by row for degree reduce) ----
  hist_kernel<<<(E + 255) / 256, 256, 0, stream>>>(row, col, cnt_in, outdeg, E);
  scan1<<<NCH, 256, 0, stream>>>(cnt_in, N, csums);
  scan2<<<1, 64, 0, stream>>>(csums, NCH, coffs);
  scan3<<<NCH, 256, 0, stream>>>(cnt_in, N, coffs, ptrA, cursor);
  scan1<<<NCH, 256, 0, stream>>>(outdeg, N, csums2);
  scan2<<<1, 64, 0, stream>>>(csums2, NCH, coffs2);
  scan3<<<NCH, 256, 0, stream>>>(outdeg, N, coffs2, ptrR, cursor2);
  place1<<<(E + 255) / 256, 256, 0, stream>>>(row, col, cursor, csr_src, csr_dst, csr_eid, E);
  place2<<<(E + 255) / 256, 256, 0, stream>>>(row, cursor2, csr2_eid, E);
  dinv1_kernel<<<(N + 255) / 256, 256, 0, stream>>>(outdeg, dinv1, N);
  wn1_flat<<<(E + 255) / 256, 256, 0, stream>>>(csr_src, csr_dst, dinv1, wn1, E);

  const int SB = 256;
  int rpb = (N + SB - 1) / SB;
  int gblocks = (N + 63) / 64;
  int pblocks = (N + 1) / 2;
  float invN = 1.f / (float)N;

  // ---- feature BN + gfn linear + relu ----
  colstats_castx<<<SB, 256, 0, stream>>>(x, xbf, N, rpb, stats, stats + HD);
  gemm_mfma<<<gblocks, 256, 0, stream>>>(xbf, Wfeat, bnfg, bnfb, stats, stats + HD, invN,
                                         nullptr, 0, B0, N, 1);

  // ---- 3 GCN conv layers ----
  for (int i = 0; i < 3; i++) {
    float* hs = stats + 2 * HD + i * 2 * HD;
    colstats_bf<<<SB, 256, 0, stream>>>(B0, N, rpb, hs, hs + HD);
    gemm_mfma<<<gblocks, 256, 0, stream>>>(B0, convW + (size_t)i * HD * HD,
                                           bnsg + i * HD, bnsb + i * HD, hs, hs + HD, invN,
                                           nullptr, 0, Z1, N, 0);
    prop_kernel<<<pblocks, 256, 0, stream>>>(Z1, ptrA, csr_src, wn1, dinv1, 1,
                                             convb + i * HD, B0, N, 1);
  }

  // ---- attention (atomic-free) ----
  proj_kernel<<<512, 256, 0, stream>>>(B0, Weatt, Wnatt, bnatt, natt, pe, N);
  eatt_flat<<<(E + 255) / 256, 256, 0, stream>>>(row, col, pe, beatt, eattO, E);
  deg_kernel<<<(N * 64 + 255) / 256, 256, 0, stream>>>(ptrR, csr2_eid, eattO, ddeg, N);
  wn_flat<<<(E + 255) / 256, 256, 0, stream>>>(csr_src, csr_dst, csr_eid, eattO, ddeg,
                                               wnc, wno, E);

  // ---- xc / xo paths ----
  float* cs = stats + 8 * HD;
  colstats_scaled<<<SB, 256, 0, stream>>>(B0, natt, N, rpb, cs);
  gemm_mfma<<<gblocks, 256, 0, stream>>>(B0, Wc, bncg, bncb, cs, cs + HD, invN,
                                         natt, 2, Z1, N, 0);
  gemm_mfma<<<gblocks, 256, 0, stream>>>(B0, Wo, bnog, bnob, cs + 2 * HD, cs + 3 * HD, invN,
                                         natt + 1, 2, Z2, N, 0);

  prop_kernel<<<pblocks, 256, 0, stream>>>(Z1, ptrA, csr_src, wnc, (const float*)ddeg, 2,
                                           bc, Xc, N, 1);
  prop_kernel<<<pblocks, 256, 0, stream>>>(Z2, ptrA, csr_src, wno, ((const float*)ddeg) + 1, 2,
                                           bo, Xo, N, 1);

  // ---- pool + heads ----
  pool_kernel<<<(N + POOL_RPB - 1) / POOL_RPB, 128, 0, stream>>>(Xc, Xo, batch, N, pooledc, pooledo);
  head1<<<12, 256, 0, stream>>>(pooledc, pooledo, robn1g, robn1b, roW1, rob1, Ybuf);
  head2<<<3, 256, 0, stream>>>(Ybuf, robn2g, robn2b, roW2, rob2, out);
}

// Round 7
// 784.878 us; speedup vs baseline: 1.5917x; 1.1148x over previous
//
#include <hip/hip_runtime.h>

#define HD 128

typedef __attribute__((ext_vector_type(8))) short bf16x8v;
typedef __attribute__((ext_vector_type(4))) float f32x4v;

__device__ __forceinline__ unsigned short f2bf(float f) {
  unsigned int u = __float_as_uint(f);
  u += 0x7FFFu + ((u >> 16) & 1u);   // RNE
  return (unsigned short)(u >> 16);
}
__device__ __forceinline__ float bf2f(unsigned short h) {
  return __uint_as_float(((unsigned int)h) << 16);
}
__device__ __forceinline__ float bflo(unsigned int u) { return __uint_as_float(u << 16); }
__device__ __forceinline__ float bfhi(unsigned int u) { return __uint_as_float(u & 0xFFFF0000u); }
__device__ __forceinline__ unsigned int packbf(float a, float b) {
  return (unsigned int)f2bf(a) | ((unsigned int)f2bf(b) << 16);
}

// ===================== graph preprocessing =====================

__global__ void hist_kernel(const int* __restrict__ row, const int* __restrict__ col,
                            int* __restrict__ cnt_in, int* __restrict__ outdeg, int e) {
  int i = blockIdx.x * blockDim.x + threadIdx.x;
  if (i < e) { atomicAdd(&cnt_in[col[i]], 1); atomicAdd(&outdeg[row[i]], 1); }
}

__global__ void scan1(const int* __restrict__ cnt, int n, int* __restrict__ sums) {
  __shared__ int lds[256];
  int b = blockIdx.x, t = threadIdx.x;
  int base = b * 1024 + t * 4;
  int s = 0;
#pragma unroll
  for (int m = 0; m < 4; m++) if (base + m < n) s += cnt[base + m];
  lds[t] = s;
  __syncthreads();
  for (int d = 128; d > 0; d >>= 1) {
    if (t < d) lds[t] += lds[t + d];
    __syncthreads();
  }
  if (t == 0) sums[b] = lds[0];
}

__global__ void scan2(const int* __restrict__ sums, int nc, int* __restrict__ off) {
  int l = threadIdx.x;
  int v = (l < nc) ? sums[l] : 0;
  int x = v;
#pragma unroll
  for (int d = 1; d < 64; d <<= 1) {
    int y = __shfl_up(x, d, 64);
    if (l >= d) x += y;
  }
  if (l < nc) off[l] = x - v;  // exclusive
}

__global__ void scan3(const int* __restrict__ cnt, int n, const int* __restrict__ off,
                      int* __restrict__ ptr, int* __restrict__ cursor) {
  __shared__ int lds[256];
  int b = blockIdx.x, t = threadIdx.x;
  int base = b * 1024 + t * 4;
  int v[4], p[4];
#pragma unroll
  for (int m = 0; m < 4; m++) v[m] = (base + m < n) ? cnt[base + m] : 0;
  p[0] = v[0];
#pragma unroll
  for (int m = 1; m < 4; m++) p[m] = p[m - 1] + v[m];
  int tsum = p[3];
  lds[t] = tsum;
  __syncthreads();
  for (int d = 1; d < 256; d <<= 1) {
    int y = 0;
    if (t >= d) y = lds[t - d];
    __syncthreads();
    lds[t] += y;
    __syncthreads();
  }
  int basev = off[b] + lds[t] - tsum;
  if (b == 0 && t == 0) ptr[0] = 0;
#pragma unroll
  for (int m = 0; m < 4; m++) {
    int i = base + m;
    if (i < n) {
      int incl = basev + p[m];
      ptr[i + 1] = incl;
      cursor[i] = incl - v[m];
    }
  }
}

__global__ void place1(const int* __restrict__ row, const int* __restrict__ col,
                       int* __restrict__ cursor, int* __restrict__ csr_src,
                       int* __restrict__ csr_dst, int* __restrict__ csr_eid, int e) {
  int i = blockIdx.x * blockDim.x + threadIdx.x;
  if (i < e) {
    int c = col[i];
    int pos = atomicAdd(&cursor[c], 1);
    csr_src[pos] = row[i];
    csr_dst[pos] = c;
    csr_eid[pos] = i;
  }
}

__global__ void place2(const int* __restrict__ row, int* __restrict__ cursor2,
                       int* __restrict__ csr2_eid, int e) {
  int i = blockIdx.x * blockDim.x + threadIdx.x;
  if (i < e) {
    int pos = atomicAdd(&cursor2[row[i]], 1);
    csr2_eid[pos] = i;
  }
}

__global__ void dinv1_kernel(const int* __restrict__ outdeg, float* __restrict__ dinv1, int n) {
  int i = blockIdx.x * blockDim.x + threadIdx.x;
  if (i < n) dinv1[i] = rsqrtf((float)(outdeg[i] + 1));
}

__global__ void wn1_flat(const int* __restrict__ csr_src, const int* __restrict__ csr_dst,
                         const float* __restrict__ dinv1, float* __restrict__ wn, int e) {
  int i = blockIdx.x * blockDim.x + threadIdx.x;
  if (i < e) wn[i] = dinv1[csr_src[i]] * dinv1[csr_dst[i]];
}

// ===================== BN stats =====================

__global__ void colstats_castx(const float* __restrict__ A, unsigned short* __restrict__ Abf,
                               int n, int rpb, float* __restrict__ sum, float* __restrict__ sumsq) {
  int colj = threadIdx.x & (HD - 1);
  int half = threadIdx.x >> 7;
  int r0 = blockIdx.x * rpb;
  int r1 = min(n, r0 + rpb);
  float s = 0.f, q = 0.f;
  for (int r = r0 + half; r < r1; r += 2) {
    float v = A[(size_t)r * HD + colj];
    Abf[(size_t)r * HD + colj] = f2bf(v);
    s += v; q += v * v;
  }
  atomicAdd(&sum[colj], s);
  atomicAdd(&sumsq[colj], q);
}

__global__ void colstats_bf(const unsigned short* __restrict__ A, int n, int rpb,
                            float* __restrict__ sum, float* __restrict__ sumsq) {
  int colj = threadIdx.x & (HD - 1);
  int half = threadIdx.x >> 7;
  int r0 = blockIdx.x * rpb;
  int r1 = min(n, r0 + rpb);
  float s = 0.f, q = 0.f;
  for (int r = r0 + half; r < r1; r += 2) {
    float v = bf2f(A[(size_t)r * HD + colj]);
    s += v; q += v * v;
  }
  atomicAdd(&sum[colj], s);
  atomicAdd(&sumsq[colj], q);
}

__global__ void colstats_scaled(const unsigned short* __restrict__ A, const float* __restrict__ natt,
                                int n, int rpb, float* __restrict__ o4) {
  int colj = threadIdx.x & (HD - 1);
  int half = threadIdx.x >> 7;
  int r0 = blockIdx.x * rpb;
  int r1 = min(n, r0 + rpb);
  float sc = 0.f, qc = 0.f, so = 0.f, qo = 0.f;
  for (int r = r0 + half; r < r1; r += 2) {
    float v = bf2f(A[(size_t)r * HD + colj]);
    float a0 = natt[r * 2], a1 = natt[r * 2 + 1];
    float vc = a0 * v, vo = a1 * v;
    sc += vc; qc += vc * vc; so += vo; qo += vo * vo;
  }
  atomicAdd(&o4[colj], sc);
  atomicAdd(&o4[HD + colj], qc);
  atomicAdd(&o4[2 * HD + colj], so);
  atomicAdd(&o4[3 * HD + colj], qo);
}

// ===================== MFMA GEMM (bf16 in/out, fp32 acc) with fused BN-fold =====================
// 128 rows per block (2 sub-tiles of 64), W staged transposed + s-folded once.

__global__ __launch_bounds__(256) void gemm_mfma(
    const unsigned short* __restrict__ A, const float* __restrict__ W,
    const float* __restrict__ g, const float* __restrict__ b,
    const float* __restrict__ ssum, const float* __restrict__ ssq, float invN,
    const float* __restrict__ rowscale, int rsStride,
    unsigned short* __restrict__ out, int n, int relu) {
  __shared__ unsigned short WT[128][136];
  __shared__ float sA[HD], tA[HD], tb[HD];
  int tid = threadIdx.x;
  int r00 = blockIdx.x * 128;

  if (tid < HD) {
    float m = ssum[tid] * invN;
    float v = ssq[tid] * invN - m * m;
    float s = g[tid] * rsqrtf(v + 1e-5f);
    sA[tid] = s;
    tA[tid] = b[tid] - m * s;
  }
  __syncthreads();
  for (int idx = tid; idx < 4096; idx += 256) {
    int k = idx >> 5;
    int j4 = (idx & 31) * 4;
    float4 w = *(const float4*)(W + (size_t)k * 128 + j4);
    float s = sA[k];
    WT[j4 + 0][k] = f2bf(w.x * s);
    WT[j4 + 1][k] = f2bf(w.y * s);
    WT[j4 + 2][k] = f2bf(w.z * s);
    WT[j4 + 3][k] = f2bf(w.w * s);
  }
  if (tid < HD) {
    float acc = 0.f;
#pragma unroll 8
    for (int k = 0; k < HD; k++) acc += tA[k] * W[(size_t)k * 128 + tid];
    tb[tid] = acc;
  }
  __syncthreads();

  int w = tid >> 6;
  int l = tid & 63;
  int colb = l & 15;
  int kcb = l >> 4;

#pragma unroll
  for (int rt = 0; rt < 2; rt++) {
    int r0 = r00 + rt * 64;
    if (r0 >= n) break;
    int arow = r0 + w * 16 + colb;
    bool rowok = arow < n;

    f32x4v acc[8];
#pragma unroll
    for (int jt = 0; jt < 8; jt++) acc[jt] = (f32x4v){0.f, 0.f, 0.f, 0.f};

    const unsigned short* Ap = A + (size_t)(rowok ? arow : 0) * 128 + kcb * 8;
#pragma unroll
    for (int kit = 0; kit < 4; kit++) {
      bf16x8v a;
      if (rowok) a = *(const bf16x8v*)(Ap + kit * 32);
      else a = (bf16x8v){0, 0, 0, 0, 0, 0, 0, 0};
#pragma unroll
      for (int jt = 0; jt < 8; jt++) {
        bf16x8v bb = *(const bf16x8v*)&WT[jt * 16 + colb][kit * 32 + kcb * 8];
        acc[jt] = __builtin_amdgcn_mfma_f32_16x16x32_bf16(a, bb, acc[jt], 0, 0, 0);
      }
    }

    int rbase = r0 + w * 16 + kcb * 4;
    float rs[4];
#pragma unroll
    for (int i = 0; i < 4; i++)
      rs[i] = rowscale ? ((rbase + i < n) ? rowscale[(size_t)(rbase + i) * rsStride] : 0.f) : 1.f;
#pragma unroll
    for (int jt = 0; jt < 8; jt++) {
      int colj = jt * 16 + colb;
      float tbv = tb[colj];
#pragma unroll
      for (int i = 0; i < 4; i++) {
        int r = rbase + i;
        if (r < n) {
          float v = acc[jt][i] * rs[i] + tbv;
          if (relu) v = fmaxf(v, 0.f);
          out[(size_t)r * 128 + colj] = f2bf(v);
        }
      }
    }
  }
}

// ===================== GCN aggregation =====================
// One WAVE per node; lane owns a column pair (1 dword = 2 bf16).
// One wave-load per edge row (256B), unroll x4.

__global__ __launch_bounds__(256) void prop1(
    const unsigned short* __restrict__ z, const int* __restrict__ ptr,
    const int* __restrict__ src, const float* __restrict__ wn,
    const float* __restrict__ dinv, const float* __restrict__ bias,
    unsigned short* __restrict__ out, int n, int relu) {
  int node = blockIdx.x * 4 + (threadIdx.x >> 6);
  if (node >= n) return;
  int lane = threadIdx.x & 63;
  const unsigned int* zp = (const unsigned int*)z;
  float dn = dinv[node];
  float ws = dn * dn;
  unsigned int us = zp[(size_t)node * 64 + lane];
  float a0 = ws * bflo(us), a1 = ws * bfhi(us);
  int e = ptr[node], e1 = ptr[node + 1];
  for (; e + 3 < e1; e += 4) {
    int s0 = src[e], s1 = src[e + 1], s2 = src[e + 2], s3 = src[e + 3];
    float w0 = wn[e], w1 = wn[e + 1], w2 = wn[e + 2], w3 = wn[e + 3];
    unsigned int u0 = zp[(size_t)s0 * 64 + lane];
    unsigned int u1 = zp[(size_t)s1 * 64 + lane];
    unsigned int u2 = zp[(size_t)s2 * 64 + lane];
    unsigned int u3 = zp[(size_t)s3 * 64 + lane];
    a0 += w0 * bflo(u0) + w1 * bflo(u1) + w2 * bflo(u2) + w3 * bflo(u3);
    a1 += w0 * bfhi(u0) + w1 * bfhi(u1) + w2 * bfhi(u2) + w3 * bfhi(u3);
  }
  for (; e < e1; e++) {
    unsigned int u = zp[(size_t)src[e] * 64 + lane];
    float we = wn[e];
    a0 += we * bflo(u);
    a1 += we * bfhi(u);
  }
  a0 += bias[lane * 2];
  a1 += bias[lane * 2 + 1];
  if (relu) { a0 = fmaxf(a0, 0.f); a1 = fmaxf(a1, 0.f); }
  ((unsigned int*)out)[(size_t)node * 64 + lane] = packbf(a0, a1);
}

// fused xc/xo aggregation: per edge read src once, gather Z1 and Z2 rows
__global__ __launch_bounds__(256) void prop2(
    const unsigned short* __restrict__ z1, const unsigned short* __restrict__ z2,
    const int* __restrict__ ptr, const int* __restrict__ src,
    const float* __restrict__ wnc, const float* __restrict__ wno,
    const float2* __restrict__ ddeg, const float* __restrict__ bc,
    const float* __restrict__ bo, unsigned short* __restrict__ xc,
    unsigned short* __restrict__ xo, int n) {
  int node = blockIdx.x * 4 + (threadIdx.x >> 6);
  if (node >= n) return;
  int lane = threadIdx.x & 63;
  const unsigned int* z1p = (const unsigned int*)z1;
  const unsigned int* z2p = (const unsigned int*)z2;
  float2 dd = ddeg[node];
  float wsc = dd.x * dd.x, wso = dd.y * dd.y;
  unsigned int uc = z1p[(size_t)node * 64 + lane];
  unsigned int uo = z2p[(size_t)node * 64 + lane];
  float c0 = wsc * bflo(uc), c1 = wsc * bfhi(uc);
  float o0 = wso * bflo(uo), o1 = wso * bfhi(uo);
  int e = ptr[node], e1 = ptr[node + 1];
  for (; e + 1 < e1; e += 2) {
    int s0 = src[e], s1 = src[e + 1];
    float wc0 = wnc[e], wc1 = wnc[e + 1];
    float wo0 = wno[e], wo1 = wno[e + 1];
    unsigned int a0 = z1p[(size_t)s0 * 64 + lane];
    unsigned int b0 = z2p[(size_t)s0 * 64 + lane];
    unsigned int a1 = z1p[(size_t)s1 * 64 + lane];
    unsigned int b1 = z2p[(size_t)s1 * 64 + lane];
    c0 += wc0 * bflo(a0) + wc1 * bflo(a1);
    c1 += wc0 * bfhi(a0) + wc1 * bfhi(a1);
    o0 += wo0 * bflo(b0) + wo1 * bflo(b1);
    o1 += wo0 * bfhi(b0) + wo1 * bfhi(b1);
  }
  for (; e < e1; e++) {
    int s = src[e];
    float wc = wnc[e], wo = wno[e];
    unsigned int a = z1p[(size_t)s * 64 + lane];
    unsigned int b = z2p[(size_t)s * 64 + lane];
    c0 += wc * bflo(a); c1 += wc * bfhi(a);
    o0 += wo * bflo(b); o1 += wo * bfhi(b);
  }
  c0 = fmaxf(c0 + bc[lane * 2], 0.f);
  c1 = fmaxf(c1 + bc[lane * 2 + 1], 0.f);
  o0 = fmaxf(o0 + bo[lane * 2], 0.f);
  o1 = fmaxf(o1 + bo[lane * 2 + 1], 0.f);
  ((unsigned int*)xc)[(size_t)node * 64 + lane] = packbf(c0, c1);
  ((unsigned int*)xo)[(size_t)node * 64 + lane] = packbf(o0, o1);
}

// ===================== attention =====================

__global__ void proj_kernel(const unsigned short* __restrict__ h, const float* __restrict__ We,
                            const float* __restrict__ Wn, const float* __restrict__ bn,
                            float* __restrict__ natt, float* __restrict__ pe, int n) {
  int gtid = blockIdx.x * blockDim.x + threadIdx.x;
  int wave = gtid >> 6;
  int lane = threadIdx.x & 63;
  int nwaves = (gridDim.x * blockDim.x) >> 6;
  for (int node = wave; node < n; node += nwaves) {
    float h0 = bf2f(h[(size_t)node * HD + lane]);
    float h1 = bf2f(h[(size_t)node * HD + 64 + lane]);
    float v[6];
    v[0] = h0 * We[lane * 2 + 0] + h1 * We[(64 + lane) * 2 + 0];
    v[1] = h0 * We[lane * 2 + 1] + h1 * We[(64 + lane) * 2 + 1];
    v[2] = h0 * We[(128 + lane) * 2 + 0] + h1 * We[(192 + lane) * 2 + 0];
    v[3] = h0 * We[(128 + lane) * 2 + 1] + h1 * We[(192 + lane) * 2 + 1];
    v[4] = h0 * Wn[lane * 2 + 0] + h1 * Wn[(64 + lane) * 2 + 0];
    v[5] = h0 * Wn[lane * 2 + 1] + h1 * Wn[(64 + lane) * 2 + 1];
#pragma unroll
    for (int m = 32; m > 0; m >>= 1) {
#pragma unroll
      for (int q = 0; q < 6; q++) v[q] += __shfl_xor(v[q], m, 64);
    }
    if (lane == 0) {
      float q0 = v[4] + bn[0], q1 = v[5] + bn[1];
      float mx = fmaxf(q0, q1);
      float e0 = expf(q0 - mx), e1 = expf(q1 - mx);
      float inv = 1.f / (e0 + e1);
      natt[node * 2 + 0] = e0 * inv;
      natt[node * 2 + 1] = e1 * inv;
      pe[node * 4 + 0] = v[0];
      pe[node * 4 + 1] = v[1];
      pe[node * 4 + 2] = v[2];
      pe[node * 4 + 3] = v[3];
    }
  }
}

__global__ void eatt_flat(const int* __restrict__ row, const int* __restrict__ col,
                          const float* __restrict__ pe, const float* __restrict__ be,
                          float2* __restrict__ eattO, int e) {
  int i = blockIdx.x * blockDim.x + threadIdx.x;
  if (i >= e) return;
  int r = row[i], c = col[i];
  float l0 = pe[r * 4 + 0] + pe[c * 4 + 2] + be[0];
  float l1 = pe[r * 4 + 1] + pe[c * 4 + 3] + be[1];
  float m = fmaxf(l0, l1);
  float e0 = expf(l0 - m), e1 = expf(l1 - m);
  float inv = 1.f / (e0 + e1);
  eattO[i] = make_float2(e0 * inv, e1 * inv);
}

__global__ void deg_kernel(const int* __restrict__ ptrR, const int* __restrict__ csr2_eid,
                           const float2* __restrict__ eattO, float2* __restrict__ ddeg, int n) {
  int gtid = blockIdx.x * blockDim.x + threadIdx.x;
  int node = gtid >> 6;
  int lane = threadIdx.x & 63;
  if (node >= n) return;
  int e0 = ptrR[node], e1 = ptrR[node + 1];
  float sc = 0.f, so = 0.f;
  for (int e = e0 + lane; e < e1; e += 64) {
    float2 at = eattO[csr2_eid[e]];
    sc += at.x; so += at.y;
  }
#pragma unroll
  for (int m = 32; m > 0; m >>= 1) {
    sc += __shfl_xor(sc, m, 64);
    so += __shfl_xor(so, m, 64);
  }
  if (lane == 0) ddeg[node] = make_float2(rsqrtf(1.f + sc), rsqrtf(1.f + so));
}

__global__ void wn_flat(const int* __restrict__ csr_src, const int* __restrict__ csr_dst,
                        const int* __restrict__ csr_eid, const float2* __restrict__ eattO,
                        const float2* __restrict__ ddeg, float* __restrict__ wnc,
                        float* __restrict__ wno, int e) {
  int i = blockIdx.x * blockDim.x + threadIdx.x;
  if (i >= e) return;
  int s = csr_src[i], c = csr_dst[i];
  float2 at = eattO[csr_eid[i]];
  float2 ds = ddeg[s], dc = ddeg[c];
  wnc[i] = ds.x * at.x * dc.x;
  wno[i] = ds.y * at.y * dc.y;
}

// ===================== pooling =====================

#define POOL_RPB 32

__global__ void pool_kernel(const unsigned short* __restrict__ xc,
                            const unsigned short* __restrict__ xo,
                            const int* __restrict__ batch, int n,
                            float* __restrict__ pc, float* __restrict__ po) {
  int j = threadIdx.x;  // 128
  int r0 = blockIdx.x * POOL_RPB;
  int r1 = min(n, r0 + POOL_RPB);
  if (r0 >= n) return;
  int g = batch[r0];
  float ac = 0.f, ao = 0.f;
  for (int r = r0; r < r1; r++) {
    int br = batch[r];
    if (br != g) {
      atomicAdd(&pc[g * HD + j], ac);
      atomicAdd(&po[g * HD + j], ao);
      ac = 0.f; ao = 0.f; g = br;
    }
    ac += bf2f(xc[(size_t)r * HD + j]);
    ao += bf2f(xo[(size_t)r * HD + j]);
  }
  atomicAdd(&pc[g * HD + j], ac);
  atomicAdd(&po[g * HD + j], ao);
}

// ===================== readout heads =====================

__global__ __launch_bounds__(256) void head1(
    const float* __restrict__ pc, const float* __restrict__ po,
    const float* __restrict__ bn1g, const float* __restrict__ bn1b,
    const float* __restrict__ W1, const float* __restrict__ b1,
    float* __restrict__ Ybuf) {
  int t = blockIdx.x >> 2;
  int jt = blockIdx.x & 3;
  __shared__ float V[128][132];
  __shared__ float Wt[128][33];
  __shared__ float sA[128], tA[128];
  __shared__ float redS[2][128], redQ[2][128];
  int tid = threadIdx.x;

  for (int idx = tid; idx < 16384; idx += 256) {
    int r = idx >> 7, j = idx & 127;
    float v = (t == 0) ? pc[idx] : (t == 1) ? po[idx] : (pc[idx] + po[idx]);
    V[r][j] = v;
  }
  for (int idx = tid; idx < 4096; idx += 256) {
    int k = idx >> 5, c = idx & 31;
    Wt[k][c] = W1[(size_t)t * 16384 + k * 128 + jt * 32 + c];
  }
  __syncthreads();
  {
    int cj = tid & 127, ch = tid >> 7;
    float s = 0.f, q = 0.f;
    for (int r = ch * 64; r < ch * 64 + 64; r++) { float v = V[r][cj]; s += v; q += v * v; }
    redS[ch][cj] = s; redQ[ch][cj] = q;
  }
  __syncthreads();
  if (tid < 128) {
    float s = redS[0][tid] + redS[1][tid];
    float q = redQ[0][tid] + redQ[1][tid];
    float m = s * (1.f / 128.f), var = q * (1.f / 128.f) - m * m;
    float sc = bn1g[t * 128 + tid] * rsqrtf(var + 1e-5f);
    sA[tid] = sc; tA[tid] = bn1b[t * 128 + tid] - m * sc;
  }
  __syncthreads();
  for (int idx = tid; idx < 16384; idx += 256) {
    int r = idx >> 7, j = idx & 127;
    V[r][j] = V[r][j] * sA[j] + tA[j];
  }
  __syncthreads();
  int tr = tid >> 5, tc = tid & 31;
  float acc[16];
#pragma unroll
  for (int i = 0; i < 16; i++) acc[i] = 0.f;
  for (int k = 0; k < 128; k += 4) {
    float w0 = Wt[k][tc], w1 = Wt[k + 1][tc], w2 = Wt[k + 2][tc], w3 = Wt[k + 3][tc];
#pragma unroll
    for (int i = 0; i < 16; i++) {
      float4 v = *(float4*)&V[tr * 16 + i][k];
      acc[i] += v.x * w0 + v.y * w1 + v.z * w2 + v.w * w3;
    }
  }
  float bj = b1[t * 128 + jt * 32 + tc];
#pragma unroll
  for (int i = 0; i < 16; i++) {
    int r = tr * 16 + i;
    Ybuf[(size_t)t * 16384 + r * 128 + jt * 32 + tc] = fmaxf(acc[i] + bj, 0.f);
  }
}

__global__ __launch_bounds__(256) void head2(
    const float* __restrict__ Ybuf,
    const float* __restrict__ bn2g, const float* __restrict__ bn2b,
    const float* __restrict__ W2, const float* __restrict__ b2,
    float* __restrict__ out) {
  int t = blockIdx.x;
  __shared__ float Y[128][132];
  __shared__ float W2s[128][11];
  __shared__ float Z[128][12];
  __shared__ float sA[128], tA[128];
  __shared__ float redS[2][128], redQ[2][128];
  int tid = threadIdx.x;

  for (int idx = tid; idx < 16384; idx += 256) {
    int r = idx >> 7, j = idx & 127;
    Y[r][j] = Ybuf[(size_t)t * 16384 + idx];
  }
  for (int idx = tid; idx < 1280; idx += 256) {
    int k = idx / 10, c = idx % 10;
    W2s[k][c] = W2[(size_t)t * 1280 + idx];
  }
  __syncthreads();
  {
    int cj = tid & 127, ch = tid >> 7;
    float s = 0.f, q = 0.f;
    for (int r = ch * 64; r < ch * 64 + 64; r++) { float v = Y[r][cj]; s += v; q += v * v; }
    redS[ch][cj] = s; redQ[ch][cj] = q;
  }
  __syncthreads();
  if (tid < 128) {
    float s = redS[0][tid] + redS[1][tid];
    float q = redQ[0][tid] + redQ[1][tid];
    float m = s * (1.f / 128.f), var = q * (1.f / 128.f) - m * m;
    float sc = bn2g[t * 128 + tid] * rsqrtf(var + 1e-5f);
    sA[tid] = sc; tA[tid] = bn2b[t * 128 + tid] - m * sc;
  }
  __syncthreads();
  for (int idx = tid; idx < 16384; idx += 256) {
    int r = idx >> 7, j = idx & 127;
    Y[r][j] = Y[r][j] * sA[j] + tA[j];
  }
  __syncthreads();
  for (int idx = tid; idx < 1280; idx += 256) {
    int r = idx / 10, c = idx % 10;
    float acc = b2[t * 10 + c];
#pragma unroll 8
    for (int k = 0; k < 128; k++) acc += Y[r][k] * W2s[k][c];
    Z[r][c] = acc;
  }
  __syncthreads();
  if (tid < 128) {
    int r = tid;
    float m = -1e30f;
    for (int c = 0; c < 10; c++) m = fmaxf(m, Z[r][c]);
    float se = 0.f;
    for (int c = 0; c < 10; c++) se += expf(Z[r][c] - m);
    float lse = m + logf(se);
    for (int c = 0; c < 10; c++) out[t * 1280 + r * 10 + c] = Z[r][c] - lse;
  }
}

// ===================== launch =====================

extern "C" void kernel_launch(void* const* d_in, const int* in_sizes, int n_in,
                              void* d_out, int out_size, void* d_ws, size_t ws_size,
                              hipStream_t stream) {
  const int N = in_sizes[0] / HD;
  const int E = in_sizes[1] / 2;
  const int G = out_size / 30;

  const float* x      = (const float*)d_in[0];
  const int*   ei     = (const int*)d_in[1];
  const int*   batch  = (const int*)d_in[2];
  const float* bnfg   = (const float*)d_in[3];
  const float* bnfb   = (const float*)d_in[4];
  const float* Wfeat  = (const float*)d_in[5];
  const float* bnsg   = (const float*)d_in[6];
  const float* bnsb   = (const float*)d_in[7];
  const float* convW  = (const float*)d_in[8];
  const float* convb  = (const float*)d_in[9];
  const float* Weatt  = (const float*)d_in[10];
  const float* beatt  = (const float*)d_in[11];
  const float* Wnatt  = (const float*)d_in[12];
  const float* bnatt  = (const float*)d_in[13];
  const float* bncg   = (const float*)d_in[14];
  const float* bncb   = (const float*)d_in[15];
  const float* bnog   = (const float*)d_in[16];
  const float* bnob   = (const float*)d_in[17];
  const float* Wc     = (const float*)d_in[18];
  const float* bc     = (const float*)d_in[19];
  const float* Wo     = (const float*)d_in[20];
  const float* bo     = (const float*)d_in[21];
  const float* robn1g = (const float*)d_in[22];
  const float* robn1b = (const float*)d_in[23];
  const float* roW1   = (const float*)d_in[24];
  const float* rob1   = (const float*)d_in[25];
  const float* robn2g = (const float*)d_in[26];
  const float* robn2b = (const float*)d_in[27];
  const float* roW2   = (const float*)d_in[28];
  const float* rob2   = (const float*)d_in[29];
  float* out = (float*)d_out;

  const int* row = ei;
  const int* col = ei + E;

  char* p = (char*)d_ws;
  auto alloc = [&](size_t bytes) -> void* {
    void* r = (void*)p;
    p += (bytes + 255) & ~(size_t)255;
    return r;
  };
  unsigned short* xbf = (unsigned short*)alloc((size_t)N * HD * 2);
  unsigned short* B0  = (unsigned short*)alloc((size_t)N * HD * 2);
  unsigned short* Xc  = (unsigned short*)alloc((size_t)N * HD * 2);
  unsigned short* Xo  = (unsigned short*)alloc((size_t)N * HD * 2);
  unsigned short* Z1  = (unsigned short*)alloc((size_t)N * HD * 2);
  unsigned short* Z2  = (unsigned short*)alloc((size_t)N * HD * 2);
  float2* eattO  = (float2*)alloc((size_t)E * 8);
  int*   csr_src = (int*)alloc((size_t)E * 4);
  int*   csr_dst = (int*)alloc((size_t)E * 4);
  int*   csr_eid = (int*)alloc((size_t)E * 4);
  int*   csr2_eid= (int*)alloc((size_t)E * 4);
  float* wn1     = (float*)alloc((size_t)E * 4);
  float* wnc     = (float*)alloc((size_t)E * 4);
  float* wno     = (float*)alloc((size_t)E * 4);
  int*   ptrA    = (int*)alloc((size_t)(N + 1) * 4);
  int*   ptrR    = (int*)alloc((size_t)(N + 1) * 4);
  int*   cursor  = (int*)alloc((size_t)N * 4);
  int*   cursor2 = (int*)alloc((size_t)N * 4);
  int*   cnt_in  = (int*)alloc((size_t)N * 4);
  int*   outdeg  = (int*)alloc((size_t)N * 4);
  float* dinv1   = (float*)alloc((size_t)N * 4);
  float2* ddeg   = (float2*)alloc((size_t)N * 8);
  float* natt    = (float*)alloc((size_t)N * 2 * 4);
  float* pe      = (float*)alloc((size_t)N * 4 * 4);
  float* stats   = (float*)alloc(12 * HD * 4);
  float* pooledc = (float*)alloc((size_t)G * HD * 4);
  float* pooledo = (float*)alloc((size_t)G * HD * 4);
  float* Ybuf    = (float*)alloc((size_t)3 * 128 * 128 * 4);
  int*   csums   = (int*)alloc(64 * 4);
  int*   coffs   = (int*)alloc(64 * 4);
  int*   csums2  = (int*)alloc(64 * 4);
  int*   coffs2  = (int*)alloc(64 * 4);

  const int NCH = (N + 1023) / 1024;

  hipMemsetAsync(cnt_in, 0, (size_t)N * 4, stream);
  hipMemsetAsync(outdeg, 0, (size_t)N * 4, stream);
  hipMemsetAsync(stats, 0, 12 * HD * 4, stream);
  hipMemsetAsync(pooledc, 0, (size_t)G * HD * 4, stream);
  hipMemsetAsync(pooledo, 0, (size_t)G * HD * 4, stream);

  hist_kernel<<<(E + 255) / 256, 256, 0, stream>>>(row, col, cnt_in, outdeg, E);
  scan1<<<NCH, 256, 0, stream>>>(cnt_in, N, csums);
  scan2<<<1, 64, 0, stream>>>(csums, NCH, coffs);
  scan3<<<NCH, 256, 0, stream>>>(cnt_in, N, coffs, ptrA, cursor);
  scan1<<<NCH, 256, 0, stream>>>(outdeg, N, csums2);
  scan2<<<1, 64, 0, stream>>>(csums2, NCH, coffs2);
  scan3<<<NCH, 256, 0, stream>>>(outdeg, N, coffs2, ptrR, cursor2);
  place1<<<(E + 255) / 256, 256, 0, stream>>>(row, col, cursor, csr_src, csr_dst, csr_eid, E);
  place2<<<(E + 255) / 256, 256, 0, stream>>>(row, cursor2, csr2_eid, E);
  dinv1_kernel<<<(N + 255) / 256, 256, 0, stream>>>(outdeg, dinv1, N);
  wn1_flat<<<(E + 255) / 256, 256, 0, stream>>>(csr_src, csr_dst, dinv1, wn1, E);

  const int SB = 256;
  int rpb = (N + SB - 1) / SB;
  int gblocks = (N + 127) / 128;
  int pblocks = (N + 3) / 4;
  float invN = 1.f / (float)N;

  colstats_castx<<<SB, 256, 0, stream>>>(x, xbf, N, rpb, stats, stats + HD);
  gemm_mfma<<<gblocks, 256, 0, stream>>>(xbf, Wfeat, bnfg, bnfb, stats, stats + HD, invN,
                                         nullptr, 0, B0, N, 1);

  for (int i = 0; i < 3; i++) {
    float* hs = stats + 2 * HD + i * 2 * HD;
    colstats_bf<<<SB, 256, 0, stream>>>(B0, N, rpb, hs, hs + HD);
    gemm_mfma<<<gblocks, 256, 0, stream>>>(B0, convW + (size_t)i * HD * HD,
                                           bnsg + i * HD, bnsb + i * HD, hs, hs + HD, invN,
                                           nullptr, 0, Z1, N, 0);
    prop1<<<pblocks, 256, 0, stream>>>(Z1, ptrA, csr_src, wn1, dinv1,
                                       convb + i * HD, B0, N, 1);
  }

  proj_kernel<<<512, 256, 0, stream>>>(B0, Weatt, Wnatt, bnatt, natt, pe, N);
  eatt_flat<<<(E + 255) / 256, 256, 0, stream>>>(row, col, pe, beatt, eattO, E);
  deg_kernel<<<(N * 64 + 255) / 256, 256, 0, stream>>>(ptrR, csr2_eid, eattO, ddeg, N);
  wn_flat<<<(E + 255) / 256, 256, 0, stream>>>(csr_src, csr_dst, csr_eid, eattO, ddeg,
                                               wnc, wno, E);

  float* cs = stats + 8 * HD;
  colstats_scaled<<<SB, 256, 0, stream>>>(B0, natt, N, rpb, cs);
  gemm_mfma<<<gblocks, 256, 0, stream>>>(B0, Wc, bncg, bncb, cs, cs + HD, invN,
                                         natt, 2, Z1, N, 0);
  gemm_mfma<<<gblocks, 256, 0, stream>>>(B0, Wo, bnog, bnob, cs + 2 * HD, cs + 3 * HD, invN,
                                         natt + 1, 2, Z2, N, 0);

  prop2<<<pblocks, 256, 0, stream>>>(Z1, Z2, ptrA, csr_src, wnc, wno, ddeg, bc, bo,
                                     Xc, Xo, N);

  pool_kernel<<<(N + POOL_RPB - 1) / POOL_RPB, 128, 0, stream>>>(Xc, Xo, batch, N, pooledc, pooledo);
  head1<<<12, 256, 0, stream>>>(pooledc, pooledo, robn1g, robn1b, roW1, rob1, Ybuf);
  head2<<<3, 256, 0, stream>>>(Ybuf, robn2g, robn2b, roW2, rob2, out);
}

// Round 8
// 702.391 us; speedup vs baseline: 1.7786x; 1.1174x over previous
//
#include <hip/hip_runtime.h>

#define HD 128

typedef __attribute__((ext_vector_type(8))) short bf16x8v;
typedef __attribute__((ext_vector_type(4))) float f32x4v;

__device__ __forceinline__ unsigned short f2bf(float f) {
  unsigned int u = __float_as_uint(f);
  u += 0x7FFFu + ((u >> 16) & 1u);   // RNE
  return (unsigned short)(u >> 16);
}
__device__ __forceinline__ float bf2f(unsigned short h) {
  return __uint_as_float(((unsigned int)h) << 16);
}
__device__ __forceinline__ float bflo(unsigned int u) { return __uint_as_float(u << 16); }
__device__ __forceinline__ float bfhi(unsigned int u) { return __uint_as_float(u & 0xFFFF0000u); }
__device__ __forceinline__ unsigned int packbf(float a, float b) {
  return (unsigned int)f2bf(a) | ((unsigned int)f2bf(b) << 16);
}

// ===================== graph preprocessing =====================

__global__ void hist_kernel(const int* __restrict__ row, const int* __restrict__ col,
                            int* __restrict__ cnt_in, int* __restrict__ outdeg, int e) {
  int i = blockIdx.x * blockDim.x + threadIdx.x;
  if (i < e) { atomicAdd(&cnt_in[col[i]], 1); atomicAdd(&outdeg[row[i]], 1); }
}

__global__ void scan1(const int* __restrict__ cnt, int n, int* __restrict__ sums) {
  __shared__ int lds[256];
  int b = blockIdx.x, t = threadIdx.x;
  int base = b * 1024 + t * 4;
  int s = 0;
#pragma unroll
  for (int m = 0; m < 4; m++) if (base + m < n) s += cnt[base + m];
  lds[t] = s;
  __syncthreads();
  for (int d = 128; d > 0; d >>= 1) {
    if (t < d) lds[t] += lds[t + d];
    __syncthreads();
  }
  if (t == 0) sums[b] = lds[0];
}

__global__ void scan2(const int* __restrict__ sums, int nc, int* __restrict__ off) {
  int l = threadIdx.x;
  int v = (l < nc) ? sums[l] : 0;
  int x = v;
#pragma unroll
  for (int d = 1; d < 64; d <<= 1) {
    int y = __shfl_up(x, d, 64);
    if (l >= d) x += y;
  }
  if (l < nc) off[l] = x - v;  // exclusive
}

__global__ void scan3(const int* __restrict__ cnt, int n, const int* __restrict__ off,
                      int* __restrict__ ptr, int* __restrict__ cursor) {
  __shared__ int lds[256];
  int b = blockIdx.x, t = threadIdx.x;
  int base = b * 1024 + t * 4;
  int v[4], p[4];
#pragma unroll
  for (int m = 0; m < 4; m++) v[m] = (base + m < n) ? cnt[base + m] : 0;
  p[0] = v[0];
#pragma unroll
  for (int m = 1; m < 4; m++) p[m] = p[m - 1] + v[m];
  int tsum = p[3];
  lds[t] = tsum;
  __syncthreads();
  for (int d = 1; d < 256; d <<= 1) {
    int y = 0;
    if (t >= d) y = lds[t - d];
    __syncthreads();
    lds[t] += y;
    __syncthreads();
  }
  int basev = off[b] + lds[t] - tsum;
  if (b == 0 && t == 0) ptr[0] = 0;
#pragma unroll
  for (int m = 0; m < 4; m++) {
    int i = base + m;
    if (i < n) {
      int incl = basev + p[m];
      ptr[i + 1] = incl;
      cursor[i] = incl - v[m];
    }
  }
}

// both CSRs in one pass
__global__ void place_both(const int* __restrict__ row, const int* __restrict__ col,
                           int* __restrict__ cursor, int* __restrict__ cursor2,
                           int* __restrict__ csr_src, int* __restrict__ csr_dst,
                           int* __restrict__ csr_eid, int* __restrict__ csr2_eid, int e) {
  int i = blockIdx.x * blockDim.x + threadIdx.x;
  if (i < e) {
    int r = row[i], c = col[i];
    int pos = atomicAdd(&cursor[c], 1);
    csr_src[pos] = r;
    csr_dst[pos] = c;
    csr_eid[pos] = i;
    int pos2 = atomicAdd(&cursor2[r], 1);
    csr2_eid[pos2] = i;
  }
}

__global__ void dinv1_kernel(const int* __restrict__ outdeg, float* __restrict__ dinv1, int n) {
  int i = blockIdx.x * blockDim.x + threadIdx.x;
  if (i < n) dinv1[i] = rsqrtf((float)(outdeg[i] + 1));
}

__global__ void wn1_flat(const int* __restrict__ csr_src, const int* __restrict__ csr_dst,
                         const float* __restrict__ dinv1, float* __restrict__ wn, int e) {
  int i = blockIdx.x * blockDim.x + threadIdx.x;
  if (i < e) wn[i] = dinv1[csr_src[i]] * dinv1[csr_dst[i]];
}

// ===================== BN stats (vectorized, LDS-reduced) =====================
// Layout per block: 256 thr = 8 row-slots x 32 col-groups(4 cols). Grid-stride by 8 rows.

#define CS_BLOCKS 512

__global__ __launch_bounds__(256) void colstats_castx(
    const float* __restrict__ A, unsigned short* __restrict__ Abf, int n,
    float* __restrict__ sum, float* __restrict__ sumsq) {
  __shared__ float redS[8][132], redQ[8][132];
  int tid = threadIdx.x;
  int cg = tid & 31, ro = tid >> 5;
  float s[4] = {0.f, 0.f, 0.f, 0.f}, q[4] = {0.f, 0.f, 0.f, 0.f};
  for (int r = blockIdx.x * 8 + ro; r < n; r += gridDim.x * 8) {
    float4 v = *(const float4*)(A + (size_t)r * HD + cg * 4);
    uint2 pk;
    pk.x = packbf(v.x, v.y);
    pk.y = packbf(v.z, v.w);
    *(uint2*)(Abf + (size_t)r * HD + cg * 4) = pk;
    s[0] += v.x; q[0] += v.x * v.x;
    s[1] += v.y; q[1] += v.y * v.y;
    s[2] += v.z; q[2] += v.z * v.z;
    s[3] += v.w; q[3] += v.w * v.w;
  }
#pragma unroll
  for (int i = 0; i < 4; i++) { redS[ro][cg * 4 + i] = s[i]; redQ[ro][cg * 4 + i] = q[i]; }
  __syncthreads();
  if (tid < 128) {
    float ts = 0.f, tq = 0.f;
#pragma unroll
    for (int k = 0; k < 8; k++) { ts += redS[k][tid]; tq += redQ[k][tid]; }
    atomicAdd(&sum[tid], ts);
    atomicAdd(&sumsq[tid], tq);
  }
}

__global__ __launch_bounds__(256) void colstats_bf(
    const unsigned short* __restrict__ A, int n,
    float* __restrict__ sum, float* __restrict__ sumsq) {
  __shared__ float redS[8][132], redQ[8][132];
  int tid = threadIdx.x;
  int cg = tid & 31, ro = tid >> 5;
  float s[4] = {0.f, 0.f, 0.f, 0.f}, q[4] = {0.f, 0.f, 0.f, 0.f};
  for (int r = blockIdx.x * 8 + ro; r < n; r += gridDim.x * 8) {
    uint2 u = *(const uint2*)(A + (size_t)r * HD + cg * 4);
    float v0 = bflo(u.x), v1 = bfhi(u.x), v2 = bflo(u.y), v3 = bfhi(u.y);
    s[0] += v0; q[0] += v0 * v0;
    s[1] += v1; q[1] += v1 * v1;
    s[2] += v2; q[2] += v2 * v2;
    s[3] += v3; q[3] += v3 * v3;
  }
#pragma unroll
  for (int i = 0; i < 4; i++) { redS[ro][cg * 4 + i] = s[i]; redQ[ro][cg * 4 + i] = q[i]; }
  __syncthreads();
  if (tid < 128) {
    float ts = 0.f, tq = 0.f;
#pragma unroll
    for (int k = 0; k < 8; k++) { ts += redS[k][tid]; tq += redQ[k][tid]; }
    atomicAdd(&sum[tid], ts);
    atomicAdd(&sumsq[tid], tq);
  }
}

__global__ __launch_bounds__(256) void colstats_scaled(
    const unsigned short* __restrict__ A, const float* __restrict__ natt, int n,
    float* __restrict__ o4) {
  __shared__ float rSC[8][132], rQC[8][132], rSO[8][132], rQO[8][132];
  int tid = threadIdx.x;
  int cg = tid & 31, ro = tid >> 5;
  float sc[4] = {0.f, 0.f, 0.f, 0.f}, qc[4] = {0.f, 0.f, 0.f, 0.f};
  float so[4] = {0.f, 0.f, 0.f, 0.f}, qo[4] = {0.f, 0.f, 0.f, 0.f};
  for (int r = blockIdx.x * 8 + ro; r < n; r += gridDim.x * 8) {
    uint2 u = *(const uint2*)(A + (size_t)r * HD + cg * 4);
    float2 at = *(const float2*)(natt + r * 2);
    float v[4] = {bflo(u.x), bfhi(u.x), bflo(u.y), bfhi(u.y)};
#pragma unroll
    for (int i = 0; i < 4; i++) {
      float vc = at.x * v[i], vo = at.y * v[i];
      sc[i] += vc; qc[i] += vc * vc;
      so[i] += vo; qo[i] += vo * vo;
    }
  }
#pragma unroll
  for (int i = 0; i < 4; i++) {
    rSC[ro][cg * 4 + i] = sc[i]; rQC[ro][cg * 4 + i] = qc[i];
    rSO[ro][cg * 4 + i] = so[i]; rQO[ro][cg * 4 + i] = qo[i];
  }
  __syncthreads();
  if (tid < 128) {
    float a = 0.f, b = 0.f, c = 0.f, d = 0.f;
#pragma unroll
    for (int k = 0; k < 8; k++) {
      a += rSC[k][tid]; b += rQC[k][tid]; c += rSO[k][tid]; d += rQO[k][tid];
    }
    atomicAdd(&o4[tid], a);
    atomicAdd(&o4[HD + tid], b);
    atomicAdd(&o4[2 * HD + tid], c);
    atomicAdd(&o4[3 * HD + tid], d);
  }
}

// ===================== MFMA GEMM (bf16 in/out, fp32 acc) with fused BN-fold =====================

__global__ __launch_bounds__(256) void gemm_mfma(
    const unsigned short* __restrict__ A, const float* __restrict__ W,
    const float* __restrict__ g, const float* __restrict__ b,
    const float* __restrict__ ssum, const float* __restrict__ ssq, float invN,
    const float* __restrict__ rowscale, int rsStride,
    unsigned short* __restrict__ out, int n, int relu) {
  __shared__ unsigned short WT[128][136];
  __shared__ float sA[HD], tA[HD], tb[HD];
  int tid = threadIdx.x;
  int r00 = blockIdx.x * 128;

  if (tid < HD) {
    float m = ssum[tid] * invN;
    float v = ssq[tid] * invN - m * m;
    float s = g[tid] * rsqrtf(v + 1e-5f);
    sA[tid] = s;
    tA[tid] = b[tid] - m * s;
  }
  __syncthreads();
  for (int idx = tid; idx < 4096; idx += 256) {
    int k = idx >> 5;
    int j4 = (idx & 31) * 4;
    float4 w = *(const float4*)(W + (size_t)k * 128 + j4);
    float s = sA[k];
    WT[j4 + 0][k] = f2bf(w.x * s);
    WT[j4 + 1][k] = f2bf(w.y * s);
    WT[j4 + 2][k] = f2bf(w.z * s);
    WT[j4 + 3][k] = f2bf(w.w * s);
  }
  if (tid < HD) {
    float acc = 0.f;
#pragma unroll 8
    for (int k = 0; k < HD; k++) acc += tA[k] * W[(size_t)k * 128 + tid];
    tb[tid] = acc;
  }
  __syncthreads();

  int w = tid >> 6;
  int l = tid & 63;
  int colb = l & 15;
  int kcb = l >> 4;

#pragma unroll
  for (int rt = 0; rt < 2; rt++) {
    int r0 = r00 + rt * 64;
    if (r0 >= n) break;
    int arow = r0 + w * 16 + colb;
    bool rowok = arow < n;

    f32x4v acc[8];
#pragma unroll
    for (int jt = 0; jt < 8; jt++) acc[jt] = (f32x4v){0.f, 0.f, 0.f, 0.f};

    const unsigned short* Ap = A + (size_t)(rowok ? arow : 0) * 128 + kcb * 8;
#pragma unroll
    for (int kit = 0; kit < 4; kit++) {
      bf16x8v a;
      if (rowok) a = *(const bf16x8v*)(Ap + kit * 32);
      else a = (bf16x8v){0, 0, 0, 0, 0, 0, 0, 0};
#pragma unroll
      for (int jt = 0; jt < 8; jt++) {
        bf16x8v bb = *(const bf16x8v*)&WT[jt * 16 + colb][kit * 32 + kcb * 8];
        acc[jt] = __builtin_amdgcn_mfma_f32_16x16x32_bf16(a, bb, acc[jt], 0, 0, 0);
      }
    }

    int rbase = r0 + w * 16 + kcb * 4;
    float rs[4];
#pragma unroll
    for (int i = 0; i < 4; i++)
      rs[i] = rowscale ? ((rbase + i < n) ? rowscale[(size_t)(rbase + i) * rsStride] : 0.f) : 1.f;
#pragma unroll
    for (int jt = 0; jt < 8; jt++) {
      int colj = jt * 16 + colb;
      float tbv = tb[colj];
#pragma unroll
      for (int i = 0; i < 4; i++) {
        int r = rbase + i;
        if (r < n) {
          float v = acc[jt][i] * rs[i] + tbv;
          if (relu) v = fmaxf(v, 0.f);
          out[(size_t)r * 128 + colj] = f2bf(v);
        }
      }
    }
  }
}

// ===================== GCN aggregation =====================

__global__ __launch_bounds__(256) void prop1(
    const unsigned short* __restrict__ z, const int* __restrict__ ptr,
    const int* __restrict__ src, const float* __restrict__ wn,
    const float* __restrict__ dinv, const float* __restrict__ bias,
    unsigned short* __restrict__ out, int n, int relu) {
  int node = blockIdx.x * 4 + (threadIdx.x >> 6);
  if (node >= n) return;
  int lane = threadIdx.x & 63;
  const unsigned int* zp = (const unsigned int*)z;
  float dn = dinv[node];
  float ws = dn * dn;
  unsigned int us = zp[(size_t)node * 64 + lane];
  float a0 = ws * bflo(us), a1 = ws * bfhi(us);
  int e = ptr[node], e1 = ptr[node + 1];
  for (; e + 3 < e1; e += 4) {
    int s0 = src[e], s1 = src[e + 1], s2 = src[e + 2], s3 = src[e + 3];
    float w0 = wn[e], w1 = wn[e + 1], w2 = wn[e + 2], w3 = wn[e + 3];
    unsigned int u0 = zp[(size_t)s0 * 64 + lane];
    unsigned int u1 = zp[(size_t)s1 * 64 + lane];
    unsigned int u2 = zp[(size_t)s2 * 64 + lane];
    unsigned int u3 = zp[(size_t)s3 * 64 + lane];
    a0 += w0 * bflo(u0) + w1 * bflo(u1) + w2 * bflo(u2) + w3 * bflo(u3);
    a1 += w0 * bfhi(u0) + w1 * bfhi(u1) + w2 * bfhi(u2) + w3 * bfhi(u3);
  }
  for (; e < e1; e++) {
    unsigned int u = zp[(size_t)src[e] * 64 + lane];
    float we = wn[e];
    a0 += we * bflo(u);
    a1 += we * bfhi(u);
  }
  a0 += bias[lane * 2];
  a1 += bias[lane * 2 + 1];
  if (relu) { a0 = fmaxf(a0, 0.f); a1 = fmaxf(a1, 0.f); }
  ((unsigned int*)out)[(size_t)node * 64 + lane] = packbf(a0, a1);
}

__global__ __launch_bounds__(256) void prop2(
    const unsigned short* __restrict__ z1, const unsigned short* __restrict__ z2,
    const int* __restrict__ ptr, const int* __restrict__ src,
    const float* __restrict__ wnc, const float* __restrict__ wno,
    const float2* __restrict__ ddeg, const float* __restrict__ bc,
    const float* __restrict__ bo, unsigned short* __restrict__ xc,
    unsigned short* __restrict__ xo, int n) {
  int node = blockIdx.x * 4 + (threadIdx.x >> 6);
  if (node >= n) return;
  int lane = threadIdx.x & 63;
  const unsigned int* z1p = (const unsigned int*)z1;
  const unsigned int* z2p = (const unsigned int*)z2;
  float2 dd = ddeg[node];
  float wsc = dd.x * dd.x, wso = dd.y * dd.y;
  unsigned int uc = z1p[(size_t)node * 64 + lane];
  unsigned int uo = z2p[(size_t)node * 64 + lane];
  float c0 = wsc * bflo(uc), c1 = wsc * bfhi(uc);
  float o0 = wso * bflo(uo), o1 = wso * bfhi(uo);
  int e = ptr[node], e1 = ptr[node + 1];
  for (; e + 1 < e1; e += 2) {
    int s0 = src[e], s1 = src[e + 1];
    float wc0 = wnc[e], wc1 = wnc[e + 1];
    float wo0 = wno[e], wo1 = wno[e + 1];
    unsigned int a0 = z1p[(size_t)s0 * 64 + lane];
    unsigned int b0 = z2p[(size_t)s0 * 64 + lane];
    unsigned int a1 = z1p[(size_t)s1 * 64 + lane];
    unsigned int b1 = z2p[(size_t)s1 * 64 + lane];
    c0 += wc0 * bflo(a0) + wc1 * bflo(a1);
    c1 += wc0 * bfhi(a0) + wc1 * bfhi(a1);
    o0 += wo0 * bflo(b0) + wo1 * bflo(b1);
    o1 += wo0 * bfhi(b0) + wo1 * bfhi(b1);
  }
  for (; e < e1; e++) {
    int s = src[e];
    float wc = wnc[e], wo = wno[e];
    unsigned int a = z1p[(size_t)s * 64 + lane];
    unsigned int b = z2p[(size_t)s * 64 + lane];
    c0 += wc * bflo(a); c1 += wc * bfhi(a);
    o0 += wo * bflo(b); o1 += wo * bfhi(b);
  }
  c0 = fmaxf(c0 + bc[lane * 2], 0.f);
  c1 = fmaxf(c1 + bc[lane * 2 + 1], 0.f);
  o0 = fmaxf(o0 + bo[lane * 2], 0.f);
  o1 = fmaxf(o1 + bo[lane * 2 + 1], 0.f);
  ((unsigned int*)xc)[(size_t)node * 64 + lane] = packbf(c0, c1);
  ((unsigned int*)xo)[(size_t)node * 64 + lane] = packbf(o0, o1);
}

// ===================== attention =====================
// lane owns col-pair: one dword covers the row across the wave; float4 weight loads

__global__ void proj_kernel(const unsigned short* __restrict__ h, const float* __restrict__ We,
                            const float* __restrict__ Wn, const float* __restrict__ bn,
                            float* __restrict__ natt, float* __restrict__ pe, int n) {
  int gtid = blockIdx.x * blockDim.x + threadIdx.x;
  int wave = gtid >> 6;
  int lane = threadIdx.x & 63;
  int nwaves = (gridDim.x * blockDim.x) >> 6;
  const unsigned int* hp = (const unsigned int*)h;
  float4 we0 = *(const float4*)(We + lane * 4);          // rows 2l,2l+1 x {0,1}
  float4 we1 = *(const float4*)(We + 256 + lane * 4);    // rows 128+2l,128+2l+1
  float4 wn0 = *(const float4*)(Wn + lane * 4);
  for (int node = wave; node < n; node += nwaves) {
    unsigned int u = hp[(size_t)node * 64 + lane];
    float h0 = bflo(u), h1 = bfhi(u);
    float v[6];
    v[0] = h0 * we0.x + h1 * we0.z;
    v[1] = h0 * we0.y + h1 * we0.w;
    v[2] = h0 * we1.x + h1 * we1.z;
    v[3] = h0 * we1.y + h1 * we1.w;
    v[4] = h0 * wn0.x + h1 * wn0.z;
    v[5] = h0 * wn0.y + h1 * wn0.w;
#pragma unroll
    for (int m = 32; m > 0; m >>= 1) {
#pragma unroll
      for (int q = 0; q < 6; q++) v[q] += __shfl_xor(v[q], m, 64);
    }
    if (lane == 0) {
      float q0 = v[4] + bn[0], q1 = v[5] + bn[1];
      float mx = fmaxf(q0, q1);
      float e0 = expf(q0 - mx), e1 = expf(q1 - mx);
      float inv = 1.f / (e0 + e1);
      natt[node * 2 + 0] = e0 * inv;
      natt[node * 2 + 1] = e1 * inv;
      pe[node * 4 + 0] = v[0];
      pe[node * 4 + 1] = v[1];
      pe[node * 4 + 2] = v[2];
      pe[node * 4 + 3] = v[3];
    }
  }
}

__global__ void eatt_flat(const int* __restrict__ row, const int* __restrict__ col,
                          const float* __restrict__ pe, const float* __restrict__ be,
                          float2* __restrict__ eattO, int e) {
  int i = blockIdx.x * blockDim.x + threadIdx.x;
  if (i >= e) return;
  int r = row[i], c = col[i];
  float l0 = pe[r * 4 + 0] + pe[c * 4 + 2] + be[0];
  float l1 = pe[r * 4 + 1] + pe[c * 4 + 3] + be[1];
  float m = fmaxf(l0, l1);
  float e0 = expf(l0 - m), e1 = expf(l1 - m);
  float inv = 1.f / (e0 + e1);
  eattO[i] = make_float2(e0 * inv, e1 * inv);
}

__global__ void deg_kernel(const int* __restrict__ ptrR, const int* __restrict__ csr2_eid,
                           const float2* __restrict__ eattO, float2* __restrict__ ddeg, int n) {
  int gtid = blockIdx.x * blockDim.x + threadIdx.x;
  int node = gtid >> 6;
  int lane = threadIdx.x & 63;
  if (node >= n) return;
  int e0 = ptrR[node], e1 = ptrR[node + 1];
  float sc = 0.f, so = 0.f;
  for (int e = e0 + lane; e < e1; e += 64) {
    float2 at = eattO[csr2_eid[e]];
    sc += at.x; so += at.y;
  }
#pragma unroll
  for (int m = 32; m > 0; m >>= 1) {
    sc += __shfl_xor(sc, m, 64);
    so += __shfl_xor(so, m, 64);
  }
  if (lane == 0) ddeg[node] = make_float2(rsqrtf(1.f + sc), rsqrtf(1.f + so));
}

__global__ void wn_flat(const int* __restrict__ csr_src, const int* __restrict__ csr_dst,
                        const int* __restrict__ csr_eid, const float2* __restrict__ eattO,
                        const float2* __restrict__ ddeg, float* __restrict__ wnc,
                        float* __restrict__ wno, int e) {
  int i = blockIdx.x * blockDim.x + threadIdx.x;
  if (i >= e) return;
  int s = csr_src[i], c = csr_dst[i];
  float2 at = eattO[csr_eid[i]];
  float2 ds = ddeg[s], dc = ddeg[c];
  wnc[i] = ds.x * at.x * dc.x;
  wno[i] = ds.y * at.y * dc.y;
}

// ===================== pooling =====================

#define POOL_RPB 32

__global__ void pool_kernel(const unsigned short* __restrict__ xc,
                            const unsigned short* __restrict__ xo,
                            const int* __restrict__ batch, int n,
                            float* __restrict__ pc, float* __restrict__ po) {
  int j = threadIdx.x;  // 128
  int r0 = blockIdx.x * POOL_RPB;
  int r1 = min(n, r0 + POOL_RPB);
  if (r0 >= n) return;
  int g = batch[r0];
  float ac = 0.f, ao = 0.f;
  for (int r = r0; r < r1; r++) {
    int br = batch[r];
    if (br != g) {
      atomicAdd(&pc[g * HD + j], ac);
      atomicAdd(&po[g * HD + j], ao);
      ac = 0.f; ao = 0.f; g = br;
    }
    ac += bf2f(xc[(size_t)r * HD + j]);
    ao += bf2f(xo[(size_t)r * HD + j]);
  }
  atomicAdd(&pc[g * HD + j], ac);
  atomicAdd(&po[g * HD + j], ao);
}

// ===================== readout heads =====================

__global__ __launch_bounds__(256) void head1(
    const float* __restrict__ pc, const float* __restrict__ po,
    const float* __restrict__ bn1g, const float* __restrict__ bn1b,
    const float* __restrict__ W1, const float* __restrict__ b1,
    float* __restrict__ Ybuf) {
  int t = blockIdx.x >> 2;
  int jt = blockIdx.x & 3;
  __shared__ float V[128][132];
  __shared__ float Wt[128][33];
  __shared__ float sA[128], tA[128];
  __shared__ float redS[2][128], redQ[2][128];
  int tid = threadIdx.x;

  for (int idx = tid; idx < 16384; idx += 256) {
    int r = idx >> 7, j = idx & 127;
    float v = (t == 0) ? pc[idx] : (t == 1) ? po[idx] : (pc[idx] + po[idx]);
    V[r][j] = v;
  }
  for (int idx = tid; idx < 4096; idx += 256) {
    int k = idx >> 5, c = idx & 31;
    Wt[k][c] = W1[(size_t)t * 16384 + k * 128 + jt * 32 + c];
  }
  __syncthreads();
  {
    int cj = tid & 127, ch = tid >> 7;
    float s = 0.f, q = 0.f;
    for (int r = ch * 64; r < ch * 64 + 64; r++) { float v = V[r][cj]; s += v; q += v * v; }
    redS[ch][cj] = s; redQ[ch][cj] = q;
  }
  __syncthreads();
  if (tid < 128) {
    float s = redS[0][tid] + redS[1][tid];
    float q = redQ[0][tid] + redQ[1][tid];
    float m = s * (1.f / 128.f), var = q * (1.f / 128.f) - m * m;
    float sc = bn1g[t * 128 + tid] * rsqrtf(var + 1e-5f);
    sA[tid] = sc; tA[tid] = bn1b[t * 128 + tid] - m * sc;
  }
  __syncthreads();
  for (int idx = tid; idx < 16384; idx += 256) {
    int r = idx >> 7, j = idx & 127;
    V[r][j] = V[r][j] * sA[j] + tA[j];
  }
  __syncthreads();
  int tr = tid >> 5, tc = tid & 31;
  float acc[16];
#pragma unroll
  for (int i = 0; i < 16; i++) acc[i] = 0.f;
  for (int k = 0; k < 128; k += 4) {
    float w0 = Wt[k][tc], w1 = Wt[k + 1][tc], w2 = Wt[k + 2][tc], w3 = Wt[k + 3][tc];
#pragma unroll
    for (int i = 0; i < 16; i++) {
      float4 v = *(float4*)&V[tr * 16 + i][k];
      acc[i] += v.x * w0 + v.y * w1 + v.z * w2 + v.w * w3;
    }
  }
  float bj = b1[t * 128 + jt * 32 + tc];
#pragma unroll
  for (int i = 0; i < 16; i++) {
    int r = tr * 16 + i;
    Ybuf[(size_t)t * 16384 + r * 128 + jt * 32 + tc] = fmaxf(acc[i] + bj, 0.f);
  }
}

__global__ __launch_bounds__(256) void head2(
    const float* __restrict__ Ybuf,
    const float* __restrict__ bn2g, const float* __restrict__ bn2b,
    const float* __restrict__ W2, const float* __restrict__ b2,
    float* __restrict__ out) {
  int t = blockIdx.x;
  __shared__ float Y[128][132];
  __shared__ float W2s[128][11];
  __shared__ float Z[128][12];
  __shared__ float sA[128], tA[128];
  __shared__ float redS[2][128], redQ[2][128];
  int tid = threadIdx.x;

  for (int idx = tid; idx < 16384; idx += 256) {
    int r = idx >> 7, j = idx & 127;
    Y[r][j] = Ybuf[(size_t)t * 16384 + idx];
  }
  for (int idx = tid; idx < 1280; idx += 256) {
    int k = idx / 10, c = idx % 10;
    W2s[k][c] = W2[(size_t)t * 1280 + idx];
  }
  __syncthreads();
  {
    int cj = tid & 127, ch = tid >> 7;
    float s = 0.f, q = 0.f;
    for (int r = ch * 64; r < ch * 64 + 64; r++) { float v = Y[r][cj]; s += v; q += v * v; }
    redS[ch][cj] = s; redQ[ch][cj] = q;
  }
  __syncthreads();
  if (tid < 128) {
    float s = redS[0][tid] + redS[1][tid];
    float q = redQ[0][tid] + redQ[1][tid];
    float m = s * (1.f / 128.f), var = q * (1.f / 128.f) - m * m;
    float sc = bn2g[t * 128 + tid] * rsqrtf(var + 1e-5f);
    sA[tid] = sc; tA[tid] = bn2b[t * 128 + tid] - m * sc;
  }
  __syncthreads();
  for (int idx = tid; idx < 16384; idx += 256) {
    int r = idx >> 7, j = idx & 127;
    Y[r][j] = Y[r][j] * sA[j] + tA[j];
  }
  __syncthreads();
  for (int idx = tid; idx < 1280; idx += 256) {
    int r = idx / 10, c = idx % 10;
    float acc = b2[t * 10 + c];
#pragma unroll 8
    for (int k = 0; k < 128; k++) acc += Y[r][k] * W2s[k][c];
    Z[r][c] = acc;
  }
  __syncthreads();
  if (tid < 128) {
    int r = tid;
    float m = -1e30f;
    for (int c = 0; c < 10; c++) m = fmaxf(m, Z[r][c]);
    float se = 0.f;
    for (int c = 0; c < 10; c++) se += expf(Z[r][c] - m);
    float lse = m + logf(se);
    for (int c = 0; c < 10; c++) out[t * 1280 + r * 10 + c] = Z[r][c] - lse;
  }
}

// ===================== launch =====================

extern "C" void kernel_launch(void* const* d_in, const int* in_sizes, int n_in,
                              void* d_out, int out_size, void* d_ws, size_t ws_size,
                              hipStream_t stream) {
  const int N = in_sizes[0] / HD;
  const int E = in_sizes[1] / 2;
  const int G = out_size / 30;

  const float* x      = (const float*)d_in[0];
  const int*   ei     = (const int*)d_in[1];
  const int*   batch  = (const int*)d_in[2];
  const float* bnfg   = (const float*)d_in[3];
  const float* bnfb   = (const float*)d_in[4];
  const float* Wfeat  = (const float*)d_in[5];
  const float* bnsg   = (const float*)d_in[6];
  const float* bnsb   = (const float*)d_in[7];
  const float* convW  = (const float*)d_in[8];
  const float* convb  = (const float*)d_in[9];
  const float* Weatt  = (const float*)d_in[10];
  const float* beatt  = (const float*)d_in[11];
  const float* Wnatt  = (const float*)d_in[12];
  const float* bnatt  = (const float*)d_in[13];
  const float* bncg   = (const float*)d_in[14];
  const float* bncb   = (const float*)d_in[15];
  const float* bnog   = (const float*)d_in[16];
  const float* bnob   = (const float*)d_in[17];
  const float* Wc     = (const float*)d_in[18];
  const float* bc     = (const float*)d_in[19];
  const float* Wo     = (const float*)d_in[20];
  const float* bo     = (const float*)d_in[21];
  const float* robn1g = (const float*)d_in[22];
  const float* robn1b = (const float*)d_in[23];
  const float* roW1   = (const float*)d_in[24];
  const float* rob1   = (const float*)d_in[25];
  const float* robn2g = (const float*)d_in[26];
  const float* robn2b = (const float*)d_in[27];
  const float* roW2   = (const float*)d_in[28];
  const float* rob2   = (const float*)d_in[29];
  float* out = (float*)d_out;

  const int* row = ei;
  const int* col = ei + E;

  char* p = (char*)d_ws;
  auto alloc = [&](size_t bytes) -> void* {
    void* r = (void*)p;
    p += (bytes + 255) & ~(size_t)255;
    return r;
  };
  unsigned short* xbf = (unsigned short*)alloc((size_t)N * HD * 2);
  unsigned short* B0  = (unsigned short*)alloc((size_t)N * HD * 2);
  unsigned short* Xc  = (unsigned short*)alloc((size_t)N * HD * 2);
  unsigned short* Xo  = (unsigned short*)alloc((size_t)N * HD * 2);
  unsigned short* Z1  = (unsigned short*)alloc((size_t)N * HD * 2);
  unsigned short* Z2  = (unsigned short*)alloc((size_t)N * HD * 2);
  float2* eattO  = (float2*)alloc((size_t)E * 8);
  int*   csr_src = (int*)alloc((size_t)E * 4);
  int*   csr_dst = (int*)alloc((size_t)E * 4);
  int*   csr_eid = (int*)alloc((size_t)E * 4);
  int*   csr2_eid= (int*)alloc((size_t)E * 4);
  float* wn1     = (float*)alloc((size_t)E * 4);
  float* wnc     = (float*)alloc((size_t)E * 4);
  float* wno     = (float*)alloc((size_t)E * 4);
  int*   ptrA    = (int*)alloc((size_t)(N + 1) * 4);
  int*   ptrR    = (int*)alloc((size_t)(N + 1) * 4);
  int*   cursor  = (int*)alloc((size_t)N * 4);
  int*   cursor2 = (int*)alloc((size_t)N * 4);
  int*   cnt_in  = (int*)alloc((size_t)N * 4);
  int*   outdeg  = (int*)alloc((size_t)N * 4);
  float* dinv1   = (float*)alloc((size_t)N * 4);
  float2* ddeg   = (float2*)alloc((size_t)N * 8);
  float* natt    = (float*)alloc((size_t)N * 2 * 4);
  float* pe      = (float*)alloc((size_t)N * 4 * 4);
  float* stats   = (float*)alloc(12 * HD * 4);
  float* pooledc = (float*)alloc((size_t)G * HD * 4);
  float* pooledo = (float*)alloc((size_t)G * HD * 4);
  float* Ybuf    = (float*)alloc((size_t)3 * 128 * 128 * 4);
  int*   csums   = (int*)alloc(64 * 4);
  int*   coffs   = (int*)alloc(64 * 4);
  int*   csums2  = (int*)alloc(64 * 4);
  int*   coffs2  = (int*)alloc(64 * 4);

  const int NCH = (N + 1023) / 1024;

  hipMemsetAsync(cnt_in, 0, (size_t)N * 4, stream);
  hipMemsetAsync(outdeg, 0, (size_t)N * 4, stream);
  hipMemsetAsync(stats, 0, 12 * HD * 4, stream);
  hipMemsetAsync(pooledc, 0, (size_t)G * HD * 4, stream);
  hipMemsetAsync(pooledo, 0, (size_t)G * HD * 4, stream);

  hist_kernel<<<(E + 255) / 256, 256, 0, stream>>>(row, col, cnt_in, outdeg, E);
  scan1<<<NCH, 256, 0, stream>>>(cnt_in, N, csums);
  scan2<<<1, 64, 0, stream>>>(csums, NCH, coffs);
  scan3<<<NCH, 256, 0, stream>>>(cnt_in, N, coffs, ptrA, cursor);
  scan1<<<NCH, 256, 0, stream>>>(outdeg, N, csums2);
  scan2<<<1, 64, 0, stream>>>(csums2, NCH, coffs2);
  scan3<<<NCH, 256, 0, stream>>>(outdeg, N, coffs2, ptrR, cursor2);
  place_both<<<(E + 255) / 256, 256, 0, stream>>>(row, col, cursor, cursor2,
                                                  csr_src, csr_dst, csr_eid, csr2_eid, E);
  dinv1_kernel<<<(N + 255) / 256, 256, 0, stream>>>(outdeg, dinv1, N);
  wn1_flat<<<(E + 255) / 256, 256, 0, stream>>>(csr_src, csr_dst, dinv1, wn1, E);

  int gblocks = (N + 127) / 128;
  int pblocks = (N + 3) / 4;
  float invN = 1.f / (float)N;

  colstats_castx<<<CS_BLOCKS, 256, 0, stream>>>(x, xbf, N, stats, stats + HD);
  gemm_mfma<<<gblocks, 256, 0, stream>>>(xbf, Wfeat, bnfg, bnfb, stats, stats + HD, invN,
                                         nullptr, 0, B0, N, 1);

  for (int i = 0; i < 3; i++) {
    float* hs = stats + 2 * HD + i * 2 * HD;
    colstats_bf<<<CS_BLOCKS, 256, 0, stream>>>(B0, N, hs, hs + HD);
    gemm_mfma<<<gblocks, 256, 0, stream>>>(B0, convW + (size_t)i * HD * HD,
                                           bnsg + i * HD, bnsb + i * HD, hs, hs + HD, invN,
                                           nullptr, 0, Z1, N, 0);
    prop1<<<pblocks, 256, 0, stream>>>(Z1, ptrA, csr_src, wn1, dinv1,
                                       convb + i * HD, B0, N, 1);
  }

  proj_kernel<<<512, 256, 0, stream>>>(B0, Weatt, Wnatt, bnatt, natt, pe, N);
  eatt_flat<<<(E + 255) / 256, 256, 0, stream>>>(row, col, pe, beatt, eattO, E);
  deg_kernel<<<(N * 64 + 255) / 256, 256, 0, stream>>>(ptrR, csr2_eid, eattO, ddeg, N);
  wn_flat<<<(E + 255) / 256, 256, 0, stream>>>(csr_src, csr_dst, csr_eid, eattO, ddeg,
                                               wnc, wno, E);

  float* cs = stats + 8 * HD;
  colstats_scaled<<<CS_BLOCKS, 256, 0, stream>>>(B0, natt, N, cs);
  gemm_mfma<<<gblocks, 256, 0, stream>>>(B0, Wc, bncg, bncb, cs, cs + HD, invN,
                                         natt, 2, Z1, N, 0);
  gemm_mfma<<<gblocks, 256, 0, stream>>>(B0, Wo, bnog, bnob, cs + 2 * HD, cs + 3 * HD, invN,
                                         natt + 1, 2, Z2, N, 0);

  prop2<<<pblocks, 256, 0, stream>>>(Z1, Z2, ptrA, csr_src, wnc, wno, ddeg, bc, bo,
                                     Xc, Xo, N);

  pool_kernel<<<(N + POOL_RPB - 1) / POOL_RPB, 128, 0, stream>>>(Xc, Xo, batch, N, pooledc, pooledo);
  head1<<<12, 256, 0, stream>>>(pooledc, pooledo, robn1g, robn1b, roW1, rob1, Ybuf);
  head2<<<3, 256, 0, stream>>>(Ybuf, robn2g, robn2b, roW2, rob2, out);
}